// Round 2
// baseline (763.937 us; speedup 1.0000x reference)
//
#include <hip/hip_runtime.h>
#include <hip/hip_bf16.h>

typedef __hip_bfloat16 bf16;
typedef __hip_bfloat162 bf162;

constexpr int kN   = 32768;   // nodes
constexpr int kNPG = 256;     // nodes per graph
constexpr int kG   = 128;     // graphs
constexpr int kE   = 262144;  // edges
constexpr int kED  = 32;      // edge feature dim
constexpr int kD   = 128;     // hidden
constexpr int kHG  = 4;       // GAT heads
constexpr int kCG  = 32;      // per-head channels
constexpr int kHA  = 8;       // global attn heads
constexpr int kDH  = 16;      // head dim

__device__ __forceinline__ float b2f(bf16 v){ return __bfloat162float(v); }
__device__ __forceinline__ bf16  f2b(float v){ return __float2bfloat16(v); }
__device__ __forceinline__ float tanh_fast(float x){
  float e = __expf(2.f*x);
  return 1.f - 2.f/(e+1.f);
}

// ---------------- input dtype detection ----------------
// Reads x as bf16 (safe under both layouts). True bf16 N(0,1) data: ~99.9% of
// |v| in (2^-10, 16). fp32 reinterpreted as bf16: even halves are mantissa
// bits -> random exponents -> only ~53% in range. flag=1 means inputs are fp32.
__global__ void detect_k(const void* xraw, int* flag){
  const bf16* p = (const bf16*)xraw;
  int good = 0;
  for (int i = threadIdx.x; i < 4096; i += 256){
    float v = fabsf(b2f(p[i]));
    if (v > 0.0009765625f && v < 16.f) good++;
  }
  __shared__ int s[256];
  s[threadIdx.x] = good;
  __syncthreads();
  for (int d = 128; d; d >>= 1){
    if (threadIdx.x < d) s[threadIdx.x] += s[threadIdx.x + d];
    __syncthreads();
  }
  if (threadIdx.x == 0) *flag = (s[0] < 3500) ? 1 : 0;
}

// ---------------- import: convert all float inputs to canonical ws buffers ---------
struct ImpEnt { const void* src; void* dst; int n; int dst_bf16; };
struct ImpArgs { ImpEnt e[25]; };
__global__ __launch_bounds__(256) void import_k(ImpArgs a, const int* __restrict__ flag){
  ImpEnt en = a.e[blockIdx.y];
  const bool f32 = (*flag != 0);
  for (int i = blockIdx.x*256 + threadIdx.x; i < en.n; i += gridDim.x*256){
    float v = f32 ? ((const float*)en.src)[i] : b2f(((const bf16*)en.src)[i]);
    if (en.dst_bf16) ((bf16*)en.dst)[i] = f2b(v);
    else             ((float*)en.dst)[i] = v;
  }
}

// ---------------- generic GEMM: C[M,DOUT] = A[M,din] @ W[din,DOUT] (+bias)(+gelu) ----
// A bf16, W fp32 (ws), bias fp32 (ws), C bf16. EPI: 0 none, 1 +bias, 2 +bias+gelu
template<int DOUT, int EPI>
__global__ __launch_bounds__(256) void gemm_k(const bf16* __restrict__ A,
                                              const float* __restrict__ W,
                                              const float* __restrict__ bias,
                                              bf16* __restrict__ C, int din){
  constexpr int NCG = DOUT/4;
  constexpr int NRG = 256/NCG;
  constexpr int NR  = 32/NRG;
  __shared__ float As[32*256];
  const int tid = threadIdx.x;
  const long r0 = (long)blockIdx.x * 32;
  const int total2 = (32*din)/2;
  const bf162* A2 = (const bf162*)(A + r0*din);
  for (int idx = tid; idx < total2; idx += 256){
    bf162 p = A2[idx];
    As[2*idx]   = b2f(p.x);
    As[2*idx+1] = b2f(p.y);
  }
  __syncthreads();
  const int cg = tid % NCG, rg = tid / NCG;
  const int c0 = cg*4;
  float acc[NR][4];
  #pragma unroll
  for (int r=0;r<NR;r++){ acc[r][0]=0.f; acc[r][1]=0.f; acc[r][2]=0.f; acc[r][3]=0.f; }
  const float* Ab = As + rg*NR*din;
  #pragma unroll 4
  for (int k=0;k<din;k++){
    const float4 w = *(const float4*)(W + (long)k*DOUT + c0);
    #pragma unroll
    for (int r=0;r<NR;r++){
      float a = Ab[r*din + k];
      acc[r][0] += a*w.x; acc[r][1] += a*w.y; acc[r][2] += a*w.z; acc[r][3] += a*w.w;
    }
  }
  float bv[4] = {0.f,0.f,0.f,0.f};
  if (EPI >= 1){
    #pragma unroll
    for (int j=0;j<4;j++) bv[j] = bias[c0+j];
  }
  #pragma unroll
  for (int r=0;r<NR;r++){
    long row = r0 + rg*NR + r;
    #pragma unroll
    for (int j=0;j<4;j++){
      float v = acc[r][j] + bv[j];
      if (EPI == 2) v = 0.5f*v*(1.f + erff(v*0.70710678118654752f));
      C[row*DOUT + c0 + j] = f2b(v);
    }
  }
}

// ---------------- per-edge: alpha[E,4] (GATv2 logits) + eb[E,8] (attn edge bias) ----
__global__ __launch_bounds__(256) void edge_k(const bf16* __restrict__ ea,
    const int* __restrict__ srcA, const int* __restrict__ dstA,
    const bf16* __restrict__ xs, const bf16* __restrict__ xd,
    const float* __restrict__ Wedge_f, const float* __restrict__ We_f,
    const float* __restrict__ att_f, const float* __restrict__ be_f,
    float* __restrict__ alpha, float* __restrict__ ebuf){
  __shared__ float sea[2][32];
  const int tid = threadIdx.x;
  const int e0 = blockIdx.x*2;
  if (tid < 64){
    int sub = tid>>5, d = tid&31;
    sea[sub][d] = b2f(ea[(long)(e0+sub)*32 + d]);
  }
  __syncthreads();
  const int sub = tid>>7, ch = tid&127;
  const int e = e0 + sub;
  const int s = srcA[e], dd = dstA[e];
  float ef = 0.f;
  #pragma unroll
  for (int d=0; d<32; d++) ef += sea[sub][d]*Wedge_f[d*128 + ch];
  float xv = b2f(xs[(long)s*128+ch]) + b2f(xd[(long)dd*128+ch]) + ef;
  float contrib = tanh_fast(xv) * att_f[ch];
  #pragma unroll
  for (int o=16; o; o>>=1) contrib += __shfl_xor(contrib, o, 32);
  if ((ch&31) == 0) alpha[(long)e*4 + (ch>>5)] = contrib;
  if (ch < 8){
    float sbe = be_f[ch];
    #pragma unroll
    for (int d=0; d<32; d++) sbe += sea[sub][d]*We_f[d*8 + ch];
    ebuf[(long)e*8 + ch] = sbe;
  }
}

// ---------------- CSR build ----------------
__global__ void hist_k(const int* __restrict__ dstA, int* __restrict__ cnt){
  int e = blockIdx.x*256 + threadIdx.x;
  if (e < kE) atomicAdd(&cnt[dstA[e]], 1);
}

__global__ __launch_bounds__(1024) void scan_k(const int* __restrict__ cnt, int* __restrict__ rowptr){
  __shared__ int part[1024];
  const int t = threadIdx.x;
  const int base = t*32;
  int s = 0;
  #pragma unroll
  for (int i=0;i<32;i++) s += cnt[base+i];
  part[t] = s;
  __syncthreads();
  for (int d=1; d<1024; d<<=1){
    int v = (t>=d) ? part[t-d] : 0;
    __syncthreads();
    part[t] += v;
    __syncthreads();
  }
  int run = (t==0) ? 0 : part[t-1];
  for (int i=0;i<32;i++){ rowptr[base+i] = run; run += cnt[base+i]; }
  if (t == 1023) rowptr[kN] = run;
}

__global__ void scatter_k(const int* __restrict__ dstA, const int* __restrict__ rowptr,
                          int* __restrict__ cursor, int* __restrict__ eidx){
  int e = blockIdx.x*256 + threadIdx.x;
  if (e < kE){
    int d = dstA[e];
    int p = atomicAdd(&cursor[d], 1);
    eidx[rowptr[d]+p] = e;
  }
}

// ---------------- GAT aggregate ----------------
__global__ __launch_bounds__(128) void gat_agg_k(const float* __restrict__ alpha,
    const int* __restrict__ rowptr, const int* __restrict__ eidx,
    const int* __restrict__ srcA, const bf16* __restrict__ xs,
    const float* __restrict__ gatb_f, bf16* __restrict__ h_local){
  const int v = blockIdx.x;
  const int tid = threadIdx.x;
  const int h = tid>>5;
  const int beg = rowptr[v], end = rowptr[v+1];
  const int deg = end - beg;
  float out = 0.f;
  if (deg > 0){
    float m = -1e30f;
    for (int i=0;i<deg;i++) m = fmaxf(m, alpha[(long)eidx[beg+i]*4 + h]);
    float den = 0.f;
    for (int i=0;i<deg;i++) den += __expf(alpha[(long)eidx[beg+i]*4 + h] - m);
    float inv = 1.f/(den + 1e-16f);
    for (int i=0;i<deg;i++){
      int e = eidx[beg+i];
      float w = __expf(alpha[(long)e*4 + h] - m) * inv;
      out += w * b2f(xs[(long)srcA[e]*128 + tid]);
    }
  }
  h_local[(long)v*128 + tid] = f2b(out + gatb_f[tid]);
}

// ---------------- dense per-graph attention with sparse edge bias --------------------
__global__ __launch_bounds__(256) void attn_k(const bf16* __restrict__ qb,
    const bf16* __restrict__ kb, const bf16* __restrict__ vb,
    const float* __restrict__ ebuf, const int* __restrict__ rowptr,
    const int* __restrict__ eidx, const int* __restrict__ srcA,
    const int* __restrict__ dstA, bf16* __restrict__ hattn_pre){
  __shared__ float Ks[256*16];
  __shared__ float Vs[256*16];
  __shared__ float bias[256*17];
  const int g = blockIdx.x >> 3, h = blockIdx.x & 7;
  const int tid = threadIdx.x;
  const int nbase = g*256;
  for (int idx = tid; idx < 4096; idx += 256){
    int row = idx>>4, d = idx&15;
    long gaddr = (long)(nbase+row)*128 + h*16 + d;
    Ks[idx] = b2f(kb[gaddr]);
    Vs[idx] = b2f(vb[gaddr]);
  }
  const int i = tid;
  float qr[16];
  #pragma unroll
  for (int d=0; d<16; d++) qr[d] = b2f(qb[(long)(nbase+i)*128 + h*16 + d]) * 0.25f;
  float m = -1e30f, l = 0.f, o[16];
  #pragma unroll
  for (int d=0; d<16; d++) o[d] = 0.f;
  for (int c=0; c<16; c++){
    __syncthreads();
    for (int idx = tid; idx < 256*17; idx += 256) bias[idx] = 0.f;
    __syncthreads();
    int rb = rowptr[nbase + c*16], re = rowptr[nbase + c*16 + 16];
    for (int t = rb + tid; t < re; t += 256){
      int e = eidx[t];
      int ii = srcA[e] - nbase;
      int jj = dstA[e] - (nbase + c*16);
      if ((unsigned)ii < 256u) atomicAdd(&bias[ii*17 + jj], ebuf[(long)e*8 + h]);
    }
    __syncthreads();
    for (int jj=0; jj<16; jj++){
      int j = c*16 + jj;
      const float* kk = Ks + j*16;
      float s = bias[i*17 + jj];
      #pragma unroll
      for (int d=0; d<16; d++) s += qr[d]*kk[d];
      float mn = fmaxf(m, s);
      float p = __expf(s - mn);
      float corr = __expf(m - mn);
      l = l*corr + p;
      const float* vv = Vs + j*16;
      #pragma unroll
      for (int d=0; d<16; d++) o[d] = o[d]*corr + p*vv[d];
      m = mn;
    }
  }
  float inv = 1.f/l;
  #pragma unroll
  for (int d=0; d<16; d++)
    hattn_pre[(long)(nbase+i)*128 + h*16 + d] = f2b(o[d]*inv);
}

// ---------------- residual add + LayerNorm ----------------
// is_final: branch output dtype on detected input dtype (fp32 in -> fp32 out)
__global__ __launch_bounds__(256) void combine_ln_k(const bf16* __restrict__ a,
    const bf16* __restrict__ b, const bf16* __restrict__ c3,
    const float* __restrict__ g, const float* __restrict__ bb,
    void* __restrict__ outp, const int* __restrict__ flag, int is_final){
  const int tid = threadIdx.x;
  const int lane = tid & 63;
  const long row = (long)blockIdx.x*4 + (tid>>6);
  const long base = row*128;
  float v0 = b2f(a[base+lane])    + b2f(b[base+lane]);
  float v1 = b2f(a[base+lane+64]) + b2f(b[base+lane+64]);
  if (c3){ v0 += b2f(c3[base+lane]); v1 += b2f(c3[base+lane+64]); }
  float s = v0 + v1;
  #pragma unroll
  for (int o=1; o<64; o<<=1) s += __shfl_xor(s, o);
  float mean = s * (1.f/128.f);
  float d0 = v0 - mean, d1 = v1 - mean;
  float q = d0*d0 + d1*d1;
  #pragma unroll
  for (int o=1; o<64; o<<=1) q += __shfl_xor(q, o);
  float r = rsqrtf(q*(1.f/128.f) + 1e-5f);
  float r0v = d0*r*g[lane]    + bb[lane];
  float r1v = d1*r*g[lane+64] + bb[lane+64];
  if (is_final && (*flag)){
    float* o = (float*)outp;
    o[base+lane]    = r0v;
    o[base+lane+64] = r1v;
  } else {
    bf16* o = (bf16*)outp;
    o[base+lane]    = f2b(r0v);
    o[base+lane+64] = f2b(r1v);
  }
}

// =====================================================================================
extern "C" void kernel_launch(void* const* d_in, const int* in_sizes, int n_in,
                              void* d_out, int out_size, void* d_ws, size_t ws_size,
                              hipStream_t stream){
  const void* x_raw   = d_in[0];
  const void* ea_raw  = d_in[1];
  const int*  ei      = (const int*)d_in[25];
  const int* srcA = ei;
  const int* dstA = ei + kE;

  char* ws = (char*)d_ws;
  size_t off = 0;
  auto alloc = [&](size_t bytes)->void*{
    void* p = ws + off;
    off = (off + bytes + 255) & ~(size_t)255;
    return p;
  };
  int*   flag    = (int*)alloc(4);
  bf16*  x_bf    = (bf16*)alloc((size_t)kN*128*2);
  bf16*  ea_bf   = (bf16*)alloc((size_t)kE*32*2);
  float* Wsrc_f  = (float*)alloc(16384*4);
  float* Wdst_f  = (float*)alloc(16384*4);
  float* Wedge_f = (float*)alloc(4096*4);
  float* att_f   = (float*)alloc(128*4);
  float* gatb_f  = (float*)alloc(128*4);
  float* Wq_f    = (float*)alloc(16384*4);
  float* bq_f    = (float*)alloc(128*4);
  float* Wk_f    = (float*)alloc(16384*4);
  float* bk_f    = (float*)alloc(128*4);
  float* Wv_f    = (float*)alloc(16384*4);
  float* bv_f    = (float*)alloc(128*4);
  float* Wo_f    = (float*)alloc(16384*4);
  float* bo_f    = (float*)alloc(128*4);
  float* We_f    = (float*)alloc(256*4);
  float* be_f    = (float*)alloc(8*4);
  float* ln1g_f  = (float*)alloc(128*4);
  float* ln1b_f  = (float*)alloc(128*4);
  float* W1_f    = (float*)alloc(32768*4);
  float* b1_f    = (float*)alloc(256*4);
  float* W2_f    = (float*)alloc(32768*4);
  float* b2_f    = (float*)alloc(128*4);
  float* ln2g_f  = (float*)alloc(128*4);
  float* ln2b_f  = (float*)alloc(128*4);
  bf16* xs        = (bf16*)alloc((size_t)kN*128*2);
  bf16* xd        = (bf16*)alloc((size_t)kN*128*2);
  bf16* qb        = (bf16*)alloc((size_t)kN*128*2);
  bf16* kbuf      = (bf16*)alloc((size_t)kN*128*2);
  bf16* vbuf      = (bf16*)alloc((size_t)kN*128*2);
  float* alpha    = (float*)alloc((size_t)kE*4*4);
  float* ebuf     = (float*)alloc((size_t)kE*8*4);
  int* cnt        = (int*)alloc((size_t)2*kN*4);
  int* cursor     = cnt + kN;
  int* rowptr     = (int*)alloc((size_t)(kN+1)*4);
  int* eidx       = (int*)alloc((size_t)kE*4);
  bf16* h_local   = (bf16*)alloc((size_t)kN*128*2);
  bf16* hattn_pre = (bf16*)alloc((size_t)kN*128*2);
  bf16* h_attn    = (bf16*)alloc((size_t)kN*128*2);
  bf16* hbuf      = (bf16*)alloc((size_t)kN*128*2);
  bf16* tbuf      = (bf16*)alloc((size_t)kN*256*2);
  bf16* f2buf     = (bf16*)alloc((size_t)kN*128*2);
  (void)ws_size; (void)in_sizes; (void)n_in; (void)out_size;

  dim3 b256(256);

  // --- dtype detection + canonical import ---
  detect_k<<<1, b256, 0, stream>>>(x_raw, flag);

  ImpArgs ia;
  const void* srcs[25] = {x_raw, ea_raw, d_in[2], d_in[3], d_in[4], d_in[5], d_in[6],
                          d_in[7], d_in[8], d_in[9], d_in[10], d_in[11], d_in[12],
                          d_in[13], d_in[14], d_in[15], d_in[16], d_in[17], d_in[18],
                          d_in[19], d_in[20], d_in[21], d_in[22], d_in[23], d_in[24]};
  void* dsts[25] = {x_bf, ea_bf, Wsrc_f, Wdst_f, Wedge_f, att_f, gatb_f,
                    Wq_f, bq_f, Wk_f, bk_f, Wv_f, bv_f,
                    Wo_f, bo_f, We_f, be_f, ln1g_f, ln1b_f,
                    W1_f, b1_f, W2_f, b2_f, ln2g_f, ln2b_f};
  int ns[25] = {kN*128, kE*32, 16384, 16384, 4096, 128, 128,
                16384, 128, 16384, 128, 16384, 128,
                16384, 128, 256, 8, 128, 128,
                32768, 256, 32768, 128, 128, 128};
  int isbf[25] = {1,1, 0,0,0,0,0, 0,0,0,0,0,0, 0,0,0,0,0,0, 0,0,0,0,0,0};
  for (int i=0;i<25;i++){ ia.e[i].src=srcs[i]; ia.e[i].dst=dsts[i]; ia.e[i].n=ns[i]; ia.e[i].dst_bf16=isbf[i]; }
  import_k<<<dim3(512,25), b256, 0, stream>>>(ia, flag);

  // --- node projections ---
  gemm_k<128,0><<<kN/32, b256, 0, stream>>>(x_bf, Wsrc_f, nullptr, xs, 128);
  gemm_k<128,0><<<kN/32, b256, 0, stream>>>(x_bf, Wdst_f, nullptr, xd, 128);
  gemm_k<128,1><<<kN/32, b256, 0, stream>>>(x_bf, Wq_f, bq_f, qb, 128);
  gemm_k<128,1><<<kN/32, b256, 0, stream>>>(x_bf, Wk_f, bk_f, kbuf, 128);
  gemm_k<128,1><<<kN/32, b256, 0, stream>>>(x_bf, Wv_f, bv_f, vbuf, 128);

  // --- per-edge logits + attn edge bias ---
  edge_k<<<kE/2, b256, 0, stream>>>(ea_bf, srcA, dstA, xs, xd,
                                    Wedge_f, We_f, att_f, be_f, alpha, ebuf);

  // --- CSR by dst ---
  hipMemsetAsync(cnt, 0, (size_t)2*kN*4, stream);
  hist_k<<<kE/256, b256, 0, stream>>>(dstA, cnt);
  scan_k<<<1, 1024, 0, stream>>>(cnt, rowptr);
  scatter_k<<<kE/256, b256, 0, stream>>>(dstA, rowptr, cursor, eidx);

  // --- GAT aggregate ---
  gat_agg_k<<<kN, dim3(128), 0, stream>>>(alpha, rowptr, eidx, srcA, xs, gatb_f, h_local);

  // --- dense per-graph attention ---
  attn_k<<<kG*kHA, b256, 0, stream>>>(qb, kbuf, vbuf, ebuf, rowptr, eidx, srcA, dstA, hattn_pre);
  gemm_k<128,1><<<kN/32, b256, 0, stream>>>(hattn_pre, Wo_f, bo_f, h_attn, 128);

  // --- combine + LN1 ---
  combine_ln_k<<<kN/4, b256, 0, stream>>>(x_bf, h_local, h_attn, ln1g_f, ln1b_f, hbuf, flag, 0);

  // --- FFN ---
  gemm_k<256,2><<<kN/32, b256, 0, stream>>>(hbuf, W1_f, b1_f, tbuf, 128);
  gemm_k<128,1><<<kN/32, b256, 0, stream>>>(tbuf, W2_f, b2_f, f2buf, 256);

  // --- final residual + LN2 -> out ---
  combine_ln_k<<<kN/4, b256, 0, stream>>>(hbuf, f2buf, nullptr, ln2g_f, ln2b_f, d_out, flag, 1);
}

// Round 3
// 572.440 us; speedup vs baseline: 1.3345x; 1.3345x over previous
//
#include <hip/hip_runtime.h>
#include <hip/hip_bf16.h>

typedef __hip_bfloat16 bf16;
typedef __hip_bfloat162 bf162;
typedef __attribute__((ext_vector_type(8))) short short8;
typedef __attribute__((ext_vector_type(4))) float f32x4;

constexpr int kN   = 32768;   // nodes
constexpr int kG   = 128;     // graphs
constexpr int kE   = 262144;  // edges
constexpr int kHA  = 8;       // global attn heads

__device__ __forceinline__ float b2f(bf16 v){ return __bfloat162float(v); }
__device__ __forceinline__ bf16  f2b(float v){ return __float2bfloat16(v); }
__device__ __forceinline__ float tanh_fast(float x){
  float e = __expf(2.f*x);
  return 1.f - 2.f/(e+1.f);
}

// ---------------- input dtype detection (bf16 vs fp32 device buffers) ----------------
__global__ void detect_k(const void* xraw, int* flag){
  const bf16* p = (const bf16*)xraw;
  int good = 0;
  for (int i = threadIdx.x; i < 4096; i += 256){
    float v = fabsf(b2f(p[i]));
    if (v > 0.0009765625f && v < 16.f) good++;
  }
  __shared__ int s[256];
  s[threadIdx.x] = good;
  __syncthreads();
  for (int d = 128; d; d >>= 1){
    if (threadIdx.x < d) s[threadIdx.x] += s[threadIdx.x + d];
    __syncthreads();
  }
  if (threadIdx.x == 0) *flag = (s[0] < 3500) ? 1 : 0;
}

// ---------------- import: convert all float inputs to canonical ws buffers ---------
struct ImpEnt { const void* src; void* dst; int n; int dst_bf16; };
struct ImpArgs { ImpEnt e[25]; };
__global__ __launch_bounds__(256) void import_k(ImpArgs a, const int* __restrict__ flag){
  ImpEnt en = a.e[blockIdx.y];
  const bool f32 = (*flag != 0);
  for (int i = blockIdx.x*256 + threadIdx.x; i < en.n; i += gridDim.x*256){
    float v = f32 ? ((const float*)en.src)[i] : b2f(((const bf16*)en.src)[i]);
    if (en.dst_bf16) ((bf16*)en.dst)[i] = f2b(v);
    else             ((float*)en.dst)[i] = v;
  }
}

// ---------------- weight repack: fp32 [K][DOUT] -> bf16 MFMA-B fragment layout -------
// dst idx = ((tile*64)+lane)*8+j ; tile = ks*ncb+cb ; k = ks*32+(lane>>4)*8+j ;
// c = cb*16+(lane&15)
__global__ __launch_bounds__(256) void repack5_k(const float* __restrict__ W0,
    const float* __restrict__ W1p, const float* __restrict__ W2p,
    const float* __restrict__ W3p, const float* __restrict__ W4p,
    bf16* __restrict__ dst){
  int idx = blockIdx.x*256 + threadIdx.x;           // < 5*16384
  const float* Ws[5] = {W0, W1p, W2p, W3p, W4p};
  int o = idx >> 14;
  int rem = idx & 16383;
  int j = rem & 7, l = (rem >> 3) & 63, t = rem >> 9;   // t = ks*8+cb
  int ks = t >> 3, cb = t & 7;
  int k = ks*32 + (l>>4)*8 + j;
  int c = cb*16 + (l&15);
  dst[idx] = f2b(Ws[o][k*128 + c]);
}

struct RepEnt { const float* src; bf16* dst; int total; int ncb_log; int dout; };
__global__ __launch_bounds__(256) void repack_k(RepEnt e0, RepEnt e1, RepEnt e2){
  RepEnt en = (blockIdx.y == 0) ? e0 : (blockIdx.y == 1) ? e1 : e2;
  int idx = blockIdx.x*256 + threadIdx.x;
  if (idx >= en.total) return;
  int j = idx & 7, l = (idx >> 3) & 63, t = idx >> 9;
  int ncbm = (1 << en.ncb_log) - 1;
  int ks = t >> en.ncb_log, cb = t & ncbm;
  int k = ks*32 + (l>>4)*8 + j;
  int c = cb*16 + (l&15);
  en.dst[idx] = f2b(en.src[k*en.dout + c]);
}

// ---------------- fused 5-way projection GEMM: x @ {Wsrc,Wdst,Wq,Wk,Wv} -------------
// block = 4 waves; each wave owns 16 rows; A-frags kept in regs across the 5 outputs.
__global__ __launch_bounds__(256) void gemm5_k(const bf16* __restrict__ A,
    const bf16* __restrict__ Wrep,      // [5][4ks][8cb][64][8]
    const float* __restrict__ bias5,    // 640 (zeros for xs/xd)
    bf16* __restrict__ proj5){          // [5][kN][128]
  const int tid = threadIdx.x;
  const int wid = tid >> 6, l = tid & 63;
  const long r0 = (long)blockIdx.x*64 + wid*16;
  const short* Arow = (const short*)(A + (r0 + (l&15))*128);
  short8 af[4];
  #pragma unroll
  for (int ks=0; ks<4; ks++)
    af[ks] = *(const short8*)(Arow + ks*32 + (l>>4)*8);
  const short8* Wp = (const short8*)Wrep;
  const int cc = l & 15, rr = (l >> 4) * 4;
  #pragma unroll 1
  for (int o=0; o<5; o++){
    f32x4 acc[8];
    #pragma unroll
    for (int cb=0; cb<8; cb++) acc[cb] = (f32x4){0.f,0.f,0.f,0.f};
    #pragma unroll
    for (int ks=0; ks<4; ks++){
      #pragma unroll
      for (int cb=0; cb<8; cb++){
        short8 bf = Wp[(o*32 + ks*8 + cb)*64 + l];
        acc[cb] = __builtin_amdgcn_mfma_f32_16x16x32_bf16(af[ks], bf, acc[cb], 0,0,0);
      }
    }
    bf16* outb = proj5 + (long)o*kN*128;
    #pragma unroll
    for (int cb=0; cb<8; cb++){
      float bb = bias5[o*128 + cb*16 + cc];
      #pragma unroll
      for (int r=0; r<4; r++){
        long row = r0 + rr + r;
        outb[row*128 + cb*16 + cc] = f2b(acc[cb][r] + bb);
      }
    }
  }
}

// ---------------- generic MFMA GEMM ----------------
// EPI: 1 +bias, 2 +bias+gelu(exact)
template<int DIN, int DOUT, int EPI>
__global__ __launch_bounds__(256) void gemm_mfma_k(const bf16* __restrict__ A,
    const bf16* __restrict__ Wrep, const float* __restrict__ bias,
    bf16* __restrict__ C){
  constexpr int KS = DIN/32, NCB = DOUT/16;
  const int tid = threadIdx.x;
  const int wid = tid >> 6, l = tid & 63;
  const long r0 = (long)blockIdx.x*64 + wid*16;
  const short* Arow = (const short*)(A + (r0 + (l&15))*(long)DIN);
  short8 af[KS];
  #pragma unroll
  for (int ks=0; ks<KS; ks++)
    af[ks] = *(const short8*)(Arow + ks*32 + (l>>4)*8);
  f32x4 acc[NCB];
  #pragma unroll
  for (int cb=0; cb<NCB; cb++) acc[cb] = (f32x4){0.f,0.f,0.f,0.f};
  const short8* Wp = (const short8*)Wrep;
  #pragma unroll
  for (int ks=0; ks<KS; ks++){
    #pragma unroll
    for (int cb=0; cb<NCB; cb++){
      short8 bf = Wp[(ks*NCB + cb)*64 + l];
      acc[cb] = __builtin_amdgcn_mfma_f32_16x16x32_bf16(af[ks], bf, acc[cb], 0,0,0);
    }
  }
  const int cc = l & 15, rr = (l >> 4) * 4;
  #pragma unroll
  for (int cb=0; cb<NCB; cb++){
    float bb = bias[cb*16 + cc];
    #pragma unroll
    for (int r=0; r<4; r++){
      long row = r0 + rr + r;
      float v = acc[cb][r] + bb;
      if (EPI == 2) v = 0.5f*v*(1.f + erff(v*0.70710678118654752f));
      C[row*DOUT + cb*16 + cc] = f2b(v);
    }
  }
}

// ---------------- per-edge: alpha[E,4] + eb[E,8], 64 edges per block ----------------
__global__ __launch_bounds__(256) void edge2_k(const bf16* __restrict__ ea,
    const int* __restrict__ srcA, const int* __restrict__ dstA,
    const bf16* __restrict__ xs, const bf16* __restrict__ xd,
    const float* __restrict__ Wedge_f, const float* __restrict__ We_f,
    const float* __restrict__ att_f, const float* __restrict__ be_f,
    float* __restrict__ alpha, float* __restrict__ ebuf){
  __shared__ float sW[32*128];      // 16 KB
  __shared__ float sWe[32*8];
  __shared__ float sAtt[128];
  __shared__ float sEa[64][32];     // 8 KB
  __shared__ int   sSrc[64], sDst[64];
  __shared__ float sAlpha[64][4];
  const int tid = threadIdx.x;
  const long e0 = (long)blockIdx.x * 64;
  for (int i = tid; i < 4096; i += 256) sW[i] = Wedge_f[i];
  if (tid < 256) sWe[tid] = We_f[tid];
  if (tid < 128) sAtt[tid] = att_f[tid];
  for (int i = tid; i < 64*32; i += 256) sEa[i>>5][i&31] = b2f(ea[e0*32 + i]);
  if (tid < 64){ sSrc[tid] = srcA[e0+tid]; sDst[tid] = dstA[e0+tid]; }
  __syncthreads();
  const int half = tid >> 7;
  const int ch = tid & 127;
  const int h = ch >> 5;
  const float attv = sAtt[ch];
  for (int i = 0; i < 32; i++){
    int le = half*32 + i;
    int s = sSrc[le], dd = sDst[le];
    float ef = 0.f;
    const float* earow = sEa[le];
    #pragma unroll 8
    for (int d = 0; d < 32; d++) ef += earow[d] * sW[d*128 + ch];
    float xv = b2f(xs[(long)s*128+ch]) + b2f(xd[(long)dd*128+ch]) + ef;
    float contrib = tanh_fast(xv) * attv;
    #pragma unroll
    for (int o=16; o; o>>=1) contrib += __shfl_xor(contrib, o, 32);
    if ((ch&31) == 0) sAlpha[le][h] = contrib;
  }
  // eb: 64 edges x 8 heads = 512 values, 2 per thread
  float myeb[2];
  #pragma unroll
  for (int r = 0; r < 2; r++){
    int idx = tid*2 + r;
    int le = idx >> 3, hh = idx & 7;
    float v = be_f[hh];
    const float* earow = sEa[le];
    #pragma unroll 8
    for (int d=0; d<32; d++) v += earow[d]*sWe[d*8+hh];
    myeb[r] = v;
  }
  __syncthreads();
  if (tid < 256) alpha[e0*4 + tid] = sAlpha[tid>>2][tid&3];
  *((float2*)ebuf + e0*4 + tid) = *(float2*)myeb;
}

// ---------------- CSR build ----------------
__global__ void hist_k(const int* __restrict__ dstA, int* __restrict__ cnt){
  int e = blockIdx.x*256 + threadIdx.x;
  if (e < kE) atomicAdd(&cnt[dstA[e]], 1);
}

__global__ __launch_bounds__(1024) void scan_k(const int* __restrict__ cnt, int* __restrict__ rowptr){
  __shared__ int part[1024];
  const int t = threadIdx.x;
  const int base = t*32;
  int s = 0;
  #pragma unroll
  for (int i=0;i<32;i++) s += cnt[base+i];
  part[t] = s;
  __syncthreads();
  for (int d=1; d<1024; d<<=1){
    int v = (t>=d) ? part[t-d] : 0;
    __syncthreads();
    part[t] += v;
    __syncthreads();
  }
  int run = (t==0) ? 0 : part[t-1];
  for (int i=0;i<32;i++){ rowptr[base+i] = run; run += cnt[base+i]; }
  if (t == 1023) rowptr[kN] = run;
}

__global__ void scatter_k(const int* __restrict__ dstA, const int* __restrict__ rowptr,
                          int* __restrict__ cursor, int* __restrict__ eidx){
  int e = blockIdx.x*256 + threadIdx.x;
  if (e < kE){
    int d = dstA[e];
    int p = atomicAdd(&cursor[d], 1);
    eidx[rowptr[d]+p] = e;
  }
}

// ---------------- GAT aggregate (2-pass) ----------------
__global__ __launch_bounds__(128) void gat_agg_k(const float* __restrict__ alpha,
    const int* __restrict__ rowptr, const int* __restrict__ eidx,
    const int* __restrict__ srcA, const bf16* __restrict__ xs,
    const float* __restrict__ gatb_f, bf16* __restrict__ h_local){
  const int v = blockIdx.x;
  const int tid = threadIdx.x;
  const int h = tid>>5;
  const int beg = rowptr[v], end = rowptr[v+1];
  const int deg = end - beg;
  float out = 0.f;
  if (deg > 0){
    float m = -1e30f;
    for (int i=0;i<deg;i++) m = fmaxf(m, alpha[(long)eidx[beg+i]*4 + h]);
    float den = 0.f;
    for (int i=0;i<deg;i++){
      int e = eidx[beg+i];
      float w = __expf(alpha[(long)e*4 + h] - m);
      den += w;
      out += w * b2f(xs[(long)srcA[e]*128 + tid]);
    }
    out /= (den + 1e-16f);
  }
  h_local[(long)v*128 + tid] = f2b(out + gatb_f[tid]);
}

// ---------------- dense per-graph attention with sparse edge bias --------------------
__global__ __launch_bounds__(256) void attn_k(const bf16* __restrict__ qb,
    const bf16* __restrict__ kb, const bf16* __restrict__ vb,
    const float* __restrict__ ebuf, const int* __restrict__ rowptr,
    const int* __restrict__ eidx, const int* __restrict__ srcA,
    const int* __restrict__ dstA, bf16* __restrict__ hattn_pre){
  __shared__ float Ks[256*16];
  __shared__ float Vs[256*16];
  __shared__ float bias[256*17];
  const int g = blockIdx.x >> 3, h = blockIdx.x & 7;
  const int tid = threadIdx.x;
  const int nbase = g*256;
  for (int idx = tid; idx < 4096; idx += 256){
    int row = idx>>4, d = idx&15;
    long gaddr = (long)(nbase+row)*128 + h*16 + d;
    Ks[idx] = b2f(kb[gaddr]);
    Vs[idx] = b2f(vb[gaddr]);
  }
  const int i = tid;
  float qr[16];
  #pragma unroll
  for (int d=0; d<16; d++) qr[d] = b2f(qb[(long)(nbase+i)*128 + h*16 + d]) * 0.25f;
  float m = -1e30f, l = 0.f, o[16];
  #pragma unroll
  for (int d=0; d<16; d++) o[d] = 0.f;
  for (int c=0; c<16; c++){
    __syncthreads();
    for (int idx = tid; idx < 256*17; idx += 256) bias[idx] = 0.f;
    __syncthreads();
    int rb = rowptr[nbase + c*16], re = rowptr[nbase + c*16 + 16];
    for (int t = rb + tid; t < re; t += 256){
      int e = eidx[t];
      int ii = srcA[e] - nbase;
      int jj = dstA[e] - (nbase + c*16);
      if ((unsigned)ii < 256u) atomicAdd(&bias[ii*17 + jj], ebuf[(long)e*8 + h]);
    }
    __syncthreads();
    for (int jj=0; jj<16; jj++){
      int j = c*16 + jj;
      const float* kk = Ks + j*16;
      float s = bias[i*17 + jj];
      #pragma unroll
      for (int d=0; d<16; d++) s += qr[d]*kk[d];
      float mn = fmaxf(m, s);
      float p = __expf(s - mn);
      float corr = __expf(m - mn);
      l = l*corr + p;
      const float* vv = Vs + j*16;
      #pragma unroll
      for (int d=0; d<16; d++) o[d] = o[d]*corr + p*vv[d];
      m = mn;
    }
  }
  float inv = 1.f/l;
  #pragma unroll
  for (int d=0; d<16; d++)
    hattn_pre[(long)(nbase+i)*128 + h*16 + d] = f2b(o[d]*inv);
}

// ---------------- residual add + LayerNorm ----------------
__global__ __launch_bounds__(256) void combine_ln_k(const bf16* __restrict__ a,
    const bf16* __restrict__ b, const bf16* __restrict__ c3,
    const float* __restrict__ g, const float* __restrict__ bb,
    void* __restrict__ outp, const int* __restrict__ flag, int is_final){
  const int tid = threadIdx.x;
  const int lane = tid & 63;
  const long row = (long)blockIdx.x*4 + (tid>>6);
  const long base = row*128;
  float v0 = b2f(a[base+lane])    + b2f(b[base+lane]);
  float v1 = b2f(a[base+lane+64]) + b2f(b[base+lane+64]);
  if (c3){ v0 += b2f(c3[base+lane]); v1 += b2f(c3[base+lane+64]); }
  float s = v0 + v1;
  #pragma unroll
  for (int o=1; o<64; o<<=1) s += __shfl_xor(s, o);
  float mean = s * (1.f/128.f);
  float d0 = v0 - mean, d1 = v1 - mean;
  float q = d0*d0 + d1*d1;
  #pragma unroll
  for (int o=1; o<64; o<<=1) q += __shfl_xor(q, o);
  float r = rsqrtf(q*(1.f/128.f) + 1e-5f);
  float r0v = d0*r*g[lane]    + bb[lane];
  float r1v = d1*r*g[lane+64] + bb[lane+64];
  if (is_final && (*flag)){
    float* o = (float*)outp;
    o[base+lane]    = r0v;
    o[base+lane+64] = r1v;
  } else {
    bf16* o = (bf16*)outp;
    o[base+lane]    = f2b(r0v);
    o[base+lane+64] = f2b(r1v);
  }
}

// =====================================================================================
extern "C" void kernel_launch(void* const* d_in, const int* in_sizes, int n_in,
                              void* d_out, int out_size, void* d_ws, size_t ws_size,
                              hipStream_t stream){
  const void* x_raw   = d_in[0];
  const void* ea_raw  = d_in[1];
  const int*  ei      = (const int*)d_in[25];
  const int* srcA = ei;
  const int* dstA = ei + kE;

  char* ws = (char*)d_ws;
  size_t off = 0;
  auto alloc = [&](size_t bytes)->void*{
    void* p = ws + off;
    off = (off + bytes + 255) & ~(size_t)255;
    return p;
  };
  int*   flag    = (int*)alloc(4);
  bf16*  x_bf    = (bf16*)alloc((size_t)kN*128*2);
  bf16*  ea_bf   = (bf16*)alloc((size_t)kE*32*2);
  float* Wsrc_f  = (float*)alloc(16384*4);
  float* Wdst_f  = (float*)alloc(16384*4);
  float* Wedge_f = (float*)alloc(4096*4);
  float* att_f   = (float*)alloc(128*4);
  float* gatb_f  = (float*)alloc(128*4);
  float* Wq_f    = (float*)alloc(16384*4);
  float* Wk_f    = (float*)alloc(16384*4);
  float* Wv_f    = (float*)alloc(16384*4);
  float* Wo_f    = (float*)alloc(16384*4);
  float* bo_f    = (float*)alloc(128*4);
  float* We_f    = (float*)alloc(256*4);
  float* be_f    = (float*)alloc(8*4);
  float* ln1g_f  = (float*)alloc(128*4);
  float* ln1b_f  = (float*)alloc(128*4);
  float* W1_f    = (float*)alloc(32768*4);
  float* b1_f    = (float*)alloc(256*4);
  float* W2_f    = (float*)alloc(32768*4);
  float* b2_f    = (float*)alloc(128*4);
  float* ln2g_f  = (float*)alloc(128*4);
  float* ln2b_f  = (float*)alloc(128*4);
  float* bias5   = (float*)alloc(640*4);     // [xs0|xd0|bq|bk|bv]
  bf16*  Wrep5   = (bf16*)alloc((size_t)5*16384*2);
  bf16*  WoR     = (bf16*)alloc((size_t)16384*2);
  bf16*  W1R     = (bf16*)alloc((size_t)32768*2);
  bf16*  W2R     = (bf16*)alloc((size_t)32768*2);
  bf16*  proj5   = (bf16*)alloc((size_t)5*kN*128*2);
  bf16* xs   = proj5;
  bf16* xd   = proj5 + (size_t)kN*128;
  bf16* qb   = proj5 + (size_t)2*kN*128;
  bf16* kbuf = proj5 + (size_t)3*kN*128;
  bf16* vbuf = proj5 + (size_t)4*kN*128;
  float* alpha    = (float*)alloc((size_t)kE*4*4);
  float* ebuf     = (float*)alloc((size_t)kE*8*4);
  int* cnt        = (int*)alloc((size_t)2*kN*4);
  int* cursor     = cnt + kN;
  int* rowptr     = (int*)alloc((size_t)(kN+1)*4);
  int* eidx       = (int*)alloc((size_t)kE*4);
  bf16* h_local   = (bf16*)alloc((size_t)kN*128*2);
  bf16* hattn_pre = (bf16*)alloc((size_t)kN*128*2);
  bf16* h_attn    = (bf16*)alloc((size_t)kN*128*2);
  bf16* hbuf      = (bf16*)alloc((size_t)kN*128*2);
  bf16* tbuf      = (bf16*)alloc((size_t)kN*256*2);
  bf16* f2buf     = (bf16*)alloc((size_t)kN*128*2);
  (void)ws_size; (void)in_sizes; (void)n_in; (void)out_size;

  dim3 b256(256);

  // --- dtype detection + canonical import ---
  detect_k<<<1, b256, 0, stream>>>(x_raw, flag);
  hipMemsetAsync(bias5, 0, 256*4, stream);   // xs/xd have no bias

  ImpArgs ia;
  const void* srcs[25] = {x_raw, ea_raw, d_in[2], d_in[3], d_in[4], d_in[5], d_in[6],
                          d_in[7], d_in[8], d_in[9], d_in[10], d_in[11], d_in[12],
                          d_in[13], d_in[14], d_in[15], d_in[16], d_in[17], d_in[18],
                          d_in[19], d_in[20], d_in[21], d_in[22], d_in[23], d_in[24]};
  void* dsts[25] = {x_bf, ea_bf, Wsrc_f, Wdst_f, Wedge_f, att_f, gatb_f,
                    Wq_f, bias5+256, Wk_f, bias5+384, Wv_f, bias5+512,
                    Wo_f, bo_f, We_f, be_f, ln1g_f, ln1b_f,
                    W1_f, b1_f, W2_f, b2_f, ln2g_f, ln2b_f};
  int ns[25] = {kN*128, kE*32, 16384, 16384, 4096, 128, 128,
                16384, 128, 16384, 128, 16384, 128,
                16384, 128, 256, 8, 128, 128,
                32768, 256, 32768, 128, 128, 128};
  int isbf[25] = {1,1, 0,0,0,0,0, 0,0,0,0,0,0, 0,0,0,0,0,0, 0,0,0,0,0,0};
  for (int i=0;i<25;i++){ ia.e[i].src=srcs[i]; ia.e[i].dst=dsts[i]; ia.e[i].n=ns[i]; ia.e[i].dst_bf16=isbf[i]; }
  import_k<<<dim3(512,25), b256, 0, stream>>>(ia, flag);

  // --- weight repack to MFMA fragment layout ---
  repack5_k<<<(5*16384)/256, b256, 0, stream>>>(Wsrc_f, Wdst_f, Wq_f, Wk_f, Wv_f, Wrep5);
  RepEnt ro{Wo_f, WoR, 16384, 3, 128};
  RepEnt r1{W1_f, W1R, 32768, 4, 256};
  RepEnt r2{W2_f, W2R, 32768, 3, 128};
  repack_k<<<dim3(128,3), b256, 0, stream>>>(ro, r1, r2);

  // --- fused 5-way node projection ---
  gemm5_k<<<kN/64, b256, 0, stream>>>(x_bf, Wrep5, bias5, proj5);

  // --- per-edge logits + attn edge bias ---
  edge2_k<<<kE/64, b256, 0, stream>>>(ea_bf, srcA, dstA, xs, xd,
                                      Wedge_f, We_f, att_f, be_f, alpha, ebuf);

  // --- CSR by dst ---
  hipMemsetAsync(cnt, 0, (size_t)2*kN*4, stream);
  hist_k<<<kE/256, b256, 0, stream>>>(dstA, cnt);
  scan_k<<<1, 1024, 0, stream>>>(cnt, rowptr);
  scatter_k<<<kE/256, b256, 0, stream>>>(dstA, rowptr, cursor, eidx);

  // --- GAT aggregate ---
  gat_agg_k<<<kN, dim3(128), 0, stream>>>(alpha, rowptr, eidx, srcA, xs, gatb_f, h_local);

  // --- dense per-graph attention ---
  attn_k<<<kG*kHA, b256, 0, stream>>>(qb, kbuf, vbuf, ebuf, rowptr, eidx, srcA, dstA, hattn_pre);
  gemm_mfma_k<128,128,1><<<kN/64, b256, 0, stream>>>(hattn_pre, WoR, bo_f, h_attn);

  // --- combine + LN1 ---
  combine_ln_k<<<kN/4, b256, 0, stream>>>(x_bf, h_local, h_attn, ln1g_f, ln1b_f, hbuf, flag, 0);

  // --- FFN ---
  gemm_mfma_k<128,256,2><<<kN/64, b256, 0, stream>>>(hbuf, W1R, b1_f, tbuf);
  gemm_mfma_k<256,128,1><<<kN/64, b256, 0, stream>>>(tbuf, W2R, b2_f, f2buf);

  // --- final residual + LN2 -> out ---
  combine_ln_k<<<kN/4, b256, 0, stream>>>(hbuf, f2buf, nullptr, ln2g_f, ln2b_f, d_out, flag, 1);
}

// Round 4
// 461.353 us; speedup vs baseline: 1.6559x; 1.2408x over previous
//
#include <hip/hip_runtime.h>
#include <hip/hip_bf16.h>

typedef __hip_bfloat16 bf16;
typedef __hip_bfloat162 bf162;
typedef __attribute__((ext_vector_type(8))) short short8;
typedef __attribute__((ext_vector_type(4))) float f32x4;
typedef __attribute__((ext_vector_type(16))) float f32x16;

constexpr int kN   = 32768;   // nodes
constexpr int kG   = 128;     // graphs
constexpr int kE   = 262144;  // edges
constexpr int kHA  = 8;       // global attn heads

__device__ __forceinline__ float b2f(bf16 v){ return __bfloat162float(v); }
__device__ __forceinline__ bf16  f2b(float v){ return __float2bfloat16(v); }
__device__ __forceinline__ float tanh_fast(float x){
  float e = __expf(2.f*x);
  return 1.f - 2.f/(e+1.f);
}
__device__ __forceinline__ unsigned int cvtpk_bf16(float lo, float hi){
  unsigned int r;
  asm volatile("v_cvt_pk_bf16_f32 %0, %1, %2" : "=v"(r) : "v"(lo), "v"(hi));
  return r;
}
__device__ __forceinline__ void plane_swap(unsigned int &a, unsigned int &b){
  asm volatile("v_permlane32_swap_b32 %0, %1" : "+v"(a), "+v"(b));
}

// ---------------- input dtype detection (bf16 vs fp32 device buffers) ----------------
__global__ void detect_k(const void* xraw, int* flag){
  const bf16* p = (const bf16*)xraw;
  int good = 0;
  for (int i = threadIdx.x; i < 4096; i += 256){
    float v = fabsf(b2f(p[i]));
    if (v > 0.0009765625f && v < 16.f) good++;
  }
  __shared__ int s[256];
  s[threadIdx.x] = good;
  __syncthreads();
  for (int d = 128; d; d >>= 1){
    if (threadIdx.x < d) s[threadIdx.x] += s[threadIdx.x + d];
    __syncthreads();
  }
  if (threadIdx.x == 0) *flag = (s[0] < 3500) ? 1 : 0;
}

// ---------------- import ----------------
struct ImpEnt { const void* src; void* dst; int n; int dst_bf16; };
struct ImpArgs { ImpEnt e[25]; };
__global__ __launch_bounds__(256) void import_k(ImpArgs a, const int* __restrict__ flag){
  ImpEnt en = a.e[blockIdx.y];
  const bool f32 = (*flag != 0);
  for (int i = blockIdx.x*256 + threadIdx.x; i < en.n; i += gridDim.x*256){
    float v = f32 ? ((const float*)en.src)[i] : b2f(((const bf16*)en.src)[i]);
    if (en.dst_bf16) ((bf16*)en.dst)[i] = f2b(v);
    else             ((float*)en.dst)[i] = v;
  }
}

// ---------------- weight repack to MFMA-B fragment layout ----------------
__global__ __launch_bounds__(256) void repack5_k(const float* __restrict__ W0,
    const float* __restrict__ W1p, const float* __restrict__ W2p,
    const float* __restrict__ W3p, const float* __restrict__ W4p,
    bf16* __restrict__ dst){
  int idx = blockIdx.x*256 + threadIdx.x;
  const float* Ws[5] = {W0, W1p, W2p, W3p, W4p};
  int o = idx >> 14;
  int rem = idx & 16383;
  int j = rem & 7, l = (rem >> 3) & 63, t = rem >> 9;
  int ks = t >> 3, cb = t & 7;
  int k = ks*32 + (l>>4)*8 + j;
  int c = cb*16 + (l&15);
  dst[idx] = f2b(Ws[o][k*128 + c]);
}

struct RepEnt { const float* src; bf16* dst; int total; int ncb_log; int dout; };
__global__ __launch_bounds__(256) void repack_k(RepEnt e0, RepEnt e1, RepEnt e2){
  RepEnt en = (blockIdx.y == 0) ? e0 : (blockIdx.y == 1) ? e1 : e2;
  int idx = blockIdx.x*256 + threadIdx.x;
  if (idx >= en.total) return;
  int j = idx & 7, l = (idx >> 3) & 63, t = idx >> 9;
  int ncbm = (1 << en.ncb_log) - 1;
  int ks = t >> en.ncb_log, cb = t & ncbm;
  int k = ks*32 + (l>>4)*8 + j;
  int c = cb*16 + (l&15);
  en.dst[idx] = f2b(en.src[k*en.dout + c]);
}

// ---------------- fused 5-way projection GEMM ----------------
__global__ __launch_bounds__(256) void gemm5_k(const bf16* __restrict__ A,
    const bf16* __restrict__ Wrep, const float* __restrict__ bias5,
    bf16* __restrict__ proj5){
  const int tid = threadIdx.x;
  const int wid = tid >> 6, l = tid & 63;
  const long r0 = (long)blockIdx.x*64 + wid*16;
  const short* Arow = (const short*)(A + (r0 + (l&15))*128);
  short8 af[4];
  #pragma unroll
  for (int ks=0; ks<4; ks++)
    af[ks] = *(const short8*)(Arow + ks*32 + (l>>4)*8);
  const short8* Wp = (const short8*)Wrep;
  const int cc = l & 15, rr = (l >> 4) * 4;
  #pragma unroll 1
  for (int o=0; o<5; o++){
    f32x4 acc[8];
    #pragma unroll
    for (int cb=0; cb<8; cb++) acc[cb] = (f32x4){0.f,0.f,0.f,0.f};
    #pragma unroll
    for (int ks=0; ks<4; ks++){
      #pragma unroll
      for (int cb=0; cb<8; cb++){
        short8 bf = Wp[(o*32 + ks*8 + cb)*64 + l];
        acc[cb] = __builtin_amdgcn_mfma_f32_16x16x32_bf16(af[ks], bf, acc[cb], 0,0,0);
      }
    }
    bf16* outb = proj5 + (long)o*kN*128;
    #pragma unroll
    for (int cb=0; cb<8; cb++){
      float bb = bias5[o*128 + cb*16 + cc];
      #pragma unroll
      for (int r=0; r<4; r++){
        long row = r0 + rr + r;
        outb[row*128 + cb*16 + cc] = f2b(acc[cb][r] + bb);
      }
    }
  }
}

// ---------------- generic MFMA GEMM ----------------
template<int DIN, int DOUT, int EPI>
__global__ __launch_bounds__(256) void gemm_mfma_k(const bf16* __restrict__ A,
    const bf16* __restrict__ Wrep, const float* __restrict__ bias,
    bf16* __restrict__ C){
  constexpr int KS = DIN/32, NCB = DOUT/16;
  const int tid = threadIdx.x;
  const int wid = tid >> 6, l = tid & 63;
  const long r0 = (long)blockIdx.x*64 + wid*16;
  const short* Arow = (const short*)(A + (r0 + (l&15))*(long)DIN);
  short8 af[KS];
  #pragma unroll
  for (int ks=0; ks<KS; ks++)
    af[ks] = *(const short8*)(Arow + ks*32 + (l>>4)*8);
  f32x4 acc[NCB];
  #pragma unroll
  for (int cb=0; cb<NCB; cb++) acc[cb] = (f32x4){0.f,0.f,0.f,0.f};
  const short8* Wp = (const short8*)Wrep;
  #pragma unroll
  for (int ks=0; ks<KS; ks++){
    #pragma unroll
    for (int cb=0; cb<NCB; cb++){
      short8 bf = Wp[(ks*NCB + cb)*64 + l];
      acc[cb] = __builtin_amdgcn_mfma_f32_16x16x32_bf16(af[ks], bf, acc[cb], 0,0,0);
    }
  }
  const int cc = l & 15, rr = (l >> 4) * 4;
  #pragma unroll
  for (int cb=0; cb<NCB; cb++){
    float bb = bias[cb*16 + cc];
    #pragma unroll
    for (int r=0; r<4; r++){
      long row = r0 + rr + r;
      float v = acc[cb][r] + bb;
      if (EPI == 2) v = 0.5f*v*(1.f + erff(v*0.70710678118654752f));
      C[row*DOUT + cb*16 + cc] = f2b(v);
    }
  }
}

// ---------------- per-edge: alpha[E,4] + eb[E,8], 64 edges per block ----------------
__global__ __launch_bounds__(256) void edge2_k(const bf16* __restrict__ ea,
    const int* __restrict__ srcA, const int* __restrict__ dstA,
    const bf16* __restrict__ xs, const bf16* __restrict__ xd,
    const float* __restrict__ Wedge_f, const float* __restrict__ We_f,
    const float* __restrict__ att_f, const float* __restrict__ be_f,
    float* __restrict__ alpha, float* __restrict__ ebuf){
  __shared__ float sW[32*128];
  __shared__ float sWe[32*8];
  __shared__ float sAtt[128];
  __shared__ float sEa[64][32];
  __shared__ int   sSrc[64], sDst[64];
  __shared__ float sAlpha[64][4];
  const int tid = threadIdx.x;
  const long e0 = (long)blockIdx.x * 64;
  for (int i = tid; i < 4096; i += 256) sW[i] = Wedge_f[i];
  if (tid < 256) sWe[tid] = We_f[tid];
  if (tid < 128) sAtt[tid] = att_f[tid];
  for (int i = tid; i < 64*32; i += 256) sEa[i>>5][i&31] = b2f(ea[e0*32 + i]);
  if (tid < 64){ sSrc[tid] = srcA[e0+tid]; sDst[tid] = dstA[e0+tid]; }
  __syncthreads();
  const int half = tid >> 7;
  const int ch = tid & 127;
  const int h = ch >> 5;
  const float attv = sAtt[ch];
  for (int i = 0; i < 32; i++){
    int le = half*32 + i;
    int s = sSrc[le], dd = sDst[le];
    float ef = 0.f;
    const float* earow = sEa[le];
    #pragma unroll 8
    for (int d = 0; d < 32; d++) ef += earow[d] * sW[d*128 + ch];
    float xv = b2f(xs[(long)s*128+ch]) + b2f(xd[(long)dd*128+ch]) + ef;
    float contrib = tanh_fast(xv) * attv;
    #pragma unroll
    for (int o=16; o; o>>=1) contrib += __shfl_xor(contrib, o, 32);
    if ((ch&31) == 0) sAlpha[le][h] = contrib;
  }
  float myeb[2];
  #pragma unroll
  for (int r = 0; r < 2; r++){
    int idx = tid*2 + r;
    int le = idx >> 3, hh = idx & 7;
    float v = be_f[hh];
    const float* earow = sEa[le];
    #pragma unroll 8
    for (int d=0; d<32; d++) v += earow[d]*sWe[d*8+hh];
    myeb[r] = v;
  }
  __syncthreads();
  if (tid < 256) alpha[e0*4 + tid] = sAlpha[tid>>2][tid&3];
  *((float2*)ebuf + e0*4 + tid) = *(float2*)myeb;
}

// ---------------- CSR build ----------------
__global__ void hist_k(const int* __restrict__ dstA, int* __restrict__ cnt){
  int e = blockIdx.x*256 + threadIdx.x;
  if (e < kE) atomicAdd(&cnt[dstA[e]], 1);
}

__global__ __launch_bounds__(1024) void scan_k(const int* __restrict__ cnt, int* __restrict__ rowptr){
  __shared__ int part[1024];
  const int t = threadIdx.x;
  const int base = t*32;
  int s = 0;
  #pragma unroll
  for (int i=0;i<32;i++) s += cnt[base+i];
  part[t] = s;
  __syncthreads();
  for (int d=1; d<1024; d<<=1){
    int v = (t>=d) ? part[t-d] : 0;
    __syncthreads();
    part[t] += v;
    __syncthreads();
  }
  int run = (t==0) ? 0 : part[t-1];
  for (int i=0;i<32;i++){ rowptr[base+i] = run; run += cnt[base+i]; }
  if (t == 1023) rowptr[kN] = run;
}

__global__ void scatter_k(const int* __restrict__ dstA, const int* __restrict__ rowptr,
                          int* __restrict__ cursor, int* __restrict__ eidx){
  int e = blockIdx.x*256 + threadIdx.x;
  if (e < kE){
    int d = dstA[e];
    int p = atomicAdd(&cursor[d], 1);
    eidx[rowptr[d]+p] = e;
  }
}

// ---------------- pack: permute edge data into CSR order ----------------
__global__ void pack_k(const int* __restrict__ eidx, const int* __restrict__ srcA,
                       const int* __restrict__ dstA, const float* __restrict__ ebuf,
                       const float* __restrict__ alpha,
                       unsigned short* __restrict__ epack, float* __restrict__ ebuf_t,
                       float* __restrict__ alpha_t, int* __restrict__ src_t){
  int t = blockIdx.x*256 + threadIdx.x;
  if (t >= kE) return;
  int e = eidx[t];
  int s = srcA[e], d = dstA[e];
  epack[t] = (unsigned short)(((s & 255) << 8) | (d & 255));
  src_t[t] = s;
  float4 eb0 = *(const float4*)&ebuf[(long)e*8];
  float4 eb1 = *(const float4*)&ebuf[(long)e*8 + 4];
  ebuf_t[0l*kE + t] = eb0.x; ebuf_t[1l*kE + t] = eb0.y;
  ebuf_t[2l*kE + t] = eb0.z; ebuf_t[3l*kE + t] = eb0.w;
  ebuf_t[4l*kE + t] = eb1.x; ebuf_t[5l*kE + t] = eb1.y;
  ebuf_t[6l*kE + t] = eb1.z; ebuf_t[7l*kE + t] = eb1.w;
  *(float4*)&alpha_t[(long)t*4] = *(const float4*)&alpha[(long)e*4];
}

// ---------------- GAT aggregate (CSR-permuted inputs) ----------------
__global__ __launch_bounds__(128) void gat_agg_k(const float* __restrict__ alpha_t,
    const int* __restrict__ rowptr, const int* __restrict__ src_t,
    const bf16* __restrict__ xs, const float* __restrict__ gatb_f,
    bf16* __restrict__ h_local){
  const int v = blockIdx.x;
  const int tid = threadIdx.x;
  const int h = tid>>5;
  const int beg = rowptr[v], end = rowptr[v+1];
  const int deg = end - beg;
  float out = 0.f;
  if (deg > 0){
    float m = -1e30f;
    for (int i=0;i<deg;i++) m = fmaxf(m, alpha_t[(long)(beg+i)*4 + h]);
    float den = 0.f;
    for (int i=0;i<deg;i++){
      float w = __expf(alpha_t[(long)(beg+i)*4 + h] - m);
      den += w;
      out += w * b2f(xs[(long)src_t[beg+i]*128 + tid]);
    }
    out /= (den + 1e-16f);
  }
  h_local[(long)v*128 + tid] = f2b(out + gatb_f[tid]);
}

// ---------------- MFMA attention: block=(g,h), 8 waves, wave = 32-query tile --------
// S^T = K Q^T via mfma_32x32x16 (K=16=head dim). Lane owns query l&31; 128 scores in
// regs (hi-half of keys); partner merge via shfl_xor(32). Bias via per-key-tile LDS
// scatter (read-then-zero). PV via mfma: P packed with cvt_pk + permlane32_swap.
__global__ __launch_bounds__(512) void attn2_k(const bf16* __restrict__ qb,
    const bf16* __restrict__ kb, const bf16* __restrict__ vb,
    const float* __restrict__ ebuf_t, const unsigned short* __restrict__ epack,
    const int* __restrict__ rowptr, bf16* __restrict__ hattn){
  __shared__ short Kf[8*64*8];      // 8 KB  frag-ready K
  __shared__ short Vf[16*64*8];     // 16 KB frag-ready V (transposed gather)
  __shared__ float sb[256*33];      // 33.8 KB bias [q][k(32)+pad]
  const int g = blockIdx.x >> 3, h = blockIdx.x & 7;
  const int tid = threadIdx.x;
  const int w = tid >> 6, l = tid & 63;
  const int q31 = l & 31, hi = l >> 5;
  const int nbase = g << 8;

  // stage K frags: wave w stages key-tile w
  *(short8*)&Kf[tid*8] =
    *(const short8*)((const short*)kb + ((long)(nbase + w*32 + q31))*128 + h*16 + hi*8);
  // stage V frags: frag(f,l): V[(f>>1)*32+(f&1)*16+(l>>5)*8+j][d=l&15]
  for (int s2 = tid; s2 < 1024; s2 += 512){
    int f = s2 >> 6, ll = s2 & 63;
    int keyb = (f>>1)*32 + (f&1)*16 + ((ll>>5)*8);
    int d = ll & 15;
    short tmp[8];
    #pragma unroll
    for (int j=0;j<8;j++)
      tmp[j] = ((const short*)vb)[((long)(nbase + keyb + j))*128 + h*16 + d];
    *(short8*)&Vf[s2*8] = *(short8*)tmp;
  }
  for (int i = tid; i < 256*33; i += 512) sb[i] = 0.f;
  short8 qf = *(const short8*)((const short*)qb + ((long)(nbase + w*32 + q31))*128 + h*16 + hi*8);
  __syncthreads();

  float s_[8][16];
  #pragma unroll
  for (int kt = 0; kt < 8; kt++){
    int rb = rowptr[nbase + kt*32];
    int re = rowptr[nbase + kt*32 + 32];
    for (int t = rb + tid; t < re; t += 512){
      unsigned int p = epack[t];
      atomicAdd(&sb[(p>>8)*33 + (p&31)], ebuf_t[(long)h*kE + t]);
    }
    __syncthreads();
    short8 af = *(short8*)&Kf[(kt*64 + l)*8];
    f32x16 acc = {0.f,0.f,0.f,0.f,0.f,0.f,0.f,0.f,0.f,0.f,0.f,0.f,0.f,0.f,0.f,0.f};
    acc = __builtin_amdgcn_mfma_f32_32x32x16_bf16(af, qf, acc, 0, 0, 0);
    float* brow = &sb[(w*32 + q31)*33];
    #pragma unroll
    for (int r=0;r<16;r++){
      int krow = (r&3) + 8*(r>>2) + 4*hi;
      s_[kt][r] = acc[r]*0.25f + brow[krow];
      brow[krow] = 0.f;               // read-then-zero for next tile
    }
    __syncthreads();
  }

  // softmax over 256 keys: 128 in-lane + partner half
  float m = -1e30f;
  #pragma unroll
  for (int kt=0; kt<8; kt++){
    #pragma unroll
    for (int r=0;r<16;r++) m = fmaxf(m, s_[kt][r]);
  }
  m = fmaxf(m, __shfl_xor(m, 32));
  float lsum = 0.f;
  #pragma unroll
  for (int kt=0; kt<8; kt++){
    #pragma unroll
    for (int r=0;r<16;r++){ float p = __expf(s_[kt][r] - m); s_[kt][r] = p; lsum += p; }
  }
  lsum += __shfl_xor(lsum, 32);

  // PV: pack P to bf16 A-frags (cvt_pk + permlane32_swap), 2 mfma per key-tile
  f32x16 oacc = {0.f,0.f,0.f,0.f,0.f,0.f,0.f,0.f,0.f,0.f,0.f,0.f,0.f,0.f,0.f,0.f};
  #pragma unroll
  for (int kt=0; kt<8; kt++){
    unsigned int a  = cvtpk_bf16(s_[kt][0],  s_[kt][1]);
    unsigned int b  = cvtpk_bf16(s_[kt][2],  s_[kt][3]);
    unsigned int c  = cvtpk_bf16(s_[kt][4],  s_[kt][5]);
    unsigned int d  = cvtpk_bf16(s_[kt][6],  s_[kt][7]);
    unsigned int e  = cvtpk_bf16(s_[kt][8],  s_[kt][9]);
    unsigned int f  = cvtpk_bf16(s_[kt][10], s_[kt][11]);
    unsigned int g2 = cvtpk_bf16(s_[kt][12], s_[kt][13]);
    unsigned int h2 = cvtpk_bf16(s_[kt][14], s_[kt][15]);
    plane_swap(a, c); plane_swap(b, d); plane_swap(e, g2); plane_swap(f, h2);
    union { unsigned int u[4]; short8 s8; } A1, A2;
    A1.u[0]=a; A1.u[1]=b; A1.u[2]=c; A1.u[3]=d;
    A2.u[0]=e; A2.u[1]=f; A2.u[2]=g2; A2.u[3]=h2;
    short8 v1 = *(short8*)&Vf[((kt*2+0)*64 + l)*8];
    short8 v2 = *(short8*)&Vf[((kt*2+1)*64 + l)*8];
    oacc = __builtin_amdgcn_mfma_f32_32x32x16_bf16(A1.s8, v1, oacc, 0,0,0);
    oacc = __builtin_amdgcn_mfma_f32_32x32x16_bf16(A2.s8, v2, oacc, 0,0,0);
  }
  float linv = 1.f / lsum;
  #pragma unroll
  for (int r=0;r<16;r++){
    int qrow = (r&3) + 8*(r>>2) + 4*hi;
    float li = __shfl(linv, qrow);      // convergent
    float ov = oacc[r]*li;
    if (q31 < 16)
      hattn[((long)(nbase + w*32 + qrow))*128 + h*16 + q31] = f2b(ov);
  }
}

// ---------------- residual add + LayerNorm ----------------
__global__ __launch_bounds__(256) void combine_ln_k(const bf16* __restrict__ a,
    const bf16* __restrict__ b, const bf16* __restrict__ c3,
    const float* __restrict__ g, const float* __restrict__ bb,
    void* __restrict__ outp, const int* __restrict__ flag, int is_final){
  const int tid = threadIdx.x;
  const int lane = tid & 63;
  const long row = (long)blockIdx.x*4 + (tid>>6);
  const long base = row*128;
  float v0 = b2f(a[base+lane])    + b2f(b[base+lane]);
  float v1 = b2f(a[base+lane+64]) + b2f(b[base+lane+64]);
  if (c3){ v0 += b2f(c3[base+lane]); v1 += b2f(c3[base+lane+64]); }
  float s = v0 + v1;
  #pragma unroll
  for (int o=1; o<64; o<<=1) s += __shfl_xor(s, o);
  float mean = s * (1.f/128.f);
  float d0 = v0 - mean, d1 = v1 - mean;
  float q = d0*d0 + d1*d1;
  #pragma unroll
  for (int o=1; o<64; o<<=1) q += __shfl_xor(q, o);
  float r = rsqrtf(q*(1.f/128.f) + 1e-5f);
  float r0v = d0*r*g[lane]    + bb[lane];
  float r1v = d1*r*g[lane+64] + bb[lane+64];
  if (is_final && (*flag)){
    float* o = (float*)outp;
    o[base+lane]    = r0v;
    o[base+lane+64] = r1v;
  } else {
    bf16* o = (bf16*)outp;
    o[base+lane]    = f2b(r0v);
    o[base+lane+64] = f2b(r1v);
  }
}

// =====================================================================================
extern "C" void kernel_launch(void* const* d_in, const int* in_sizes, int n_in,
                              void* d_out, int out_size, void* d_ws, size_t ws_size,
                              hipStream_t stream){
  const void* x_raw   = d_in[0];
  const void* ea_raw  = d_in[1];
  const int*  ei      = (const int*)d_in[25];
  const int* srcA = ei;
  const int* dstA = ei + kE;

  char* ws = (char*)d_ws;
  size_t off = 0;
  auto alloc = [&](size_t bytes)->void*{
    void* p = ws + off;
    off = (off + bytes + 255) & ~(size_t)255;
    return p;
  };
  int*   flag    = (int*)alloc(4);
  bf16*  x_bf    = (bf16*)alloc((size_t)kN*128*2);
  bf16*  ea_bf   = (bf16*)alloc((size_t)kE*32*2);
  float* Wsrc_f  = (float*)alloc(16384*4);
  float* Wdst_f  = (float*)alloc(16384*4);
  float* Wedge_f = (float*)alloc(4096*4);
  float* att_f   = (float*)alloc(128*4);
  float* gatb_f  = (float*)alloc(128*4);
  float* Wq_f    = (float*)alloc(16384*4);
  float* Wk_f    = (float*)alloc(16384*4);
  float* Wv_f    = (float*)alloc(16384*4);
  float* Wo_f    = (float*)alloc(16384*4);
  float* bo_f    = (float*)alloc(128*4);
  float* We_f    = (float*)alloc(256*4);
  float* be_f    = (float*)alloc(8*4);
  float* ln1g_f  = (float*)alloc(128*4);
  float* ln1b_f  = (float*)alloc(128*4);
  float* W1_f    = (float*)alloc(32768*4);
  float* b1_f    = (float*)alloc(256*4);
  float* W2_f    = (float*)alloc(32768*4);
  float* b2_f    = (float*)alloc(128*4);
  float* ln2g_f  = (float*)alloc(128*4);
  float* ln2b_f  = (float*)alloc(128*4);
  float* bias5   = (float*)alloc(640*4);
  bf16*  Wrep5   = (bf16*)alloc((size_t)5*16384*2);
  bf16*  WoR     = (bf16*)alloc((size_t)16384*2);
  bf16*  W1R     = (bf16*)alloc((size_t)32768*2);
  bf16*  W2R     = (bf16*)alloc((size_t)32768*2);
  bf16*  proj5   = (bf16*)alloc((size_t)5*kN*128*2);
  bf16* xs   = proj5;
  bf16* xd   = proj5 + (size_t)kN*128;
  bf16* qb   = proj5 + (size_t)2*kN*128;
  bf16* kbuf = proj5 + (size_t)3*kN*128;
  bf16* vbuf = proj5 + (size_t)4*kN*128;
  float* alpha    = (float*)alloc((size_t)kE*4*4);
  float* ebuf     = (float*)alloc((size_t)kE*8*4);
  int* cnt        = (int*)alloc((size_t)2*kN*4);
  int* cursor     = cnt + kN;
  int* rowptr     = (int*)alloc((size_t)(kN+1)*4);
  int* eidx       = (int*)alloc((size_t)kE*4);
  unsigned short* epack = (unsigned short*)alloc((size_t)kE*2);
  float* ebuf_t   = (float*)alloc((size_t)8*kE*4);
  float* alpha_t  = (float*)alloc((size_t)kE*4*4);
  int*   src_t    = (int*)alloc((size_t)kE*4);
  bf16* h_local   = (bf16*)alloc((size_t)kN*128*2);
  bf16* hattn_pre = (bf16*)alloc((size_t)kN*128*2);
  bf16* h_attn    = (bf16*)alloc((size_t)kN*128*2);
  bf16* hbuf      = (bf16*)alloc((size_t)kN*128*2);
  bf16* tbuf      = (bf16*)alloc((size_t)kN*256*2);
  bf16* f2buf     = (bf16*)alloc((size_t)kN*128*2);
  (void)ws_size; (void)in_sizes; (void)n_in; (void)out_size;

  dim3 b256(256);

  detect_k<<<1, b256, 0, stream>>>(x_raw, flag);
  hipMemsetAsync(bias5, 0, 256*4, stream);

  ImpArgs ia;
  const void* srcs[25] = {x_raw, ea_raw, d_in[2], d_in[3], d_in[4], d_in[5], d_in[6],
                          d_in[7], d_in[8], d_in[9], d_in[10], d_in[11], d_in[12],
                          d_in[13], d_in[14], d_in[15], d_in[16], d_in[17], d_in[18],
                          d_in[19], d_in[20], d_in[21], d_in[22], d_in[23], d_in[24]};
  void* dsts[25] = {x_bf, ea_bf, Wsrc_f, Wdst_f, Wedge_f, att_f, gatb_f,
                    Wq_f, bias5+256, Wk_f, bias5+384, Wv_f, bias5+512,
                    Wo_f, bo_f, We_f, be_f, ln1g_f, ln1b_f,
                    W1_f, b1_f, W2_f, b2_f, ln2g_f, ln2b_f};
  int ns[25] = {kN*128, kE*32, 16384, 16384, 4096, 128, 128,
                16384, 128, 16384, 128, 16384, 128,
                16384, 128, 256, 8, 128, 128,
                32768, 256, 32768, 128, 128, 128};
  int isbf[25] = {1,1, 0,0,0,0,0, 0,0,0,0,0,0, 0,0,0,0,0,0, 0,0,0,0,0,0};
  for (int i=0;i<25;i++){ ia.e[i].src=srcs[i]; ia.e[i].dst=dsts[i]; ia.e[i].n=ns[i]; ia.e[i].dst_bf16=isbf[i]; }
  import_k<<<dim3(512,25), b256, 0, stream>>>(ia, flag);

  repack5_k<<<(5*16384)/256, b256, 0, stream>>>(Wsrc_f, Wdst_f, Wq_f, Wk_f, Wv_f, Wrep5);
  RepEnt ro{Wo_f, WoR, 16384, 3, 128};
  RepEnt r1{W1_f, W1R, 32768, 4, 256};
  RepEnt r2{W2_f, W2R, 32768, 3, 128};
  repack_k<<<dim3(128,3), b256, 0, stream>>>(ro, r1, r2);

  gemm5_k<<<kN/64, b256, 0, stream>>>(x_bf, Wrep5, bias5, proj5);

  edge2_k<<<kE/64, b256, 0, stream>>>(ea_bf, srcA, dstA, xs, xd,
                                      Wedge_f, We_f, att_f, be_f, alpha, ebuf);

  hipMemsetAsync(cnt, 0, (size_t)2*kN*4, stream);
  hist_k<<<kE/256, b256, 0, stream>>>(dstA, cnt);
  scan_k<<<1, 1024, 0, stream>>>(cnt, rowptr);
  scatter_k<<<kE/256, b256, 0, stream>>>(dstA, rowptr, cursor, eidx);
  pack_k<<<kE/256, b256, 0, stream>>>(eidx, srcA, dstA, ebuf, alpha,
                                      epack, ebuf_t, alpha_t, src_t);

  gat_agg_k<<<kN, dim3(128), 0, stream>>>(alpha_t, rowptr, src_t, xs, gatb_f, h_local);

  attn2_k<<<kG*kHA, dim3(512), 0, stream>>>(qb, kbuf, vbuf, ebuf_t, epack, rowptr, hattn_pre);
  gemm_mfma_k<128,128,1><<<kN/64, b256, 0, stream>>>(hattn_pre, WoR, bo_f, h_attn);

  combine_ln_k<<<kN/4, b256, 0, stream>>>(x_bf, h_local, h_attn, ln1g_f, ln1b_f, hbuf, flag, 0);

  gemm_mfma_k<128,256,2><<<kN/64, b256, 0, stream>>>(hbuf, W1R, b1_f, tbuf);
  gemm_mfma_k<256,128,1><<<kN/64, b256, 0, stream>>>(tbuf, W2R, b2_f, f2buf);

  combine_ln_k<<<kN/4, b256, 0, stream>>>(hbuf, f2buf, nullptr, ln2g_f, ln2b_f, d_out, flag, 1);
}

// Round 5
// 385.036 us; speedup vs baseline: 1.9841x; 1.1982x over previous
//
#include <hip/hip_runtime.h>
#include <hip/hip_bf16.h>

typedef __hip_bfloat16 bf16;
typedef __hip_bfloat162 bf162;
typedef __attribute__((ext_vector_type(8))) short short8;
typedef __attribute__((ext_vector_type(4))) float f32x4;
typedef __attribute__((ext_vector_type(16))) float f32x16;

constexpr int kN   = 32768;   // nodes
constexpr int kG   = 128;     // graphs
constexpr int kE   = 262144;  // edges
constexpr int kHA  = 8;       // global attn heads

__device__ __forceinline__ float b2f(bf16 v){ return __bfloat162float(v); }
__device__ __forceinline__ bf16  f2b(float v){ return __float2bfloat16(v); }
__device__ __forceinline__ float b2f_raw(unsigned short u){
  return __uint_as_float((unsigned)u << 16);
}
__device__ __forceinline__ unsigned short f2b_raw(float v){
  union{ bf16 b; unsigned short u; } c; c.b = f2b(v); return c.u;
}
__device__ __forceinline__ float tanh_fast(float x){
  float e = __expf(2.f*x);
  return 1.f - 2.f/(e+1.f);
}
__device__ __forceinline__ unsigned int cvtpk_bf16(float lo, float hi){
  unsigned int r;
  asm volatile("v_cvt_pk_bf16_f32 %0, %1, %2" : "=v"(r) : "v"(lo), "v"(hi));
  return r;
}
__device__ __forceinline__ void plane_swap(unsigned int &a, unsigned int &b){
  asm volatile("v_permlane32_swap_b32 %0, %1" : "+v"(a), "+v"(b));
}

// ---------------- input dtype detection (bf16 vs fp32 device buffers) ----------------
__global__ void detect_k(const void* xraw, int* flag){
  const bf16* p = (const bf16*)xraw;
  int good = 0;
  for (int i = threadIdx.x; i < 4096; i += 256){
    float v = fabsf(b2f(p[i]));
    if (v > 0.0009765625f && v < 16.f) good++;
  }
  __shared__ int s[256];
  s[threadIdx.x] = good;
  __syncthreads();
  for (int d = 128; d; d >>= 1){
    if (threadIdx.x < d) s[threadIdx.x] += s[threadIdx.x + d];
    __syncthreads();
  }
  if (threadIdx.x == 0) *flag = (s[0] < 3500) ? 1 : 0;
}

// ---------------- import ----------------
struct ImpEnt { const void* src; void* dst; int n; int dst_bf16; };
struct ImpArgs { ImpEnt e[25]; };
__global__ __launch_bounds__(256) void import_k(ImpArgs a, const int* __restrict__ flag){
  ImpEnt en = a.e[blockIdx.y];
  const bool f32 = (*flag != 0);
  for (int i = blockIdx.x*256 + threadIdx.x; i < en.n; i += gridDim.x*256){
    float v = f32 ? ((const float*)en.src)[i] : b2f(((const bf16*)en.src)[i]);
    if (en.dst_bf16) ((bf16*)en.dst)[i] = f2b(v);
    else             ((float*)en.dst)[i] = v;
  }
}

// ---------------- weight repack to MFMA-B fragment layout ----------------
__global__ __launch_bounds__(256) void repack5_k(const float* __restrict__ W0,
    const float* __restrict__ W1p, const float* __restrict__ W2p,
    const float* __restrict__ W3p, const float* __restrict__ W4p,
    bf16* __restrict__ dst){
  int idx = blockIdx.x*256 + threadIdx.x;
  const float* Ws[5] = {W0, W1p, W2p, W3p, W4p};
  int o = idx >> 14;
  int rem = idx & 16383;
  int j = rem & 7, l = (rem >> 3) & 63, t = rem >> 9;
  int ks = t >> 3, cb = t & 7;
  int k = ks*32 + (l>>4)*8 + j;
  int c = cb*16 + (l&15);
  dst[idx] = f2b(Ws[o][k*128 + c]);
}

struct RepEnt { const float* src; bf16* dst; int total; int ncb_log; int dout; };
__global__ __launch_bounds__(256) void repack_k(RepEnt e0, RepEnt e1, RepEnt e2, RepEnt e3){
  RepEnt en = (blockIdx.y == 0) ? e0 : (blockIdx.y == 1) ? e1 :
              (blockIdx.y == 2) ? e2 : e3;
  int idx = blockIdx.x*256 + threadIdx.x;
  if (idx >= en.total) return;
  int j = idx & 7, l = (idx >> 3) & 63, t = idx >> 9;
  int ncbm = (1 << en.ncb_log) - 1;
  int ks = t >> en.ncb_log, cb = t & ncbm;
  int k = ks*32 + (l>>4)*8 + j;
  int c = cb*16 + (l&15);
  en.dst[idx] = f2b(en.src[k*en.dout + c]);
}

// ---------------- fused 5-way projection GEMM ----------------
__global__ __launch_bounds__(256) void gemm5_k(const bf16* __restrict__ A,
    const bf16* __restrict__ Wrep, const float* __restrict__ bias5,
    bf16* __restrict__ proj5){
  const int tid = threadIdx.x;
  const int wid = tid >> 6, l = tid & 63;
  const long r0 = (long)blockIdx.x*64 + wid*16;
  const short* Arow = (const short*)(A + (r0 + (l&15))*128);
  short8 af[4];
  #pragma unroll
  for (int ks=0; ks<4; ks++)
    af[ks] = *(const short8*)(Arow + ks*32 + (l>>4)*8);
  const short8* Wp = (const short8*)Wrep;
  const int cc = l & 15, rr = (l >> 4) * 4;
  #pragma unroll 1
  for (int o=0; o<5; o++){
    f32x4 acc[8];
    #pragma unroll
    for (int cb=0; cb<8; cb++) acc[cb] = (f32x4){0.f,0.f,0.f,0.f};
    #pragma unroll
    for (int ks=0; ks<4; ks++){
      #pragma unroll
      for (int cb=0; cb<8; cb++){
        short8 bf = Wp[(o*32 + ks*8 + cb)*64 + l];
        acc[cb] = __builtin_amdgcn_mfma_f32_16x16x32_bf16(af[ks], bf, acc[cb], 0,0,0);
      }
    }
    bf16* outb = proj5 + (long)o*kN*128;
    #pragma unroll
    for (int cb=0; cb<8; cb++){
      float bb = bias5[o*128 + cb*16 + cc];
      #pragma unroll
      for (int r=0; r<4; r++){
        long row = r0 + rr + r;
        outb[row*128 + cb*16 + cc] = f2b(acc[cb][r] + bb);
      }
    }
  }
}

// ---------------- generic MFMA GEMM ----------------
template<int DIN, int DOUT, int EPI>
__global__ __launch_bounds__(256) void gemm_mfma_k(const bf16* __restrict__ A,
    const bf16* __restrict__ Wrep, const float* __restrict__ bias,
    bf16* __restrict__ C){
  constexpr int KS = DIN/32, NCB = DOUT/16;
  const int tid = threadIdx.x;
  const int wid = tid >> 6, l = tid & 63;
  const long r0 = (long)blockIdx.x*64 + wid*16;
  const short* Arow = (const short*)(A + (r0 + (l&15))*(long)DIN);
  short8 af[KS];
  #pragma unroll
  for (int ks=0; ks<KS; ks++)
    af[ks] = *(const short8*)(Arow + ks*32 + (l>>4)*8);
  f32x4 acc[NCB];
  #pragma unroll
  for (int cb=0; cb<NCB; cb++) acc[cb] = (f32x4){0.f,0.f,0.f,0.f};
  const short8* Wp = (const short8*)Wrep;
  #pragma unroll
  for (int ks=0; ks<KS; ks++){
    #pragma unroll
    for (int cb=0; cb<NCB; cb++){
      short8 bf = Wp[(ks*NCB + cb)*64 + l];
      acc[cb] = __builtin_amdgcn_mfma_f32_16x16x32_bf16(af[ks], bf, acc[cb], 0,0,0);
    }
  }
  const int cc = l & 15, rr = (l >> 4) * 4;
  #pragma unroll
  for (int cb=0; cb<NCB; cb++){
    float bb = bias[cb*16 + cc];
    #pragma unroll
    for (int r=0; r<4; r++){
      long row = r0 + rr + r;
      float v = acc[cb][r] + bb;
      if (EPI == 2) v = 0.5f*v*(1.f + erff(v*0.70710678118654752f));
      C[row*DOUT + cb*16 + cc] = f2b(v);
    }
  }
}

// ---------------- edge3: MFMA edge GEMM + staged gather; 128 edges/block -------------
// alpha[E,4] GATv2 logits + eb[E,8] attn bias.
__global__ __launch_bounds__(256) void edge3_k(const bf16* __restrict__ ea,
    const int* __restrict__ srcA, const int* __restrict__ dstA,
    const bf16* __restrict__ xs, const bf16* __restrict__ xd,
    const bf16* __restrict__ WeR_edge,   // W_edge in MFMA-B frag layout [8cb][64][8]
    const float* __restrict__ We_f, const float* __restrict__ att_f,
    const float* __restrict__ be_f,
    float* __restrict__ alpha, float* __restrict__ ebuf){
  __shared__ unsigned short sxd[128*132];   // 33.8 KB padded (xs[src]+xd[dst]) bf16
  __shared__ float sWe[256];
  __shared__ float sAtt[128];
  __shared__ float sBe[8];
  __shared__ int   sSrc[128], sDst[128];
  __shared__ float sAlphaF[128*4];
  const int tid = threadIdx.x;
  const int w = tid >> 6, l = tid & 63;
  const long e0 = (long)blockIdx.x * 128;

  // small param staging
  if (tid < 256) sWe[tid] = We_f[tid];
  if (tid < 128){ sAtt[tid] = att_f[tid]; sSrc[tid] = srcA[e0+tid]; sDst[tid] = dstA[e0+tid]; }
  else if (tid < 136) sBe[tid-128] = be_f[tid-128];

  // MFMA operand loads (global, independent of LDS)
  const short* eap = (const short*)ea + e0*32;
  short8 wb[8];
  #pragma unroll
  for (int cb=0; cb<8; cb++)
    wb[cb] = *(const short8*)((const short*)WeR_edge + (cb*64 + l)*8);
  short8 af[2];
  #pragma unroll
  for (int m=0; m<2; m++)
    af[m] = *(const short8*)(eap + (w*32 + m*16 + (l&15))*32 + (l>>4)*8);
  __syncthreads();

  // stage xs[src]+xd[dst] -> sxd (independent vector loads, coalesced per row)
  {
    const int ewr = tid >> 5;          // 0..7
    const int c0  = (tid & 31) * 4;
    const unsigned short* xsu = (const unsigned short*)xs;
    const unsigned short* xdu = (const unsigned short*)xd;
    #pragma unroll 4
    for (int i = 0; i < 16; i++){
      int e = i*8 + ewr;
      long s = sSrc[e], dd = sDst[e];
      ushort4 a = *(const ushort4*)(xsu + s*128 + c0);
      ushort4 b = *(const ushort4*)(xdu + dd*128 + c0);
      unsigned int lo = cvtpk_bf16(b2f_raw(a.x)+b2f_raw(b.x), b2f_raw(a.y)+b2f_raw(b.y));
      unsigned int hi = cvtpk_bf16(b2f_raw(a.z)+b2f_raw(b.z), b2f_raw(a.w)+b2f_raw(b.w));
      *(uint2*)&sxd[e*132 + c0] = (uint2){lo, hi};
    }
  }

  // ef = ea @ W_edge via MFMA (overlaps other waves' staging)
  f32x4 acc[2][8];
  #pragma unroll
  for (int m=0; m<2; m++)
    #pragma unroll
    for (int cb=0; cb<8; cb++)
      acc[m][cb] = __builtin_amdgcn_mfma_f32_16x16x32_bf16(af[m], wb[cb],
                    (f32x4){0.f,0.f,0.f,0.f}, 0,0,0);

  // eb = ea @ We + be  (L2-hot ea rows)
  {
    int e_eb = tid >> 1, h0 = (tid & 1) * 4;
    const unsigned short* earow = (const unsigned short*)ea + (e0 + e_eb)*32;
    float accb[4];
    #pragma unroll
    for (int h=0; h<4; h++) accb[h] = sBe[h0+h];
    #pragma unroll
    for (int dq=0; dq<8; dq++){
      ushort4 u = *(const ushort4*)(earow + dq*4);
      float f0 = b2f_raw(u.x), f1 = b2f_raw(u.y), f2 = b2f_raw(u.z), f3 = b2f_raw(u.w);
      #pragma unroll
      for (int h=0; h<4; h++){
        accb[h] += f0*sWe[(dq*4+0)*8 + h0+h] + f1*sWe[(dq*4+1)*8 + h0+h]
                 + f2*sWe[(dq*4+2)*8 + h0+h] + f3*sWe[(dq*4+3)*8 + h0+h];
      }
    }
    *(float4*)&ebuf[(e0 + e_eb)*8 + h0] = (float4){accb[0],accb[1],accb[2],accb[3]};
  }
  __syncthreads();   // sxd ready

  // epilogue: tanh(ef + sxd) * att, reduce over channels per head
  #pragma unroll
  for (int m=0; m<2; m++){
    #pragma unroll
    for (int r=0; r<4; r++){
      int e_l = w*32 + m*16 + (l>>4)*4 + r;
      float hp[4] = {0.f,0.f,0.f,0.f};
      #pragma unroll
      for (int cb=0; cb<8; cb++){
        int ch = cb*16 + (l&15);
        float v = acc[m][cb][r] + b2f_raw(sxd[e_l*132 + ch]);
        v = tanh_fast(v) * sAtt[ch];
        hp[cb>>1] += v;
      }
      #pragma unroll
      for (int hh=0; hh<4; hh++){
        float sv = hp[hh];
        sv += __shfl_xor(sv,1); sv += __shfl_xor(sv,2);
        sv += __shfl_xor(sv,4); sv += __shfl_xor(sv,8);
        if ((l&15) == 0) sAlphaF[e_l*4 + hh] = sv;
      }
    }
  }
  __syncthreads();
  if (tid < 128)
    *(float4*)&alpha[(e0 + tid)*4] = *(float4*)&sAlphaF[tid*4];
}

// ---------------- CSR build ----------------
__global__ void hist_k(const int* __restrict__ dstA, int* __restrict__ cnt){
  int e = blockIdx.x*256 + threadIdx.x;
  if (e < kE) atomicAdd(&cnt[dstA[e]], 1);
}

__global__ __launch_bounds__(1024) void scan_k(const int* __restrict__ cnt, int* __restrict__ rowptr){
  __shared__ int part[1024];
  const int t = threadIdx.x;
  const int base = t*32;
  int s = 0;
  #pragma unroll
  for (int i=0;i<32;i++) s += cnt[base+i];
  part[t] = s;
  __syncthreads();
  for (int d=1; d<1024; d<<=1){
    int v = (t>=d) ? part[t-d] : 0;
    __syncthreads();
    part[t] += v;
    __syncthreads();
  }
  int run = (t==0) ? 0 : part[t-1];
  for (int i=0;i<32;i++){ rowptr[base+i] = run; run += cnt[base+i]; }
  if (t == 1023) rowptr[kN] = run;
}

__global__ void scatter_k(const int* __restrict__ dstA, const int* __restrict__ rowptr,
                          int* __restrict__ cursor, int* __restrict__ eidx){
  int e = blockIdx.x*256 + threadIdx.x;
  if (e < kE){
    int d = dstA[e];
    int p = atomicAdd(&cursor[d], 1);
    eidx[rowptr[d]+p] = e;
  }
}

// ---------------- pack: permute edge data into CSR order ----------------
__global__ void pack_k(const int* __restrict__ eidx, const int* __restrict__ srcA,
                       const int* __restrict__ dstA, const float* __restrict__ ebuf,
                       const float* __restrict__ alpha,
                       unsigned short* __restrict__ epack, float* __restrict__ ebuf_t,
                       float* __restrict__ alpha_t, int* __restrict__ src_t){
  int t = blockIdx.x*256 + threadIdx.x;
  if (t >= kE) return;
  int e = eidx[t];
  int s = srcA[e], d = dstA[e];
  epack[t] = (unsigned short)(((s & 255) << 8) | (d & 255));
  src_t[t] = s;
  float4 eb0 = *(const float4*)&ebuf[(long)e*8];
  float4 eb1 = *(const float4*)&ebuf[(long)e*8 + 4];
  ebuf_t[0l*kE + t] = eb0.x; ebuf_t[1l*kE + t] = eb0.y;
  ebuf_t[2l*kE + t] = eb0.z; ebuf_t[3l*kE + t] = eb0.w;
  ebuf_t[4l*kE + t] = eb1.x; ebuf_t[5l*kE + t] = eb1.y;
  ebuf_t[6l*kE + t] = eb1.z; ebuf_t[7l*kE + t] = eb1.w;
  *(float4*)&alpha_t[(long)t*4] = *(const float4*)&alpha[(long)e*4];
}

// ---------------- GAT aggregate (CSR-permuted inputs) ----------------
__global__ __launch_bounds__(128) void gat_agg_k(const float* __restrict__ alpha_t,
    const int* __restrict__ rowptr, const int* __restrict__ src_t,
    const bf16* __restrict__ xs, const float* __restrict__ gatb_f,
    bf16* __restrict__ h_local){
  const int v = blockIdx.x;
  const int tid = threadIdx.x;
  const int h = tid>>5;
  const int beg = rowptr[v], end = rowptr[v+1];
  const int deg = end - beg;
  float out = 0.f;
  if (deg > 0){
    float m = -1e30f;
    for (int i=0;i<deg;i++) m = fmaxf(m, alpha_t[(long)(beg+i)*4 + h]);
    float den = 0.f;
    for (int i=0;i<deg;i++){
      float w = __expf(alpha_t[(long)(beg+i)*4 + h] - m);
      den += w;
      out += w * b2f(xs[(long)src_t[beg+i]*128 + tid]);
    }
    out /= (den + 1e-16f);
  }
  h_local[(long)v*128 + tid] = f2b(out + gatb_f[tid]);
}

// ---------------- MFMA attention: block=(g,h), 8 waves, wave = 32-query tile --------
__global__ __launch_bounds__(512) void attn2_k(const bf16* __restrict__ qb,
    const bf16* __restrict__ kb, const bf16* __restrict__ vb,
    const float* __restrict__ ebuf_t, const unsigned short* __restrict__ epack,
    const int* __restrict__ rowptr, bf16* __restrict__ hattn){
  __shared__ short Kf[8*64*8];
  __shared__ short Vf[16*64*8];
  __shared__ float sb[256*33];
  const int g = blockIdx.x >> 3, h = blockIdx.x & 7;
  const int tid = threadIdx.x;
  const int w = tid >> 6, l = tid & 63;
  const int q31 = l & 31, hi = l >> 5;
  const int nbase = g << 8;

  *(short8*)&Kf[tid*8] =
    *(const short8*)((const short*)kb + ((long)(nbase + w*32 + q31))*128 + h*16 + hi*8);
  for (int s2 = tid; s2 < 1024; s2 += 512){
    int f = s2 >> 6, ll = s2 & 63;
    int keyb = (f>>1)*32 + (f&1)*16 + ((ll>>5)*8);
    int d = ll & 15;
    short tmp[8];
    #pragma unroll
    for (int j=0;j<8;j++)
      tmp[j] = ((const short*)vb)[((long)(nbase + keyb + j))*128 + h*16 + d];
    *(short8*)&Vf[s2*8] = *(short8*)tmp;
  }
  for (int i = tid; i < 256*33; i += 512) sb[i] = 0.f;
  short8 qf = *(const short8*)((const short*)qb + ((long)(nbase + w*32 + q31))*128 + h*16 + hi*8);
  __syncthreads();

  float s_[8][16];
  #pragma unroll
  for (int kt = 0; kt < 8; kt++){
    int rb = rowptr[nbase + kt*32];
    int re = rowptr[nbase + kt*32 + 32];
    for (int t = rb + tid; t < re; t += 512){
      unsigned int p = epack[t];
      atomicAdd(&sb[(p>>8)*33 + (p&31)], ebuf_t[(long)h*kE + t]);
    }
    __syncthreads();
    short8 af = *(short8*)&Kf[(kt*64 + l)*8];
    f32x16 acc = {0.f,0.f,0.f,0.f,0.f,0.f,0.f,0.f,0.f,0.f,0.f,0.f,0.f,0.f,0.f,0.f};
    acc = __builtin_amdgcn_mfma_f32_32x32x16_bf16(af, qf, acc, 0, 0, 0);
    float* brow = &sb[(w*32 + q31)*33];
    #pragma unroll
    for (int r=0;r<16;r++){
      int krow = (r&3) + 8*(r>>2) + 4*hi;
      s_[kt][r] = acc[r]*0.25f + brow[krow];
      brow[krow] = 0.f;
    }
    __syncthreads();
  }

  float m = -1e30f;
  #pragma unroll
  for (int kt=0; kt<8; kt++){
    #pragma unroll
    for (int r=0;r<16;r++) m = fmaxf(m, s_[kt][r]);
  }
  m = fmaxf(m, __shfl_xor(m, 32));
  float lsum = 0.f;
  #pragma unroll
  for (int kt=0; kt<8; kt++){
    #pragma unroll
    for (int r=0;r<16;r++){ float p = __expf(s_[kt][r] - m); s_[kt][r] = p; lsum += p; }
  }
  lsum += __shfl_xor(lsum, 32);

  f32x16 oacc = {0.f,0.f,0.f,0.f,0.f,0.f,0.f,0.f,0.f,0.f,0.f,0.f,0.f,0.f,0.f,0.f};
  #pragma unroll
  for (int kt=0; kt<8; kt++){
    unsigned int a  = cvtpk_bf16(s_[kt][0],  s_[kt][1]);
    unsigned int b  = cvtpk_bf16(s_[kt][2],  s_[kt][3]);
    unsigned int c  = cvtpk_bf16(s_[kt][4],  s_[kt][5]);
    unsigned int d  = cvtpk_bf16(s_[kt][6],  s_[kt][7]);
    unsigned int e  = cvtpk_bf16(s_[kt][8],  s_[kt][9]);
    unsigned int f  = cvtpk_bf16(s_[kt][10], s_[kt][11]);
    unsigned int g2 = cvtpk_bf16(s_[kt][12], s_[kt][13]);
    unsigned int h2 = cvtpk_bf16(s_[kt][14], s_[kt][15]);
    plane_swap(a, c); plane_swap(b, d); plane_swap(e, g2); plane_swap(f, h2);
    union { unsigned int u[4]; short8 s8; } A1, A2;
    A1.u[0]=a; A1.u[1]=b; A1.u[2]=c; A1.u[3]=d;
    A2.u[0]=e; A2.u[1]=f; A2.u[2]=g2; A2.u[3]=h2;
    short8 v1 = *(short8*)&Vf[((kt*2+0)*64 + l)*8];
    short8 v2 = *(short8*)&Vf[((kt*2+1)*64 + l)*8];
    oacc = __builtin_amdgcn_mfma_f32_32x32x16_bf16(A1.s8, v1, oacc, 0,0,0);
    oacc = __builtin_amdgcn_mfma_f32_32x32x16_bf16(A2.s8, v2, oacc, 0,0,0);
  }
  float linv = 1.f / lsum;
  #pragma unroll
  for (int r=0;r<16;r++){
    int qrow = (r&3) + 8*(r>>2) + 4*hi;
    float li = __shfl(linv, qrow);
    float ov = oacc[r]*li;
    if (q31 < 16)
      hattn[((long)(nbase + w*32 + qrow))*128 + h*16 + q31] = f2b(ov);
  }
}

// ---------------- residual add + LayerNorm ----------------
__global__ __launch_bounds__(256) void combine_ln_k(const bf16* __restrict__ a,
    const bf16* __restrict__ b, const bf16* __restrict__ c3,
    const float* __restrict__ g, const float* __restrict__ bb,
    void* __restrict__ outp, const int* __restrict__ flag, int is_final){
  const int tid = threadIdx.x;
  const int lane = tid & 63;
  const long row = (long)blockIdx.x*4 + (tid>>6);
  const long base = row*128;
  float v0 = b2f(a[base+lane])    + b2f(b[base+lane]);
  float v1 = b2f(a[base+lane+64]) + b2f(b[base+lane+64]);
  if (c3){ v0 += b2f(c3[base+lane]); v1 += b2f(c3[base+lane+64]); }
  float s = v0 + v1;
  #pragma unroll
  for (int o=1; o<64; o<<=1) s += __shfl_xor(s, o);
  float mean = s * (1.f/128.f);
  float d0 = v0 - mean, d1 = v1 - mean;
  float q = d0*d0 + d1*d1;
  #pragma unroll
  for (int o=1; o<64; o<<=1) q += __shfl_xor(q, o);
  float r = rsqrtf(q*(1.f/128.f) + 1e-5f);
  float r0v = d0*r*g[lane]    + bb[lane];
  float r1v = d1*r*g[lane+64] + bb[lane+64];
  if (is_final && (*flag)){
    float* o = (float*)outp;
    o[base+lane]    = r0v;
    o[base+lane+64] = r1v;
  } else {
    bf16* o = (bf16*)outp;
    o[base+lane]    = f2b(r0v);
    o[base+lane+64] = f2b(r1v);
  }
}

// =====================================================================================
extern "C" void kernel_launch(void* const* d_in, const int* in_sizes, int n_in,
                              void* d_out, int out_size, void* d_ws, size_t ws_size,
                              hipStream_t stream){
  const void* x_raw   = d_in[0];
  const void* ea_raw  = d_in[1];
  const int*  ei      = (const int*)d_in[25];
  const int* srcA = ei;
  const int* dstA = ei + kE;

  char* ws = (char*)d_ws;
  size_t off = 0;
  auto alloc = [&](size_t bytes)->void*{
    void* p = ws + off;
    off = (off + bytes + 255) & ~(size_t)255;
    return p;
  };
  int*   flag    = (int*)alloc(4);
  bf16*  x_bf    = (bf16*)alloc((size_t)kN*128*2);
  bf16*  ea_bf   = (bf16*)alloc((size_t)kE*32*2);
  float* Wsrc_f  = (float*)alloc(16384*4);
  float* Wdst_f  = (float*)alloc(16384*4);
  float* Wedge_f = (float*)alloc(4096*4);
  float* att_f   = (float*)alloc(128*4);
  float* gatb_f  = (float*)alloc(128*4);
  float* Wq_f    = (float*)alloc(16384*4);
  float* Wk_f    = (float*)alloc(16384*4);
  float* Wv_f    = (float*)alloc(16384*4);
  float* Wo_f    = (float*)alloc(16384*4);
  float* bo_f    = (float*)alloc(128*4);
  float* We_f    = (float*)alloc(256*4);
  float* be_f    = (float*)alloc(8*4);
  float* ln1g_f  = (float*)alloc(128*4);
  float* ln1b_f  = (float*)alloc(128*4);
  float* W1_f    = (float*)alloc(32768*4);
  float* b1_f    = (float*)alloc(256*4);
  float* W2_f    = (float*)alloc(32768*4);
  float* b2_f    = (float*)alloc(128*4);
  float* ln2g_f  = (float*)alloc(128*4);
  float* ln2b_f  = (float*)alloc(128*4);
  float* bias5   = (float*)alloc(640*4);
  bf16*  Wrep5   = (bf16*)alloc((size_t)5*16384*2);
  bf16*  WoR     = (bf16*)alloc((size_t)16384*2);
  bf16*  W1R     = (bf16*)alloc((size_t)32768*2);
  bf16*  W2R     = (bf16*)alloc((size_t)32768*2);
  bf16*  WeR     = (bf16*)alloc((size_t)4096*2);
  bf16*  proj5   = (bf16*)alloc((size_t)5*kN*128*2);
  bf16* xs   = proj5;
  bf16* xd   = proj5 + (size_t)kN*128;
  bf16* qb   = proj5 + (size_t)2*kN*128;
  bf16* kbuf = proj5 + (size_t)3*kN*128;
  bf16* vbuf = proj5 + (size_t)4*kN*128;
  float* alpha    = (float*)alloc((size_t)kE*4*4);
  float* ebuf     = (float*)alloc((size_t)kE*8*4);
  int* cnt        = (int*)alloc((size_t)2*kN*4);
  int* cursor     = cnt + kN;
  int* rowptr     = (int*)alloc((size_t)(kN+1)*4);
  int* eidx       = (int*)alloc((size_t)kE*4);
  unsigned short* epack = (unsigned short*)alloc((size_t)kE*2);
  float* ebuf_t   = (float*)alloc((size_t)8*kE*4);
  float* alpha_t  = (float*)alloc((size_t)kE*4*4);
  int*   src_t    = (int*)alloc((size_t)kE*4);
  bf16* h_local   = (bf16*)alloc((size_t)kN*128*2);
  bf16* hattn_pre = (bf16*)alloc((size_t)kN*128*2);
  bf16* h_attn    = (bf16*)alloc((size_t)kN*128*2);
  bf16* hbuf      = (bf16*)alloc((size_t)kN*128*2);
  bf16* tbuf      = (bf16*)alloc((size_t)kN*256*2);
  bf16* f2buf     = (bf16*)alloc((size_t)kN*128*2);
  (void)ws_size; (void)in_sizes; (void)n_in; (void)out_size;

  dim3 b256(256);

  detect_k<<<1, b256, 0, stream>>>(x_raw, flag);
  hipMemsetAsync(bias5, 0, 256*4, stream);

  ImpArgs ia;
  const void* srcs[25] = {x_raw, ea_raw, d_in[2], d_in[3], d_in[4], d_in[5], d_in[6],
                          d_in[7], d_in[8], d_in[9], d_in[10], d_in[11], d_in[12],
                          d_in[13], d_in[14], d_in[15], d_in[16], d_in[17], d_in[18],
                          d_in[19], d_in[20], d_in[21], d_in[22], d_in[23], d_in[24]};
  void* dsts[25] = {x_bf, ea_bf, Wsrc_f, Wdst_f, Wedge_f, att_f, gatb_f,
                    Wq_f, bias5+256, Wk_f, bias5+384, Wv_f, bias5+512,
                    Wo_f, bo_f, We_f, be_f, ln1g_f, ln1b_f,
                    W1_f, b1_f, W2_f, b2_f, ln2g_f, ln2b_f};
  int ns[25] = {kN*128, kE*32, 16384, 16384, 4096, 128, 128,
                16384, 128, 16384, 128, 16384, 128,
                16384, 128, 256, 8, 128, 128,
                32768, 256, 32768, 128, 128, 128};
  int isbf[25] = {1,1, 0,0,0,0,0, 0,0,0,0,0,0, 0,0,0,0,0,0, 0,0,0,0,0,0};
  for (int i=0;i<25;i++){ ia.e[i].src=srcs[i]; ia.e[i].dst=dsts[i]; ia.e[i].n=ns[i]; ia.e[i].dst_bf16=isbf[i]; }
  import_k<<<dim3(512,25), b256, 0, stream>>>(ia, flag);

  repack5_k<<<(5*16384)/256, b256, 0, stream>>>(Wsrc_f, Wdst_f, Wq_f, Wk_f, Wv_f, Wrep5);
  RepEnt ro{Wo_f, WoR, 16384, 3, 128};
  RepEnt r1{W1_f, W1R, 32768, 4, 256};
  RepEnt r2{W2_f, W2R, 32768, 3, 128};
  RepEnt re{Wedge_f, WeR, 4096, 3, 128};
  repack_k<<<dim3(128,4), b256, 0, stream>>>(ro, r1, r2, re);

  gemm5_k<<<kN/64, b256, 0, stream>>>(x_bf, Wrep5, bias5, proj5);

  edge3_k<<<kE/128, b256, 0, stream>>>(ea_bf, srcA, dstA, xs, xd,
                                       WeR, We_f, att_f, be_f, alpha, ebuf);

  hipMemsetAsync(cnt, 0, (size_t)2*kN*4, stream);
  hist_k<<<kE/256, b256, 0, stream>>>(dstA, cnt);
  scan_k<<<1, 1024, 0, stream>>>(cnt, rowptr);
  scatter_k<<<kE/256, b256, 0, stream>>>(dstA, rowptr, cursor, eidx);
  pack_k<<<kE/256, b256, 0, stream>>>(eidx, srcA, dstA, ebuf, alpha,
                                      epack, ebuf_t, alpha_t, src_t);

  gat_agg_k<<<kN, dim3(128), 0, stream>>>(alpha_t, rowptr, src_t, xs, gatb_f, h_local);

  attn2_k<<<kG*kHA, dim3(512), 0, stream>>>(qb, kbuf, vbuf, ebuf_t, epack, rowptr, hattn_pre);
  gemm_mfma_k<128,128,1><<<kN/64, b256, 0, stream>>>(hattn_pre, WoR, bo_f, h_attn);

  combine_ln_k<<<kN/4, b256, 0, stream>>>(x_bf, h_local, h_attn, ln1g_f, ln1b_f, hbuf, flag, 0);

  gemm_mfma_k<128,256,2><<<kN/64, b256, 0, stream>>>(hbuf, W1R, b1_f, tbuf);
  gemm_mfma_k<256,128,1><<<kN/64, b256, 0, stream>>>(tbuf, W2R, b2_f, f2buf);

  combine_ln_k<<<kN/4, b256, 0, stream>>>(hbuf, f2buf, nullptr, ln2g_f, ln2b_f, d_out, flag, 1);
}

// Round 6
// 351.159 us; speedup vs baseline: 2.1755x; 1.0965x over previous
//
#include <hip/hip_runtime.h>
#include <hip/hip_bf16.h>

typedef __hip_bfloat16 bf16;
typedef __hip_bfloat162 bf162;
typedef __attribute__((ext_vector_type(8))) short short8;
typedef __attribute__((ext_vector_type(4))) float f32x4;
typedef __attribute__((ext_vector_type(16))) float f32x16;

constexpr int kN   = 32768;   // nodes
constexpr int kG   = 128;     // graphs
constexpr int kE   = 262144;  // edges
constexpr int kHA  = 8;       // global attn heads

__device__ __forceinline__ float b2f(bf16 v){ return __bfloat162float(v); }
__device__ __forceinline__ bf16  f2b(float v){ return __float2bfloat16(v); }
__device__ __forceinline__ float b2f_raw(unsigned short u){
  return __uint_as_float((unsigned)u << 16);
}
__device__ __forceinline__ float tanh_fast(float x){
  float e = __expf(2.f*x);
  return 1.f - 2.f/(e+1.f);
}
__device__ __forceinline__ unsigned int cvtpk_bf16(float lo, float hi){
  unsigned int r;
  asm volatile("v_cvt_pk_bf16_f32 %0, %1, %2" : "=v"(r) : "v"(lo), "v"(hi));
  return r;
}
__device__ __forceinline__ void plane_swap(unsigned int &a, unsigned int &b){
  asm volatile("v_permlane32_swap_b32 %0, %1" : "+v"(a), "+v"(b));
}

// ---------------- input dtype detection (bf16 vs fp32 device buffers) ----------------
__global__ void detect_k(const void* xraw, int* flag){
  const bf16* p = (const bf16*)xraw;
  int good = 0;
  for (int i = threadIdx.x; i < 4096; i += 256){
    float v = fabsf(b2f(p[i]));
    if (v > 0.0009765625f && v < 16.f) good++;
  }
  __shared__ int s[256];
  s[threadIdx.x] = good;
  __syncthreads();
  for (int d = 128; d; d >>= 1){
    if (threadIdx.x < d) s[threadIdx.x] += s[threadIdx.x + d];
    __syncthreads();
  }
  if (threadIdx.x == 0) *flag = (s[0] < 3500) ? 1 : 0;
}

// ---------------- import ----------------
struct ImpEnt { const void* src; void* dst; int n; int dst_bf16; };
struct ImpArgs { ImpEnt e[24]; };
__global__ __launch_bounds__(256) void import_k(ImpArgs a, const int* __restrict__ flag){
  ImpEnt en = a.e[blockIdx.y];
  const bool f32 = (*flag != 0);
  for (int i = blockIdx.x*256 + threadIdx.x; i < en.n; i += gridDim.x*256){
    float v = f32 ? ((const float*)en.src)[i] : b2f(((const bf16*)en.src)[i]);
    if (en.dst_bf16) ((bf16*)en.dst)[i] = f2b(v);
    else             ((float*)en.dst)[i] = v;
  }
}

// ---------------- weight repack to MFMA-B fragment layout ----------------
__global__ __launch_bounds__(256) void repack5_k(const float* __restrict__ W0,
    const float* __restrict__ W1p, const float* __restrict__ W2p,
    const float* __restrict__ W3p, const float* __restrict__ W4p,
    bf16* __restrict__ dst){
  int idx = blockIdx.x*256 + threadIdx.x;
  const float* Ws[5] = {W0, W1p, W2p, W3p, W4p};
  int o = idx >> 14;
  int rem = idx & 16383;
  int j = rem & 7, l = (rem >> 3) & 63, t = rem >> 9;
  int ks = t >> 3, cb = t & 7;
  int k = ks*32 + (l>>4)*8 + j;
  int c = cb*16 + (l&15);
  dst[idx] = f2b(Ws[o][k*128 + c]);
}

struct RepEnt { const float* src; bf16* dst; int total; int ncb_log; int dout; };
__global__ __launch_bounds__(256) void repack_k(RepEnt e0, RepEnt e1, RepEnt e2, RepEnt e3){
  RepEnt en = (blockIdx.y == 0) ? e0 : (blockIdx.y == 1) ? e1 :
              (blockIdx.y == 2) ? e2 : e3;
  int idx = blockIdx.x*256 + threadIdx.x;
  if (idx >= en.total) return;
  int j = idx & 7, l = (idx >> 3) & 63, t = idx >> 9;
  int ncbm = (1 << en.ncb_log) - 1;
  int ks = t >> en.ncb_log, cb = t & ncbm;
  int k = ks*32 + (l>>4)*8 + j;
  int c = cb*16 + (l&15);
  en.dst[idx] = f2b(en.src[k*en.dout + c]);
}

// ---------------- fused 5-way projection GEMM (reads raw x, dtype-flag branch) -------
__global__ __launch_bounds__(256) void gemm5_k(const void* __restrict__ xraw,
    const int* __restrict__ flag,
    const bf16* __restrict__ Wrep, const float* __restrict__ bias5,
    bf16* __restrict__ proj5){
  const int tid = threadIdx.x;
  const int wid = tid >> 6, l = tid & 63;
  const long r0 = (long)blockIdx.x*64 + wid*16;
  const bool f32 = (*flag != 0);
  short8 af[4];
  if (f32){
    const float* fr = (const float*)xraw + (r0 + (l&15))*128;
    #pragma unroll
    for (int ks=0; ks<4; ks++){
      float4 a = *(const float4*)(fr + ks*32 + (l>>4)*8);
      float4 b = *(const float4*)(fr + ks*32 + (l>>4)*8 + 4);
      union{ unsigned int u[4]; short8 s; } c;
      c.u[0]=cvtpk_bf16(a.x,a.y); c.u[1]=cvtpk_bf16(a.z,a.w);
      c.u[2]=cvtpk_bf16(b.x,b.y); c.u[3]=cvtpk_bf16(b.z,b.w);
      af[ks] = c.s;
    }
  } else {
    const short* Arow = (const short*)xraw + (r0 + (l&15))*128;
    #pragma unroll
    for (int ks=0; ks<4; ks++)
      af[ks] = *(const short8*)(Arow + ks*32 + (l>>4)*8);
  }
  const short8* Wp = (const short8*)Wrep;
  const int cc = l & 15, rr = (l >> 4) * 4;
  #pragma unroll 1
  for (int o=0; o<5; o++){
    f32x4 acc[8];
    #pragma unroll
    for (int cb=0; cb<8; cb++) acc[cb] = (f32x4){0.f,0.f,0.f,0.f};
    #pragma unroll
    for (int ks=0; ks<4; ks++){
      #pragma unroll
      for (int cb=0; cb<8; cb++){
        short8 bf = Wp[(o*32 + ks*8 + cb)*64 + l];
        acc[cb] = __builtin_amdgcn_mfma_f32_16x16x32_bf16(af[ks], bf, acc[cb], 0,0,0);
      }
    }
    bf16* outb = proj5 + (long)o*kN*128;
    #pragma unroll
    for (int cb=0; cb<8; cb++){
      float bb = bias5[o*128 + cb*16 + cc];
      #pragma unroll
      for (int r=0; r<4; r++){
        long row = r0 + rr + r;
        outb[row*128 + cb*16 + cc] = f2b(acc[cb][r] + bb);
      }
    }
  }
}

// ---------------- generic MFMA GEMM ----------------
template<int DIN, int DOUT, int EPI>
__global__ __launch_bounds__(256) void gemm_mfma_k(const bf16* __restrict__ A,
    const bf16* __restrict__ Wrep, const float* __restrict__ bias,
    bf16* __restrict__ C){
  constexpr int KS = DIN/32, NCB = DOUT/16;
  const int tid = threadIdx.x;
  const int wid = tid >> 6, l = tid & 63;
  const long r0 = (long)blockIdx.x*64 + wid*16;
  const short* Arow = (const short*)(A + (r0 + (l&15))*(long)DIN);
  short8 af[KS];
  #pragma unroll
  for (int ks=0; ks<KS; ks++)
    af[ks] = *(const short8*)(Arow + ks*32 + (l>>4)*8);
  f32x4 acc[NCB];
  #pragma unroll
  for (int cb=0; cb<NCB; cb++) acc[cb] = (f32x4){0.f,0.f,0.f,0.f};
  const short8* Wp = (const short8*)Wrep;
  #pragma unroll
  for (int ks=0; ks<KS; ks++){
    #pragma unroll
    for (int cb=0; cb<NCB; cb++){
      short8 bf = Wp[(ks*NCB + cb)*64 + l];
      acc[cb] = __builtin_amdgcn_mfma_f32_16x16x32_bf16(af[ks], bf, acc[cb], 0,0,0);
    }
  }
  const int cc = l & 15, rr = (l >> 4) * 4;
  #pragma unroll
  for (int cb=0; cb<NCB; cb++){
    float bb = bias[cb*16 + cc];
    #pragma unroll
    for (int r=0; r<4; r++){
      long row = r0 + rr + r;
      float v = acc[cb][r] + bb;
      if (EPI == 2) v = 0.5f*v*(1.f + erff(v*0.70710678118654752f));
      C[row*DOUT + cb*16 + cc] = f2b(v);
    }
  }
}

// ---------------- CSR build ----------------
__global__ void hist_k(const int* __restrict__ dstA, int* __restrict__ cnt){
  int e = blockIdx.x*256 + threadIdx.x;
  if (e < kE) atomicAdd(&cnt[dstA[e]], 1);
}

__global__ __launch_bounds__(1024) void scan_k(const int* __restrict__ cnt, int* __restrict__ rowptr){
  __shared__ int part[1024];
  const int t = threadIdx.x;
  const int base = t*32;
  int s = 0;
  #pragma unroll
  for (int i=0;i<32;i++) s += cnt[base+i];
  part[t] = s;
  __syncthreads();
  for (int d=1; d<1024; d<<=1){
    int v = (t>=d) ? part[t-d] : 0;
    __syncthreads();
    part[t] += v;
    __syncthreads();
  }
  int run = (t==0) ? 0 : part[t-1];
  for (int i=0;i<32;i++){ rowptr[base+i] = run; run += cnt[base+i]; }
  if (t == 1023) rowptr[kN] = run;
}

__global__ void scatter_k(const int* __restrict__ dstA, const int* __restrict__ rowptr,
                          int* __restrict__ cursor, int* __restrict__ eidx){
  int e = blockIdx.x*256 + threadIdx.x;
  if (e < kE){
    int d = dstA[e];
    int p = atomicAdd(&cursor[d], 1);
    eidx[rowptr[d]+p] = e;
  }
}

// ---------------- edge3: CSR-ordered, MFMA edge GEMM + staged gather; 64 edges/block
// writes alpha_t[t,4], ebuf_t[h][t], epack[t], src_t[t] directly (pack fused).
__global__ __launch_bounds__(256) void edge3_k(const bf16* __restrict__ ea,
    const int* __restrict__ eidx, const int* __restrict__ srcA,
    const int* __restrict__ dstA,
    const bf16* __restrict__ xs, const bf16* __restrict__ xd,
    const bf16* __restrict__ WeR_edge,
    const float* __restrict__ We_f, const float* __restrict__ att_f,
    const float* __restrict__ be_f,
    float* __restrict__ alpha_t, float* __restrict__ ebuf_t,
    unsigned short* __restrict__ epack, int* __restrict__ src_t){
  __shared__ unsigned short sxd[64*132];   // 16.9 KB
  __shared__ float sWe[256];
  __shared__ float sAtt[128];
  __shared__ float sBe[8];
  __shared__ int   sEid[64], sSrc[64], sDst[64];
  __shared__ float sAlphaF[64*4];
  const int tid = threadIdx.x;
  const int w = tid >> 6, l = tid & 63;
  const long t0 = (long)blockIdx.x * 64;

  if (tid < 64){
    int e = eidx[t0 + tid];
    int s = srcA[e], d = dstA[e];
    sEid[tid] = e; sSrc[tid] = s; sDst[tid] = d;
    src_t[t0 + tid] = s;
    epack[t0 + tid] = (unsigned short)(((s & 255) << 8) | (d & 255));
  }
  if (tid < 256) sWe[tid] = We_f[tid];
  if (tid < 128) sAtt[tid] = att_f[tid];
  else if (tid < 136) sBe[tid-128] = be_f[tid-128];
  __syncthreads();

  // MFMA operands: A = 16 edge rows per wave (via eidx), B = W_edge frags
  const short* eap = (const short*)ea;
  short8 af = *(const short8*)(eap + (long)sEid[w*16 + (l&15)]*32 + (l>>4)*8);
  short8 wb[8];
  #pragma unroll
  for (int cb=0; cb<8; cb++)
    wb[cb] = *(const short8*)((const short*)WeR_edge + (cb*64 + l)*8);

  // stage xs[src]+xd[dst] -> sxd (8 passes, independent 8B loads)
  {
    const int c0 = (tid & 31) * 4;
    const int rb = tid >> 5;             // 8 rows per pass
    const unsigned short* xsu = (const unsigned short*)xs;
    const unsigned short* xdu = (const unsigned short*)xd;
    #pragma unroll 4
    for (int p = 0; p < 8; p++){
      int row = p*8 + rb;
      long s = sSrc[row], dd = sDst[row];
      ushort4 a = *(const ushort4*)(xsu + s*128 + c0);
      ushort4 b = *(const ushort4*)(xdu + dd*128 + c0);
      unsigned int lo = cvtpk_bf16(b2f_raw(a.x)+b2f_raw(b.x), b2f_raw(a.y)+b2f_raw(b.y));
      unsigned int hi = cvtpk_bf16(b2f_raw(a.z)+b2f_raw(b.z), b2f_raw(a.w)+b2f_raw(b.w));
      *(uint2*)&sxd[row*132 + c0] = (uint2){lo, hi};
    }
  }

  // ef = ea @ W_edge via MFMA
  f32x4 acc[8];
  #pragma unroll
  for (int cb=0; cb<8; cb++)
    acc[cb] = __builtin_amdgcn_mfma_f32_16x16x32_bf16(af, wb[cb],
                (f32x4){0.f,0.f,0.f,0.f}, 0,0,0);

  // eb = ea @ We + be : thread -> (edge tid>>2, head pair (tid&3)*2)
  {
    int e_eb = tid >> 2, h0 = (tid & 3) * 2;
    const unsigned short* earow = (const unsigned short*)ea + (long)sEid[e_eb]*32;
    float a0 = sBe[h0], a1 = sBe[h0+1];
    #pragma unroll
    for (int dq=0; dq<8; dq++){
      ushort4 u = *(const ushort4*)(earow + dq*4);
      float f0 = b2f_raw(u.x), f1 = b2f_raw(u.y), f2 = b2f_raw(u.z), f3 = b2f_raw(u.w);
      a0 += f0*sWe[(dq*4+0)*8 + h0]   + f1*sWe[(dq*4+1)*8 + h0]
          + f2*sWe[(dq*4+2)*8 + h0]   + f3*sWe[(dq*4+3)*8 + h0];
      a1 += f0*sWe[(dq*4+0)*8 + h0+1] + f1*sWe[(dq*4+1)*8 + h0+1]
          + f2*sWe[(dq*4+2)*8 + h0+1] + f3*sWe[(dq*4+3)*8 + h0+1];
    }
    ebuf_t[(long)h0*kE     + t0 + e_eb] = a0;
    ebuf_t[(long)(h0+1)*kE + t0 + e_eb] = a1;
  }
  __syncthreads();   // sxd ready

  // epilogue: tanh(ef + sxd) * att, per-head 16-lane reduce
  #pragma unroll
  for (int r=0; r<4; r++){
    int e_l = w*16 + (l>>4)*4 + r;
    float hp[4] = {0.f,0.f,0.f,0.f};
    #pragma unroll
    for (int cb=0; cb<8; cb++){
      int ch = cb*16 + (l&15);
      float v = acc[cb][r] + b2f_raw(sxd[e_l*132 + ch]);
      v = tanh_fast(v) * sAtt[ch];
      hp[cb>>1] += v;
    }
    #pragma unroll
    for (int hh=0; hh<4; hh++){
      float sv = hp[hh];
      sv += __shfl_xor(sv,1); sv += __shfl_xor(sv,2);
      sv += __shfl_xor(sv,4); sv += __shfl_xor(sv,8);
      if ((l&15) == 0) sAlphaF[e_l*4 + hh] = sv;
    }
  }
  __syncthreads();
  if (tid < 64)
    *(float4*)&alpha_t[(t0 + tid)*4] = *(float4*)&sAlphaF[tid*4];
}

// ---------------- GAT aggregate (CSR-permuted inputs) ----------------
__global__ __launch_bounds__(128) void gat_agg_k(const float* __restrict__ alpha_t,
    const int* __restrict__ rowptr, const int* __restrict__ src_t,
    const bf16* __restrict__ xs, const float* __restrict__ gatb_f,
    bf16* __restrict__ h_local){
  const int v = blockIdx.x;
  const int tid = threadIdx.x;
  const int h = tid>>5;
  const int beg = rowptr[v], end = rowptr[v+1];
  const int deg = end - beg;
  float out = 0.f;
  if (deg > 0){
    float m = -1e30f;
    for (int i=0;i<deg;i++) m = fmaxf(m, alpha_t[(long)(beg+i)*4 + h]);
    float den = 0.f;
    for (int i=0;i<deg;i++){
      float w = __expf(alpha_t[(long)(beg+i)*4 + h] - m);
      den += w;
      out += w * b2f(xs[(long)src_t[beg+i]*128 + tid]);
    }
    out /= (den + 1e-16f);
  }
  h_local[(long)v*128 + tid] = f2b(out + gatb_f[tid]);
}

// ---------------- MFMA attention: block=(g,h), 8 waves, wave = 32-query tile --------
__global__ __launch_bounds__(512) void attn2_k(const bf16* __restrict__ qb,
    const bf16* __restrict__ kb, const bf16* __restrict__ vb,
    const float* __restrict__ ebuf_t, const unsigned short* __restrict__ epack,
    const int* __restrict__ rowptr, bf16* __restrict__ hattn){
  __shared__ short Kf[8*64*8];
  __shared__ short Vf[16*64*8];
  __shared__ float sb[256*33];
  const int g = blockIdx.x >> 3, h = blockIdx.x & 7;
  const int tid = threadIdx.x;
  const int w = tid >> 6, l = tid & 63;
  const int q31 = l & 31, hi = l >> 5;
  const int nbase = g << 8;

  *(short8*)&Kf[tid*8] =
    *(const short8*)((const short*)kb + ((long)(nbase + w*32 + q31))*128 + h*16 + hi*8);
  for (int s2 = tid; s2 < 1024; s2 += 512){
    int f = s2 >> 6, ll = s2 & 63;
    int keyb = (f>>1)*32 + (f&1)*16 + ((ll>>5)*8);
    int d = ll & 15;
    short tmp[8];
    #pragma unroll
    for (int j=0;j<8;j++)
      tmp[j] = ((const short*)vb)[((long)(nbase + keyb + j))*128 + h*16 + d];
    *(short8*)&Vf[s2*8] = *(short8*)tmp;
  }
  for (int i = tid; i < 256*33; i += 512) sb[i] = 0.f;
  short8 qf = *(const short8*)((const short*)qb + ((long)(nbase + w*32 + q31))*128 + h*16 + hi*8);
  __syncthreads();

  float s_[8][16];
  #pragma unroll
  for (int kt = 0; kt < 8; kt++){
    int rb = rowptr[nbase + kt*32];
    int re = rowptr[nbase + kt*32 + 32];
    for (int t = rb + tid; t < re; t += 512){
      unsigned int p = epack[t];
      atomicAdd(&sb[(p>>8)*33 + (p&31)], ebuf_t[(long)h*kE + t]);
    }
    __syncthreads();
    short8 af = *(short8*)&Kf[(kt*64 + l)*8];
    f32x16 acc = {0.f,0.f,0.f,0.f,0.f,0.f,0.f,0.f,0.f,0.f,0.f,0.f,0.f,0.f,0.f,0.f};
    acc = __builtin_amdgcn_mfma_f32_32x32x16_bf16(af, qf, acc, 0, 0, 0);
    float* brow = &sb[(w*32 + q31)*33];
    #pragma unroll
    for (int r=0;r<16;r++){
      int krow = (r&3) + 8*(r>>2) + 4*hi;
      s_[kt][r] = acc[r]*0.25f + brow[krow];
      brow[krow] = 0.f;
    }
    __syncthreads();
  }

  float m = -1e30f;
  #pragma unroll
  for (int kt=0; kt<8; kt++){
    #pragma unroll
    for (int r=0;r<16;r++) m = fmaxf(m, s_[kt][r]);
  }
  m = fmaxf(m, __shfl_xor(m, 32));
  float lsum = 0.f;
  #pragma unroll
  for (int kt=0; kt<8; kt++){
    #pragma unroll
    for (int r=0;r<16;r++){ float p = __expf(s_[kt][r] - m); s_[kt][r] = p; lsum += p; }
  }
  lsum += __shfl_xor(lsum, 32);

  f32x16 oacc = {0.f,0.f,0.f,0.f,0.f,0.f,0.f,0.f,0.f,0.f,0.f,0.f,0.f,0.f,0.f,0.f};
  #pragma unroll
  for (int kt=0; kt<8; kt++){
    unsigned int a  = cvtpk_bf16(s_[kt][0],  s_[kt][1]);
    unsigned int b  = cvtpk_bf16(s_[kt][2],  s_[kt][3]);
    unsigned int c  = cvtpk_bf16(s_[kt][4],  s_[kt][5]);
    unsigned int d  = cvtpk_bf16(s_[kt][6],  s_[kt][7]);
    unsigned int e  = cvtpk_bf16(s_[kt][8],  s_[kt][9]);
    unsigned int f  = cvtpk_bf16(s_[kt][10], s_[kt][11]);
    unsigned int g2 = cvtpk_bf16(s_[kt][12], s_[kt][13]);
    unsigned int h2 = cvtpk_bf16(s_[kt][14], s_[kt][15]);
    plane_swap(a, c); plane_swap(b, d); plane_swap(e, g2); plane_swap(f, h2);
    union { unsigned int u[4]; short8 s8; } A1, A2;
    A1.u[0]=a; A1.u[1]=b; A1.u[2]=c; A1.u[3]=d;
    A2.u[0]=e; A2.u[1]=f; A2.u[2]=g2; A2.u[3]=h2;
    short8 v1 = *(short8*)&Vf[((kt*2+0)*64 + l)*8];
    short8 v2 = *(short8*)&Vf[((kt*2+1)*64 + l)*8];
    oacc = __builtin_amdgcn_mfma_f32_32x32x16_bf16(A1.s8, v1, oacc, 0,0,0);
    oacc = __builtin_amdgcn_mfma_f32_32x32x16_bf16(A2.s8, v2, oacc, 0,0,0);
  }
  float linv = 1.f / lsum;
  #pragma unroll
  for (int r=0;r<16;r++){
    int qrow = (r&3) + 8*(r>>2) + 4*hi;
    float li = __shfl(linv, qrow);
    float ov = oacc[r]*li;
    if (q31 < 16)
      hattn[((long)(nbase + w*32 + qrow))*128 + h*16 + q31] = f2b(ov);
  }
}

// ---------------- residual add + LayerNorm ----------------
// a_raw: read a per detected dtype (x input). is_final: out dtype per flag.
__global__ __launch_bounds__(256) void combine_ln_k(const void* __restrict__ a,
    const bf16* __restrict__ b, const bf16* __restrict__ c3,
    const float* __restrict__ g, const float* __restrict__ bb,
    void* __restrict__ outp, const int* __restrict__ flag,
    int a_raw, int is_final){
  const int tid = threadIdx.x;
  const int lane = tid & 63;
  const long row = (long)blockIdx.x*4 + (tid>>6);
  const long base = row*128;
  float a0, a1;
  if (a_raw && (*flag)){
    const float* ap = (const float*)a;
    a0 = ap[base+lane]; a1 = ap[base+lane+64];
  } else {
    const bf16* ap = (const bf16*)a;
    a0 = b2f(ap[base+lane]); a1 = b2f(ap[base+lane+64]);
  }
  float v0 = a0 + b2f(b[base+lane]);
  float v1 = a1 + b2f(b[base+lane+64]);
  if (c3){ v0 += b2f(c3[base+lane]); v1 += b2f(c3[base+lane+64]); }
  float s = v0 + v1;
  #pragma unroll
  for (int o=1; o<64; o<<=1) s += __shfl_xor(s, o);
  float mean = s * (1.f/128.f);
  float d0 = v0 - mean, d1 = v1 - mean;
  float q = d0*d0 + d1*d1;
  #pragma unroll
  for (int o=1; o<64; o<<=1) q += __shfl_xor(q, o);
  float r = rsqrtf(q*(1.f/128.f) + 1e-5f);
  float r0v = d0*r*g[lane]    + bb[lane];
  float r1v = d1*r*g[lane+64] + bb[lane+64];
  if (is_final && (*flag)){
    float* o = (float*)outp;
    o[base+lane]    = r0v;
    o[base+lane+64] = r1v;
  } else {
    bf16* o = (bf16*)outp;
    o[base+lane]    = f2b(r0v);
    o[base+lane+64] = f2b(r1v);
  }
}

// =====================================================================================
extern "C" void kernel_launch(void* const* d_in, const int* in_sizes, int n_in,
                              void* d_out, int out_size, void* d_ws, size_t ws_size,
                              hipStream_t stream){
  const void* x_raw   = d_in[0];
  const void* ea_raw  = d_in[1];
  const int*  ei      = (const int*)d_in[25];
  const int* srcA = ei;
  const int* dstA = ei + kE;

  char* ws = (char*)d_ws;
  size_t off = 0;
  auto alloc = [&](size_t bytes)->void*{
    void* p = ws + off;
    off = (off + bytes + 255) & ~(size_t)255;
    return p;
  };
  int*   flag    = (int*)alloc(4);
  bf16*  ea_bf   = (bf16*)alloc((size_t)kE*32*2);
  float* Wsrc_f  = (float*)alloc(16384*4);
  float* Wdst_f  = (float*)alloc(16384*4);
  float* Wedge_f = (float*)alloc(4096*4);
  float* att_f   = (float*)alloc(128*4);
  float* gatb_f  = (float*)alloc(128*4);
  float* Wq_f    = (float*)alloc(16384*4);
  float* Wk_f    = (float*)alloc(16384*4);
  float* Wv_f    = (float*)alloc(16384*4);
  float* Wo_f    = (float*)alloc(16384*4);
  float* bo_f    = (float*)alloc(128*4);
  float* We_f    = (float*)alloc(256*4);
  float* be_f    = (float*)alloc(8*4);
  float* ln1g_f  = (float*)alloc(128*4);
  float* ln1b_f  = (float*)alloc(128*4);
  float* W1_f    = (float*)alloc(32768*4);
  float* b1_f    = (float*)alloc(256*4);
  float* W2_f    = (float*)alloc(32768*4);
  float* b2_f    = (float*)alloc(128*4);
  float* ln2g_f  = (float*)alloc(128*4);
  float* ln2b_f  = (float*)alloc(128*4);
  float* bias5   = (float*)alloc(640*4);
  bf16*  Wrep5   = (bf16*)alloc((size_t)5*16384*2);
  bf16*  WoR     = (bf16*)alloc((size_t)16384*2);
  bf16*  W1R     = (bf16*)alloc((size_t)32768*2);
  bf16*  W2R     = (bf16*)alloc((size_t)32768*2);
  bf16*  WeR     = (bf16*)alloc((size_t)4096*2);
  bf16*  proj5   = (bf16*)alloc((size_t)5*kN*128*2);
  bf16* xs   = proj5;
  bf16* xd   = proj5 + (size_t)kN*128;
  bf16* qb   = proj5 + (size_t)2*kN*128;
  bf16* kbuf = proj5 + (size_t)3*kN*128;
  bf16* vbuf = proj5 + (size_t)4*kN*128;
  int* cnt        = (int*)alloc((size_t)2*kN*4);
  int* cursor     = cnt + kN;
  int* rowptr     = (int*)alloc((size_t)(kN+1)*4);
  int* eidx       = (int*)alloc((size_t)kE*4);
  unsigned short* epack = (unsigned short*)alloc((size_t)kE*2);
  float* ebuf_t   = (float*)alloc((size_t)8*kE*4);
  float* alpha_t  = (float*)alloc((size_t)kE*4*4);
  int*   src_t    = (int*)alloc((size_t)kE*4);
  bf16* h_local   = (bf16*)alloc((size_t)kN*128*2);
  bf16* hattn_pre = (bf16*)alloc((size_t)kN*128*2);
  bf16* h_attn    = (bf16*)alloc((size_t)kN*128*2);
  bf16* hbuf      = (bf16*)alloc((size_t)kN*128*2);
  bf16* tbuf      = (bf16*)alloc((size_t)kN*256*2);
  bf16* f2buf     = (bf16*)alloc((size_t)kN*128*2);
  (void)ws_size; (void)in_sizes; (void)n_in; (void)out_size;

  dim3 b256(256);

  detect_k<<<1, b256, 0, stream>>>(x_raw, flag);
  hipMemsetAsync(bias5, 0, 256*4, stream);
  hipMemsetAsync(cnt, 0, (size_t)2*kN*4, stream);

  // CSR build first (only needs dstA) so edge3 can run in CSR order
  hist_k<<<kE/256, b256, 0, stream>>>(dstA, cnt);
  scan_k<<<1, 1024, 0, stream>>>(cnt, rowptr);
  scatter_k<<<kE/256, b256, 0, stream>>>(dstA, rowptr, cursor, eidx);

  ImpArgs ia;
  const void* srcs[24] = {ea_raw, d_in[2], d_in[3], d_in[4], d_in[5], d_in[6],
                          d_in[7], d_in[8], d_in[9], d_in[10], d_in[11], d_in[12],
                          d_in[13], d_in[14], d_in[15], d_in[16], d_in[17], d_in[18],
                          d_in[19], d_in[20], d_in[21], d_in[22], d_in[23], d_in[24]};
  void* dsts[24] = {ea_bf, Wsrc_f, Wdst_f, Wedge_f, att_f, gatb_f,
                    Wq_f, bias5+256, Wk_f, bias5+384, Wv_f, bias5+512,
                    Wo_f, bo_f, We_f, be_f, ln1g_f, ln1b_f,
                    W1_f, b1_f, W2_f, b2_f, ln2g_f, ln2b_f};
  int ns[24] = {kE*32, 16384, 16384, 4096, 128, 128,
                16384, 128, 16384, 128, 16384, 128,
                16384, 128, 256, 8, 128, 128,
                32768, 256, 32768, 128, 128, 128};
  int isbf[24] = {1, 0,0,0,0,0, 0,0,0,0,0,0, 0,0,0,0,0,0, 0,0,0,0,0,0};
  for (int i=0;i<24;i++){ ia.e[i].src=srcs[i]; ia.e[i].dst=dsts[i]; ia.e[i].n=ns[i]; ia.e[i].dst_bf16=isbf[i]; }
  import_k<<<dim3(512,24), b256, 0, stream>>>(ia, flag);

  repack5_k<<<(5*16384)/256, b256, 0, stream>>>(Wsrc_f, Wdst_f, Wq_f, Wk_f, Wv_f, Wrep5);
  RepEnt ro{Wo_f, WoR, 16384, 3, 128};
  RepEnt r1{W1_f, W1R, 32768, 4, 256};
  RepEnt r2{W2_f, W2R, 32768, 3, 128};
  RepEnt re{Wedge_f, WeR, 4096, 3, 128};
  repack_k<<<dim3(128,4), b256, 0, stream>>>(ro, r1, r2, re);

  gemm5_k<<<kN/64, b256, 0, stream>>>(x_raw, flag, Wrep5, bias5, proj5);

  edge3_k<<<kE/64, b256, 0, stream>>>(ea_bf, eidx, srcA, dstA, xs, xd,
                                      WeR, We_f, att_f, be_f,
                                      alpha_t, ebuf_t, epack, src_t);

  gat_agg_k<<<kN, dim3(128), 0, stream>>>(alpha_t, rowptr, src_t, xs, gatb_f, h_local);

  attn2_k<<<kG*kHA, dim3(512), 0, stream>>>(qb, kbuf, vbuf, ebuf_t, epack, rowptr, hattn_pre);
  gemm_mfma_k<128,128,1><<<kN/64, b256, 0, stream>>>(hattn_pre, WoR, bo_f, h_attn);

  combine_ln_k<<<kN/4, b256, 0, stream>>>(x_raw, h_local, h_attn, ln1g_f, ln1b_f,
                                          hbuf, flag, 1, 0);

  gemm_mfma_k<128,256,2><<<kN/64, b256, 0, stream>>>(hbuf, W1R, b1_f, tbuf);
  gemm_mfma_k<256,128,1><<<kN/64, b256, 0, stream>>>(tbuf, W2R, b2_f, f2buf);

  combine_ln_k<<<kN/4, b256, 0, stream>>>(hbuf, f2buf, nullptr, ln2g_f, ln2b_f,
                                          d_out, flag, 0, 1);
}

// Round 7
// 327.086 us; speedup vs baseline: 2.3356x; 1.0736x over previous
//
#include <hip/hip_runtime.h>
#include <hip/hip_bf16.h>

typedef __hip_bfloat16 bf16;
typedef __hip_bfloat162 bf162;
typedef __attribute__((ext_vector_type(8))) short short8;
typedef __attribute__((ext_vector_type(4))) float f32x4;
typedef __attribute__((ext_vector_type(16))) float f32x16;

constexpr int kN   = 32768;   // nodes
constexpr int kG   = 128;     // graphs
constexpr int kE   = 262144;  // edges
constexpr int kHA  = 8;       // global attn heads

__device__ __forceinline__ float b2f(bf16 v){ return __bfloat162float(v); }
__device__ __forceinline__ bf16  f2b(float v){ return __float2bfloat16(v); }
__device__ __forceinline__ float b2f_raw(unsigned short u){
  return __uint_as_float((unsigned)u << 16);
}
__device__ __forceinline__ float tanh_fast(float x){
  float e = __expf(2.f*x);
  return 1.f - 2.f/(e+1.f);
}
__device__ __forceinline__ unsigned int cvtpk_bf16(float lo, float hi){
  unsigned int r;
  asm volatile("v_cvt_pk_bf16_f32 %0, %1, %2" : "=v"(r) : "v"(lo), "v"(hi));
  return r;
}
__device__ __forceinline__ void plane_swap(unsigned int &a, unsigned int &b){
  asm volatile("v_permlane32_swap_b32 %0, %1" : "+v"(a), "+v"(b));
}

// ---------------- input dtype detection (bf16 vs fp32 device buffers) ----------------
__global__ void detect_k(const void* xraw, int* flag){
  const bf16* p = (const bf16*)xraw;
  int good = 0;
  for (int i = threadIdx.x; i < 4096; i += 256){
    float v = fabsf(b2f(p[i]));
    if (v > 0.0009765625f && v < 16.f) good++;
  }
  __shared__ int s[256];
  s[threadIdx.x] = good;
  __syncthreads();
  for (int d = 128; d; d >>= 1){
    if (threadIdx.x < d) s[threadIdx.x] += s[threadIdx.x + d];
    __syncthreads();
  }
  if (threadIdx.x == 0) *flag = (s[0] < 3500) ? 1 : 0;
}

// ---------------- import ----------------
struct ImpEnt { const void* src; void* dst; int n; int dst_bf16; };
struct ImpArgs { ImpEnt e[24]; };
__global__ __launch_bounds__(256) void import_k(ImpArgs a, const int* __restrict__ flag){
  ImpEnt en = a.e[blockIdx.y];
  const bool f32 = (*flag != 0);
  for (int i = blockIdx.x*256 + threadIdx.x; i < en.n; i += gridDim.x*256){
    float v = f32 ? ((const float*)en.src)[i] : b2f(((const bf16*)en.src)[i]);
    if (en.dst_bf16) ((bf16*)en.dst)[i] = f2b(v);
    else             ((float*)en.dst)[i] = v;
  }
}

// ---------------- weight repack to MFMA-B fragment layout ----------------
__global__ __launch_bounds__(256) void repack5_k(const float* __restrict__ W0,
    const float* __restrict__ W1p, const float* __restrict__ W2p,
    const float* __restrict__ W3p, const float* __restrict__ W4p,
    bf16* __restrict__ dst){
  int idx = blockIdx.x*256 + threadIdx.x;
  const float* Ws[5] = {W0, W1p, W2p, W3p, W4p};
  int o = idx >> 14;
  int rem = idx & 16383;
  int j = rem & 7, l = (rem >> 3) & 63, t = rem >> 9;
  int ks = t >> 3, cb = t & 7;
  int k = ks*32 + (l>>4)*8 + j;
  int c = cb*16 + (l&15);
  dst[idx] = f2b(Ws[o][k*128 + c]);
}

struct RepEnt { const float* src; bf16* dst; int total; int ncb_log; int dout; };
__global__ __launch_bounds__(256) void repack_k(RepEnt e0, RepEnt e1, RepEnt e2, RepEnt e3){
  RepEnt en = (blockIdx.y == 0) ? e0 : (blockIdx.y == 1) ? e1 :
              (blockIdx.y == 2) ? e2 : e3;
  int idx = blockIdx.x*256 + threadIdx.x;
  if (idx >= en.total) return;
  int j = idx & 7, l = (idx >> 3) & 63, t = idx >> 9;
  int ncbm = (1 << en.ncb_log) - 1;
  int ks = t >> en.ncb_log, cb = t & ncbm;
  int k = ks*32 + (l>>4)*8 + j;
  int c = cb*16 + (l&15);
  en.dst[idx] = f2b(en.src[k*en.dout + c]);
}

// ---------------- fused 5-way projection GEMM (reads raw x, dtype-flag branch) -------
__global__ __launch_bounds__(256) void gemm5_k(const void* __restrict__ xraw,
    const int* __restrict__ flag,
    const bf16* __restrict__ Wrep, const float* __restrict__ bias5,
    bf16* __restrict__ proj5){
  const int tid = threadIdx.x;
  const int wid = tid >> 6, l = tid & 63;
  const long r0 = (long)blockIdx.x*64 + wid*16;
  const bool f32 = (*flag != 0);
  short8 af[4];
  if (f32){
    const float* fr = (const float*)xraw + (r0 + (l&15))*128;
    #pragma unroll
    for (int ks=0; ks<4; ks++){
      float4 a = *(const float4*)(fr + ks*32 + (l>>4)*8);
      float4 b = *(const float4*)(fr + ks*32 + (l>>4)*8 + 4);
      union{ unsigned int u[4]; short8 s; } c;
      c.u[0]=cvtpk_bf16(a.x,a.y); c.u[1]=cvtpk_bf16(a.z,a.w);
      c.u[2]=cvtpk_bf16(b.x,b.y); c.u[3]=cvtpk_bf16(b.z,b.w);
      af[ks] = c.s;
    }
  } else {
    const short* Arow = (const short*)xraw + (r0 + (l&15))*128;
    #pragma unroll
    for (int ks=0; ks<4; ks++)
      af[ks] = *(const short8*)(Arow + ks*32 + (l>>4)*8);
  }
  const short8* Wp = (const short8*)Wrep;
  const int cc = l & 15, rr = (l >> 4) * 4;
  #pragma unroll 1
  for (int o=0; o<5; o++){
    f32x4 acc[8];
    #pragma unroll
    for (int cb=0; cb<8; cb++) acc[cb] = (f32x4){0.f,0.f,0.f,0.f};
    #pragma unroll
    for (int ks=0; ks<4; ks++){
      #pragma unroll
      for (int cb=0; cb<8; cb++){
        short8 bf = Wp[(o*32 + ks*8 + cb)*64 + l];
        acc[cb] = __builtin_amdgcn_mfma_f32_16x16x32_bf16(af[ks], bf, acc[cb], 0,0,0);
      }
    }
    bf16* outb = proj5 + (long)o*kN*128;
    #pragma unroll
    for (int cb=0; cb<8; cb++){
      float bb = bias5[o*128 + cb*16 + cc];
      #pragma unroll
      for (int r=0; r<4; r++){
        long row = r0 + rr + r;
        outb[row*128 + cb*16 + cc] = f2b(acc[cb][r] + bb);
      }
    }
  }
}

// ---------------- generic MFMA GEMM ----------------
template<int DIN, int DOUT, int EPI>
__global__ __launch_bounds__(256) void gemm_mfma_k(const bf16* __restrict__ A,
    const bf16* __restrict__ Wrep, const float* __restrict__ bias,
    bf16* __restrict__ C){
  constexpr int KS = DIN/32, NCB = DOUT/16;
  const int tid = threadIdx.x;
  const int wid = tid >> 6, l = tid & 63;
  const long r0 = (long)blockIdx.x*64 + wid*16;
  const short* Arow = (const short*)(A + (r0 + (l&15))*(long)DIN);
  short8 af[KS];
  #pragma unroll
  for (int ks=0; ks<KS; ks++)
    af[ks] = *(const short8*)(Arow + ks*32 + (l>>4)*8);
  f32x4 acc[NCB];
  #pragma unroll
  for (int cb=0; cb<NCB; cb++) acc[cb] = (f32x4){0.f,0.f,0.f,0.f};
  const short8* Wp = (const short8*)Wrep;
  #pragma unroll
  for (int ks=0; ks<KS; ks++){
    #pragma unroll
    for (int cb=0; cb<NCB; cb++){
      short8 bf = Wp[(ks*NCB + cb)*64 + l];
      acc[cb] = __builtin_amdgcn_mfma_f32_16x16x32_bf16(af[ks], bf, acc[cb], 0,0,0);
    }
  }
  const int cc = l & 15, rr = (l >> 4) * 4;
  #pragma unroll
  for (int cb=0; cb<NCB; cb++){
    float bb = bias[cb*16 + cc];
    #pragma unroll
    for (int r=0; r<4; r++){
      long row = r0 + rr + r;
      float v = acc[cb][r] + bb;
      if (EPI == 2) v = 0.5f*v*(1.f + erff(v*0.70710678118654752f));
      C[row*DOUT + cb*16 + cc] = f2b(v);
    }
  }
}

// ---------------- CSR build ----------------
__global__ void hist_k(const int* __restrict__ dstA, int* __restrict__ cnt){
  int e = blockIdx.x*256 + threadIdx.x;
  if (e < kE) atomicAdd(&cnt[dstA[e]], 1);
}

__global__ __launch_bounds__(1024) void scan_k(const int* __restrict__ cnt, int* __restrict__ rowptr){
  __shared__ int part[1024];
  const int t = threadIdx.x;
  const int base = t*32;
  int s = 0;
  #pragma unroll
  for (int i=0;i<32;i++) s += cnt[base+i];
  part[t] = s;
  __syncthreads();
  for (int d=1; d<1024; d<<=1){
    int v = (t>=d) ? part[t-d] : 0;
    __syncthreads();
    part[t] += v;
    __syncthreads();
  }
  int run = (t==0) ? 0 : part[t-1];
  for (int i=0;i<32;i++){ rowptr[base+i] = run; run += cnt[base+i]; }
  if (t == 1023) rowptr[kN] = run;
}

__global__ void scatter_k(const int* __restrict__ dstA, const int* __restrict__ rowptr,
                          int* __restrict__ cursor, int* __restrict__ eidx){
  int e = blockIdx.x*256 + threadIdx.x;
  if (e < kE){
    int d = dstA[e];
    int p = atomicAdd(&cursor[d], 1);
    eidx[rowptr[d]+p] = e;
  }
}

// ---------------- edge3: CSR-ordered, MFMA edge GEMM + staged gather; 64 edges/block
__global__ __launch_bounds__(256) void edge3_k(const bf16* __restrict__ ea,
    const int* __restrict__ eidx, const int* __restrict__ srcA,
    const int* __restrict__ dstA,
    const bf16* __restrict__ xs, const bf16* __restrict__ xd,
    const bf16* __restrict__ WeR_edge,
    const float* __restrict__ We_f, const float* __restrict__ att_f,
    const float* __restrict__ be_f,
    float* __restrict__ alpha_t, float* __restrict__ ebuf_t,
    unsigned short* __restrict__ epack, int* __restrict__ src_t){
  __shared__ unsigned short sxd[64*132];   // 16.9 KB
  __shared__ float sWe[256];
  __shared__ float sAtt[128];
  __shared__ float sBe[8];
  __shared__ int   sEid[64], sSrc[64], sDst[64];
  __shared__ float sAlphaF[64*4];
  const int tid = threadIdx.x;
  const int w = tid >> 6, l = tid & 63;
  const long t0 = (long)blockIdx.x * 64;

  if (tid < 64){
    int e = eidx[t0 + tid];
    int s = srcA[e], d = dstA[e];
    sEid[tid] = e; sSrc[tid] = s; sDst[tid] = d;
    src_t[t0 + tid] = s;
    epack[t0 + tid] = (unsigned short)(((s & 255) << 8) | (d & 255));
  }
  if (tid < 256) sWe[tid] = We_f[tid];
  if (tid < 128) sAtt[tid] = att_f[tid];
  else if (tid < 136) sBe[tid-128] = be_f[tid-128];
  __syncthreads();

  // MFMA operands: A = 16 edge rows per wave (via eidx), B = W_edge frags
  const short* eap = (const short*)ea;
  short8 af = *(const short8*)(eap + (long)sEid[w*16 + (l&15)]*32 + (l>>4)*8);
  short8 wb[8];
  #pragma unroll
  for (int cb=0; cb<8; cb++)
    wb[cb] = *(const short8*)((const short*)WeR_edge + (cb*64 + l)*8);

  // stage xs[src]+xd[dst] -> sxd
  {
    const int c0 = (tid & 31) * 4;
    const int rb = tid >> 5;
    const unsigned short* xsu = (const unsigned short*)xs;
    const unsigned short* xdu = (const unsigned short*)xd;
    #pragma unroll 4
    for (int p = 0; p < 8; p++){
      int row = p*8 + rb;
      long s = sSrc[row], dd = sDst[row];
      ushort4 a = *(const ushort4*)(xsu + s*128 + c0);
      ushort4 b = *(const ushort4*)(xdu + dd*128 + c0);
      unsigned int lo = cvtpk_bf16(b2f_raw(a.x)+b2f_raw(b.x), b2f_raw(a.y)+b2f_raw(b.y));
      unsigned int hi = cvtpk_bf16(b2f_raw(a.z)+b2f_raw(b.z), b2f_raw(a.w)+b2f_raw(b.w));
      *(uint2*)&sxd[row*132 + c0] = (uint2){lo, hi};
    }
  }

  // ef = ea @ W_edge via MFMA
  f32x4 acc[8];
  #pragma unroll
  for (int cb=0; cb<8; cb++)
    acc[cb] = __builtin_amdgcn_mfma_f32_16x16x32_bf16(af, wb[cb],
                (f32x4){0.f,0.f,0.f,0.f}, 0,0,0);

  // eb = ea @ We + be
  {
    int e_eb = tid >> 2, h0 = (tid & 3) * 2;
    const unsigned short* earow = (const unsigned short*)ea + (long)sEid[e_eb]*32;
    float a0 = sBe[h0], a1 = sBe[h0+1];
    #pragma unroll
    for (int dq=0; dq<8; dq++){
      ushort4 u = *(const ushort4*)(earow + dq*4);
      float f0 = b2f_raw(u.x), f1 = b2f_raw(u.y), f2 = b2f_raw(u.z), f3 = b2f_raw(u.w);
      a0 += f0*sWe[(dq*4+0)*8 + h0]   + f1*sWe[(dq*4+1)*8 + h0]
          + f2*sWe[(dq*4+2)*8 + h0]   + f3*sWe[(dq*4+3)*8 + h0];
      a1 += f0*sWe[(dq*4+0)*8 + h0+1] + f1*sWe[(dq*4+1)*8 + h0+1]
          + f2*sWe[(dq*4+2)*8 + h0+1] + f3*sWe[(dq*4+3)*8 + h0+1];
    }
    ebuf_t[(long)h0*kE     + t0 + e_eb] = a0;
    ebuf_t[(long)(h0+1)*kE + t0 + e_eb] = a1;
  }
  __syncthreads();   // sxd ready

  // epilogue: tanh(ef + sxd) * att, per-head 16-lane reduce
  #pragma unroll
  for (int r=0; r<4; r++){
    int e_l = w*16 + (l>>4)*4 + r;
    float hp[4] = {0.f,0.f,0.f,0.f};
    #pragma unroll
    for (int cb=0; cb<8; cb++){
      int ch = cb*16 + (l&15);
      float v = acc[cb][r] + b2f_raw(sxd[e_l*132 + ch]);
      v = tanh_fast(v) * sAtt[ch];
      hp[cb>>1] += v;
    }
    #pragma unroll
    for (int hh=0; hh<4; hh++){
      float sv = hp[hh];
      sv += __shfl_xor(sv,1); sv += __shfl_xor(sv,2);
      sv += __shfl_xor(sv,4); sv += __shfl_xor(sv,8);
      if ((l&15) == 0) sAlphaF[e_l*4 + hh] = sv;
    }
  }
  __syncthreads();
  if (tid < 64)
    *(float4*)&alpha_t[(t0 + tid)*4] = *(float4*)&sAlphaF[tid*4];
}

// ---------------- GAT aggregate (CSR-permuted inputs) ----------------
__global__ __launch_bounds__(128) void gat_agg_k(const float* __restrict__ alpha_t,
    const int* __restrict__ rowptr, const int* __restrict__ src_t,
    const bf16* __restrict__ xs, const float* __restrict__ gatb_f,
    bf16* __restrict__ h_local){
  const int v = blockIdx.x;
  const int tid = threadIdx.x;
  const int h = tid>>5;
  const int beg = rowptr[v], end = rowptr[v+1];
  const int deg = end - beg;
  float out = 0.f;
  if (deg > 0){
    float m = -1e30f;
    for (int i=0;i<deg;i++) m = fmaxf(m, alpha_t[(long)(beg+i)*4 + h]);
    float den = 0.f;
    for (int i=0;i<deg;i++){
      float w = __expf(alpha_t[(long)(beg+i)*4 + h] - m);
      den += w;
      out += w * b2f(xs[(long)src_t[beg+i]*128 + tid]);
    }
    out /= (den + 1e-16f);
  }
  h_local[(long)v*128 + tid] = f2b(out + gatb_f[tid]);
}

// ---------------- MFMA flash attention: block=(g,h), 8 waves, wave = 32-query tile --
// Online softmax, PV inside kt loop (no 128-reg score array). K frags loaded from
// global per tile; V frags staged in LDS; bias via per-tile LDS scatter (read+zero).
// XCD swizzle: all 8 head-blocks of a graph share bid&7 -> same XCD L2.
__global__ __launch_bounds__(512, 6) void attn2_k(const bf16* __restrict__ qb,
    const bf16* __restrict__ kb, const bf16* __restrict__ vb,
    const float* __restrict__ ebuf_t, const unsigned short* __restrict__ epack,
    const int* __restrict__ rowptr, bf16* __restrict__ hattn){
  __shared__ short Vf[16*64*8];     // 16 KB
  __shared__ float sb[256*33];      // 33.8 KB
  const int bid = blockIdx.x;
  const int h = (bid >> 3) >> 4;
  const int g = (((bid >> 3) & 15) << 3) | (bid & 7);
  const int tid = threadIdx.x;
  const int w = tid >> 6, l = tid & 63;
  const int q31 = l & 31, hi = l >> 5;
  const int nbase = g << 8;

  // stage V frags
  for (int s2 = tid; s2 < 1024; s2 += 512){
    int f = s2 >> 6, ll = s2 & 63;
    int keyb = (f>>1)*32 + (f&1)*16 + ((ll>>5)*8);
    int d = ll & 15;
    short tmp[8];
    #pragma unroll
    for (int j=0;j<8;j++)
      tmp[j] = ((const short*)vb)[((long)(nbase + keyb + j))*128 + h*16 + d];
    *(short8*)&Vf[s2*8] = *(short8*)tmp;
  }
  for (int i = tid; i < 256*33; i += 512) sb[i] = 0.f;
  short8 qf = *(const short8*)((const short*)qb + ((long)(nbase + w*32 + q31))*128 + h*16 + hi*8);
  __syncthreads();

  float m = -1e30f, lsum = 0.f;
  f32x16 oacc = {0.f,0.f,0.f,0.f,0.f,0.f,0.f,0.f,0.f,0.f,0.f,0.f,0.f,0.f,0.f,0.f};
  #pragma unroll 1
  for (int kt = 0; kt < 8; kt++){
    int rb = rowptr[nbase + kt*32];
    int re = rowptr[nbase + kt*32 + 32];
    for (int t = rb + tid; t < re; t += 512){
      unsigned int p = epack[t];
      atomicAdd(&sb[(p>>8)*33 + (p&31)], ebuf_t[(long)h*kE + t]);
    }
    __syncthreads();
    short8 af = *(const short8*)((const short*)kb +
                 ((long)(nbase + kt*32 + q31))*128 + h*16 + hi*8);
    f32x16 acc = {0.f,0.f,0.f,0.f,0.f,0.f,0.f,0.f,0.f,0.f,0.f,0.f,0.f,0.f,0.f,0.f};
    acc = __builtin_amdgcn_mfma_f32_32x32x16_bf16(af, qf, acc, 0, 0, 0);
    float s[16];
    float* brow = &sb[(w*32 + q31)*33];
    #pragma unroll
    for (int r=0;r<16;r++){
      int krow = (r&3) + 8*(r>>2) + 4*hi;
      s[r] = acc[r]*0.25f + brow[krow];
      brow[krow] = 0.f;
    }
    __syncthreads();
    // online softmax update (per-query max across lane pair)
    float tmax = s[0];
    #pragma unroll
    for (int r=1;r<16;r++) tmax = fmaxf(tmax, s[r]);
    tmax = fmaxf(tmax, __shfl_xor(tmax, 32));
    float mn = fmaxf(m, tmax);
    float corrq = __expf(m - mn);
    m = mn;
    float psum = 0.f;
    #pragma unroll
    for (int r=0;r<16;r++){ s[r] = __expf(s[r] - m); psum += s[r]; }
    lsum = lsum*corrq + psum;
    #pragma unroll
    for (int r=0;r<16;r++){
      int qrow = (r&3) + 8*(r>>2) + 4*hi;
      oacc[r] *= __shfl(corrq, qrow);
    }
    // pack P -> bf16 A-frags, 2 PV MFMAs
    unsigned int a  = cvtpk_bf16(s[0],  s[1]);
    unsigned int b  = cvtpk_bf16(s[2],  s[3]);
    unsigned int c  = cvtpk_bf16(s[4],  s[5]);
    unsigned int d  = cvtpk_bf16(s[6],  s[7]);
    unsigned int e  = cvtpk_bf16(s[8],  s[9]);
    unsigned int f  = cvtpk_bf16(s[10], s[11]);
    unsigned int g2 = cvtpk_bf16(s[12], s[13]);
    unsigned int h2 = cvtpk_bf16(s[14], s[15]);
    plane_swap(a, c); plane_swap(b, d); plane_swap(e, g2); plane_swap(f, h2);
    union { unsigned int u[4]; short8 s8; } A1, A2;
    A1.u[0]=a; A1.u[1]=b; A1.u[2]=c; A1.u[3]=d;
    A2.u[0]=e; A2.u[1]=f; A2.u[2]=g2; A2.u[3]=h2;
    short8 v1 = *(short8*)&Vf[((kt*2+0)*64 + l)*8];
    short8 v2 = *(short8*)&Vf[((kt*2+1)*64 + l)*8];
    oacc = __builtin_amdgcn_mfma_f32_32x32x16_bf16(A1.s8, v1, oacc, 0,0,0);
    oacc = __builtin_amdgcn_mfma_f32_32x32x16_bf16(A2.s8, v2, oacc, 0,0,0);
  }
  lsum += __shfl_xor(lsum, 32);
  float linv = 1.f / lsum;
  #pragma unroll
  for (int r=0;r<16;r++){
    int qrow = (r&3) + 8*(r>>2) + 4*hi;
    float li = __shfl(linv, qrow);
    float ov = oacc[r]*li;
    if (q31 < 16)
      hattn[((long)(nbase + w*32 + qrow))*128 + h*16 + q31] = f2b(ov);
  }
}

// ---------------- residual add + LayerNorm ----------------
__global__ __launch_bounds__(256) void combine_ln_k(const void* __restrict__ a,
    const bf16* __restrict__ b, const bf16* __restrict__ c3,
    const float* __restrict__ g, const float* __restrict__ bb,
    void* __restrict__ outp, const int* __restrict__ flag,
    int a_raw, int is_final){
  const int tid = threadIdx.x;
  const int lane = tid & 63;
  const long row = (long)blockIdx.x*4 + (tid>>6);
  const long base = row*128;
  float a0, a1;
  if (a_raw && (*flag)){
    const float* ap = (const float*)a;
    a0 = ap[base+lane]; a1 = ap[base+lane+64];
  } else {
    const bf16* ap = (const bf16*)a;
    a0 = b2f(ap[base+lane]); a1 = b2f(ap[base+lane+64]);
  }
  float v0 = a0 + b2f(b[base+lane]);
  float v1 = a1 + b2f(b[base+lane+64]);
  if (c3){ v0 += b2f(c3[base+lane]); v1 += b2f(c3[base+lane+64]); }
  float s = v0 + v1;
  #pragma unroll
  for (int o=1; o<64; o<<=1) s += __shfl_xor(s, o);
  float mean = s * (1.f/128.f);
  float d0 = v0 - mean, d1 = v1 - mean;
  float q = d0*d0 + d1*d1;
  #pragma unroll
  for (int o=1; o<64; o<<=1) q += __shfl_xor(q, o);
  float r = rsqrtf(q*(1.f/128.f) + 1e-5f);
  float r0v = d0*r*g[lane]    + bb[lane];
  float r1v = d1*r*g[lane+64] + bb[lane+64];
  if (is_final && (*flag)){
    float* o = (float*)outp;
    o[base+lane]    = r0v;
    o[base+lane+64] = r1v;
  } else {
    bf16* o = (bf16*)outp;
    o[base+lane]    = f2b(r0v);
    o[base+lane+64] = f2b(r1v);
  }
}

// =====================================================================================
extern "C" void kernel_launch(void* const* d_in, const int* in_sizes, int n_in,
                              void* d_out, int out_size, void* d_ws, size_t ws_size,
                              hipStream_t stream){
  const void* x_raw   = d_in[0];
  const void* ea_raw  = d_in[1];
  const int*  ei      = (const int*)d_in[25];
  const int* srcA = ei;
  const int* dstA = ei + kE;

  char* ws = (char*)d_ws;
  size_t off = 0;
  auto alloc = [&](size_t bytes)->void*{
    void* p = ws + off;
    off = (off + bytes + 255) & ~(size_t)255;
    return p;
  };
  int*   flag    = (int*)alloc(4);
  bf16*  ea_bf   = (bf16*)alloc((size_t)kE*32*2);
  float* Wsrc_f  = (float*)alloc(16384*4);
  float* Wdst_f  = (float*)alloc(16384*4);
  float* Wedge_f = (float*)alloc(4096*4);
  float* att_f   = (float*)alloc(128*4);
  float* gatb_f  = (float*)alloc(128*4);
  float* Wq_f    = (float*)alloc(16384*4);
  float* Wk_f    = (float*)alloc(16384*4);
  float* Wv_f    = (float*)alloc(16384*4);
  float* Wo_f    = (float*)alloc(16384*4);
  float* bo_f    = (float*)alloc(128*4);
  float* We_f    = (float*)alloc(256*4);
  float* be_f    = (float*)alloc(8*4);
  float* ln1g_f  = (float*)alloc(128*4);
  float* ln1b_f  = (float*)alloc(128*4);
  float* W1_f    = (float*)alloc(32768*4);
  float* b1_f    = (float*)alloc(256*4);
  float* W2_f    = (float*)alloc(32768*4);
  float* b2_f    = (float*)alloc(128*4);
  float* ln2g_f  = (float*)alloc(128*4);
  float* ln2b_f  = (float*)alloc(128*4);
  float* bias5   = (float*)alloc(640*4);
  bf16*  Wrep5   = (bf16*)alloc((size_t)5*16384*2);
  bf16*  WoR     = (bf16*)alloc((size_t)16384*2);
  bf16*  W1R     = (bf16*)alloc((size_t)32768*2);
  bf16*  W2R     = (bf16*)alloc((size_t)32768*2);
  bf16*  WeR     = (bf16*)alloc((size_t)4096*2);
  bf16*  proj5   = (bf16*)alloc((size_t)5*kN*128*2);
  bf16* xs   = proj5;
  bf16* xd   = proj5 + (size_t)kN*128;
  bf16* qb   = proj5 + (size_t)2*kN*128;
  bf16* kbuf = proj5 + (size_t)3*kN*128;
  bf16* vbuf = proj5 + (size_t)4*kN*128;
  int* cnt        = (int*)alloc((size_t)2*kN*4);
  int* cursor     = cnt + kN;
  int* rowptr     = (int*)alloc((size_t)(kN+1)*4);
  int* eidx       = (int*)alloc((size_t)kE*4);
  unsigned short* epack = (unsigned short*)alloc((size_t)kE*2);
  float* ebuf_t   = (float*)alloc((size_t)8*kE*4);
  float* alpha_t  = (float*)alloc((size_t)kE*4*4);
  int*   src_t    = (int*)alloc((size_t)kE*4);
  bf16* h_local   = (bf16*)alloc((size_t)kN*128*2);
  bf16* hattn_pre = (bf16*)alloc((size_t)kN*128*2);
  bf16* h_attn    = (bf16*)alloc((size_t)kN*128*2);
  bf16* hbuf      = (bf16*)alloc((size_t)kN*128*2);
  bf16* tbuf      = (bf16*)alloc((size_t)kN*256*2);
  bf16* f2buf     = (bf16*)alloc((size_t)kN*128*2);
  (void)ws_size; (void)in_sizes; (void)n_in; (void)out_size;

  dim3 b256(256);

  detect_k<<<1, b256, 0, stream>>>(x_raw, flag);
  hipMemsetAsync(bias5, 0, 256*4, stream);
  hipMemsetAsync(cnt, 0, (size_t)2*kN*4, stream);

  // CSR build first (only needs dstA) so edge3 can run in CSR order
  hist_k<<<kE/256, b256, 0, stream>>>(dstA, cnt);
  scan_k<<<1, 1024, 0, stream>>>(cnt, rowptr);
  scatter_k<<<kE/256, b256, 0, stream>>>(dstA, rowptr, cursor, eidx);

  ImpArgs ia;
  const void* srcs[24] = {ea_raw, d_in[2], d_in[3], d_in[4], d_in[5], d_in[6],
                          d_in[7], d_in[8], d_in[9], d_in[10], d_in[11], d_in[12],
                          d_in[13], d_in[14], d_in[15], d_in[16], d_in[17], d_in[18],
                          d_in[19], d_in[20], d_in[21], d_in[22], d_in[23], d_in[24]};
  void* dsts[24] = {ea_bf, Wsrc_f, Wdst_f, Wedge_f, att_f, gatb_f,
                    Wq_f, bias5+256, Wk_f, bias5+384, Wv_f, bias5+512,
                    Wo_f, bo_f, We_f, be_f, ln1g_f, ln1b_f,
                    W1_f, b1_f, W2_f, b2_f, ln2g_f, ln2b_f};
  int ns[24] = {kE*32, 16384, 16384, 4096, 128, 128,
                16384, 128, 16384, 128, 16384, 128,
                16384, 128, 256, 8, 128, 128,
                32768, 256, 32768, 128, 128, 128};
  int isbf[24] = {1, 0,0,0,0,0, 0,0,0,0,0,0, 0,0,0,0,0,0, 0,0,0,0,0,0};
  for (int i=0;i<24;i++){ ia.e[i].src=srcs[i]; ia.e[i].dst=dsts[i]; ia.e[i].n=ns[i]; ia.e[i].dst_bf16=isbf[i]; }
  import_k<<<dim3(512,24), b256, 0, stream>>>(ia, flag);

  repack5_k<<<(5*16384)/256, b256, 0, stream>>>(Wsrc_f, Wdst_f, Wq_f, Wk_f, Wv_f, Wrep5);
  RepEnt ro{Wo_f, WoR, 16384, 3, 128};
  RepEnt r1{W1_f, W1R, 32768, 4, 256};
  RepEnt r2{W2_f, W2R, 32768, 3, 128};
  RepEnt re{Wedge_f, WeR, 4096, 3, 128};
  repack_k<<<dim3(128,4), b256, 0, stream>>>(ro, r1, r2, re);

  gemm5_k<<<kN/64, b256, 0, stream>>>(x_raw, flag, Wrep5, bias5, proj5);

  edge3_k<<<kE/64, b256, 0, stream>>>(ea_bf, eidx, srcA, dstA, xs, xd,
                                      WeR, We_f, att_f, be_f,
                                      alpha_t, ebuf_t, epack, src_t);

  gat_agg_k<<<kN, dim3(128), 0, stream>>>(alpha_t, rowptr, src_t, xs, gatb_f, h_local);

  attn2_k<<<kG*kHA, dim3(512), 0, stream>>>(qb, kbuf, vbuf, ebuf_t, epack, rowptr, hattn_pre);
  gemm_mfma_k<128,128,1><<<kN/64, b256, 0, stream>>>(hattn_pre, WoR, bo_f, h_attn);

  combine_ln_k<<<kN/4, b256, 0, stream>>>(x_raw, h_local, h_attn, ln1g_f, ln1b_f,
                                          hbuf, flag, 1, 0);

  gemm_mfma_k<128,256,2><<<kN/64, b256, 0, stream>>>(hbuf, W1R, b1_f, tbuf);
  gemm_mfma_k<256,128,1><<<kN/64, b256, 0, stream>>>(tbuf, W2R, b2_f, f2buf);

  combine_ln_k<<<kN/4, b256, 0, stream>>>(hbuf, f2buf, nullptr, ln2g_f, ln2b_f,
                                          d_out, flag, 0, 1);
}

// Round 8
// 288.522 us; speedup vs baseline: 2.6478x; 1.1337x over previous
//
#include <hip/hip_runtime.h>
#include <hip/hip_bf16.h>

typedef __hip_bfloat16 bf16;
typedef __hip_bfloat162 bf162;
typedef __attribute__((ext_vector_type(8))) short short8;
typedef __attribute__((ext_vector_type(4))) float f32x4;
typedef __attribute__((ext_vector_type(16))) float f32x16;

constexpr int kN   = 32768;   // nodes
constexpr int kG   = 128;     // graphs
constexpr int kE   = 262144;  // edges
constexpr int kHA  = 8;       // global attn heads

__device__ __forceinline__ float b2f(bf16 v){ return __bfloat162float(v); }
__device__ __forceinline__ bf16  f2b(float v){ return __float2bfloat16(v); }
__device__ __forceinline__ float b2f_raw(unsigned short u){
  return __uint_as_float((unsigned)u << 16);
}
__device__ __forceinline__ float tanh_fast(float x){
  float e = __expf(2.f*x);
  return 1.f - 2.f/(e+1.f);
}
__device__ __forceinline__ unsigned int cvtpk_bf16(float lo, float hi){
  unsigned int r;
  asm volatile("v_cvt_pk_bf16_f32 %0, %1, %2" : "=v"(r) : "v"(lo), "v"(hi));
  return r;
}
__device__ __forceinline__ void plane_swap(unsigned int &a, unsigned int &b){
  asm volatile("v_permlane32_swap_b32 %0, %1" : "+v"(a), "+v"(b));
}

// ---------------- input dtype detection (bf16 vs fp32 device buffers) ----------------
__global__ void detect_k(const void* xraw, int* flag){
  const bf16* p = (const bf16*)xraw;
  int good = 0;
  for (int i = threadIdx.x; i < 4096; i += 256){
    float v = fabsf(b2f(p[i]));
    if (v > 0.0009765625f && v < 16.f) good++;
  }
  __shared__ int s[256];
  s[threadIdx.x] = good;
  __syncthreads();
  for (int d = 128; d; d >>= 1){
    if (threadIdx.x < d) s[threadIdx.x] += s[threadIdx.x + d];
    __syncthreads();
  }
  if (threadIdx.x == 0) *flag = (s[0] < 3500) ? 1 : 0;
}

// ---------------- import ----------------
struct ImpEnt { const void* src; void* dst; int n; int dst_bf16; };
struct ImpArgs { ImpEnt e[24]; };
__global__ __launch_bounds__(256) void import_k(ImpArgs a, const int* __restrict__ flag){
  ImpEnt en = a.e[blockIdx.y];
  const bool f32 = (*flag != 0);
  for (int i = blockIdx.x*256 + threadIdx.x; i < en.n; i += gridDim.x*256){
    float v = f32 ? ((const float*)en.src)[i] : b2f(((const bf16*)en.src)[i]);
    if (en.dst_bf16) ((bf16*)en.dst)[i] = f2b(v);
    else             ((float*)en.dst)[i] = v;
  }
}

// ---------------- weight repack to MFMA-B fragment layout ----------------
__global__ __launch_bounds__(256) void repack5_k(const float* __restrict__ W0,
    const float* __restrict__ W1p, const float* __restrict__ W2p,
    const float* __restrict__ W3p, const float* __restrict__ W4p,
    bf16* __restrict__ dst){
  int idx = blockIdx.x*256 + threadIdx.x;
  const float* Ws[5] = {W0, W1p, W2p, W3p, W4p};
  int o = idx >> 14;
  int rem = idx & 16383;
  int j = rem & 7, l = (rem >> 3) & 63, t = rem >> 9;
  int ks = t >> 3, cb = t & 7;
  int k = ks*32 + (l>>4)*8 + j;
  int c = cb*16 + (l&15);
  dst[idx] = f2b(Ws[o][k*128 + c]);
}

struct RepEnt { const float* src; bf16* dst; int total; int ncb_log; int dout; };
__global__ __launch_bounds__(256) void repack_k(RepEnt e0, RepEnt e1, RepEnt e2, RepEnt e3){
  RepEnt en = (blockIdx.y == 0) ? e0 : (blockIdx.y == 1) ? e1 :
              (blockIdx.y == 2) ? e2 : e3;
  int idx = blockIdx.x*256 + threadIdx.x;
  if (idx >= en.total) return;
  int j = idx & 7, l = (idx >> 3) & 63, t = idx >> 9;
  int ncbm = (1 << en.ncb_log) - 1;
  int ks = t >> en.ncb_log, cb = t & ncbm;
  int k = ks*32 + (l>>4)*8 + j;
  int c = cb*16 + (l&15);
  en.dst[idx] = f2b(en.src[k*en.dout + c]);
}

// ---------------- fused 5-way projection GEMM (reads raw x, dtype-flag branch) -------
__global__ __launch_bounds__(256) void gemm5_k(const void* __restrict__ xraw,
    const int* __restrict__ flag,
    const bf16* __restrict__ Wrep, const float* __restrict__ bias5,
    bf16* __restrict__ proj5){
  const int tid = threadIdx.x;
  const int wid = tid >> 6, l = tid & 63;
  const long r0 = (long)blockIdx.x*64 + wid*16;
  const bool f32 = (*flag != 0);
  short8 af[4];
  if (f32){
    const float* fr = (const float*)xraw + (r0 + (l&15))*128;
    #pragma unroll
    for (int ks=0; ks<4; ks++){
      float4 a = *(const float4*)(fr + ks*32 + (l>>4)*8);
      float4 b = *(const float4*)(fr + ks*32 + (l>>4)*8 + 4);
      union{ unsigned int u[4]; short8 s; } c;
      c.u[0]=cvtpk_bf16(a.x,a.y); c.u[1]=cvtpk_bf16(a.z,a.w);
      c.u[2]=cvtpk_bf16(b.x,b.y); c.u[3]=cvtpk_bf16(b.z,b.w);
      af[ks] = c.s;
    }
  } else {
    const short* Arow = (const short*)xraw + (r0 + (l&15))*128;
    #pragma unroll
    for (int ks=0; ks<4; ks++)
      af[ks] = *(const short8*)(Arow + ks*32 + (l>>4)*8);
  }
  const short8* Wp = (const short8*)Wrep;
  const int cc = l & 15, rr = (l >> 4) * 4;
  #pragma unroll 1
  for (int o=0; o<5; o++){
    f32x4 acc[8];
    #pragma unroll
    for (int cb=0; cb<8; cb++) acc[cb] = (f32x4){0.f,0.f,0.f,0.f};
    #pragma unroll
    for (int ks=0; ks<4; ks++){
      #pragma unroll
      for (int cb=0; cb<8; cb++){
        short8 bf = Wp[(o*32 + ks*8 + cb)*64 + l];
        acc[cb] = __builtin_amdgcn_mfma_f32_16x16x32_bf16(af[ks], bf, acc[cb], 0,0,0);
      }
    }
    bf16* outb = proj5 + (long)o*kN*128;
    #pragma unroll
    for (int cb=0; cb<8; cb++){
      float bb = bias5[o*128 + cb*16 + cc];
      #pragma unroll
      for (int r=0; r<4; r++){
        long row = r0 + rr + r;
        outb[row*128 + cb*16 + cc] = f2b(acc[cb][r] + bb);
      }
    }
  }
}

// ---------------- generic MFMA GEMM ----------------
template<int DIN, int DOUT, int EPI>
__global__ __launch_bounds__(256) void gemm_mfma_k(const bf16* __restrict__ A,
    const bf16* __restrict__ Wrep, const float* __restrict__ bias,
    bf16* __restrict__ C){
  constexpr int KS = DIN/32, NCB = DOUT/16;
  const int tid = threadIdx.x;
  const int wid = tid >> 6, l = tid & 63;
  const long r0 = (long)blockIdx.x*64 + wid*16;
  const short* Arow = (const short*)(A + (r0 + (l&15))*(long)DIN);
  short8 af[KS];
  #pragma unroll
  for (int ks=0; ks<KS; ks++)
    af[ks] = *(const short8*)(Arow + ks*32 + (l>>4)*8);
  f32x4 acc[NCB];
  #pragma unroll
  for (int cb=0; cb<NCB; cb++) acc[cb] = (f32x4){0.f,0.f,0.f,0.f};
  const short8* Wp = (const short8*)Wrep;
  #pragma unroll
  for (int ks=0; ks<KS; ks++){
    #pragma unroll
    for (int cb=0; cb<NCB; cb++){
      short8 bf = Wp[(ks*NCB + cb)*64 + l];
      acc[cb] = __builtin_amdgcn_mfma_f32_16x16x32_bf16(af[ks], bf, acc[cb], 0,0,0);
    }
  }
  const int cc = l & 15, rr = (l >> 4) * 4;
  #pragma unroll
  for (int cb=0; cb<NCB; cb++){
    float bb = bias[cb*16 + cc];
    #pragma unroll
    for (int r=0; r<4; r++){
      long row = r0 + rr + r;
      float v = acc[cb][r] + bb;
      if (EPI == 2) v = 0.5f*v*(1.f + erff(v*0.70710678118654752f));
      C[row*DOUT + cb*16 + cc] = f2b(v);
    }
  }
}

// ---------------- CSR build ----------------
__global__ void hist_k(const int* __restrict__ dstA, int* __restrict__ cnt){
  int e = blockIdx.x*256 + threadIdx.x;
  if (e < kE) atomicAdd(&cnt[dstA[e]], 1);
}

__global__ __launch_bounds__(1024) void scan_k(const int* __restrict__ cnt, int* __restrict__ rowptr){
  __shared__ int part[1024];
  const int t = threadIdx.x;
  const int base = t*32;
  int s = 0;
  #pragma unroll
  for (int i=0;i<32;i++) s += cnt[base+i];
  part[t] = s;
  __syncthreads();
  for (int d=1; d<1024; d<<=1){
    int v = (t>=d) ? part[t-d] : 0;
    __syncthreads();
    part[t] += v;
    __syncthreads();
  }
  int run = (t==0) ? 0 : part[t-1];
  for (int i=0;i<32;i++){ rowptr[base+i] = run; run += cnt[base+i]; }
  if (t == 1023) rowptr[kN] = run;
}

__global__ void scatter_k(const int* __restrict__ dstA, const int* __restrict__ rowptr,
                          int* __restrict__ cursor, int* __restrict__ eidx){
  int e = blockIdx.x*256 + threadIdx.x;
  if (e < kE){
    int d = dstA[e];
    int p = atomicAdd(&cursor[d], 1);
    eidx[rowptr[d]+p] = e;
  }
}

// ---------------- edge3: CSR-ordered, MFMA edge GEMM + staged gather; 64 edges/block
// stores EXP(alpha) (|alpha|<=~14, exp safe in fp32; max-subtraction unnecessary)
__global__ __launch_bounds__(256) void edge3_k(const bf16* __restrict__ ea,
    const int* __restrict__ eidx, const int* __restrict__ srcA,
    const int* __restrict__ dstA,
    const bf16* __restrict__ xs, const bf16* __restrict__ xd,
    const bf16* __restrict__ WeR_edge,
    const float* __restrict__ We_f, const float* __restrict__ att_f,
    const float* __restrict__ be_f,
    float* __restrict__ expal_t, float* __restrict__ ebuf_t,
    unsigned short* __restrict__ epack, int* __restrict__ src_t){
  __shared__ unsigned short sxd[64*132];   // 16.9 KB
  __shared__ float sWe[256];
  __shared__ float sAtt[128];
  __shared__ float sBe[8];
  __shared__ int   sEid[64], sSrc[64], sDst[64];
  __shared__ float sAlphaF[64*4];
  const int tid = threadIdx.x;
  const int w = tid >> 6, l = tid & 63;
  const long t0 = (long)blockIdx.x * 64;

  if (tid < 64){
    int e = eidx[t0 + tid];
    int s = srcA[e], d = dstA[e];
    sEid[tid] = e; sSrc[tid] = s; sDst[tid] = d;
    src_t[t0 + tid] = s;
    epack[t0 + tid] = (unsigned short)(((s & 255) << 8) | (d & 255));
  }
  if (tid < 256) sWe[tid] = We_f[tid];
  if (tid < 128) sAtt[tid] = att_f[tid];
  else if (tid < 136) sBe[tid-128] = be_f[tid-128];
  __syncthreads();

  // MFMA operands: A = 16 edge rows per wave (via eidx), B = W_edge frags
  const short* eap = (const short*)ea;
  short8 af = *(const short8*)(eap + (long)sEid[w*16 + (l&15)]*32 + (l>>4)*8);
  short8 wb[8];
  #pragma unroll
  for (int cb=0; cb<8; cb++)
    wb[cb] = *(const short8*)((const short*)WeR_edge + (cb*64 + l)*8);

  // stage xs[src]+xd[dst] -> sxd
  {
    const int c0 = (tid & 31) * 4;
    const int rb = tid >> 5;
    const unsigned short* xsu = (const unsigned short*)xs;
    const unsigned short* xdu = (const unsigned short*)xd;
    #pragma unroll 4
    for (int p = 0; p < 8; p++){
      int row = p*8 + rb;
      long s = sSrc[row], dd = sDst[row];
      ushort4 a = *(const ushort4*)(xsu + s*128 + c0);
      ushort4 b = *(const ushort4*)(xdu + dd*128 + c0);
      unsigned int lo = cvtpk_bf16(b2f_raw(a.x)+b2f_raw(b.x), b2f_raw(a.y)+b2f_raw(b.y));
      unsigned int hi = cvtpk_bf16(b2f_raw(a.z)+b2f_raw(b.z), b2f_raw(a.w)+b2f_raw(b.w));
      *(uint2*)&sxd[row*132 + c0] = (uint2){lo, hi};
    }
  }

  // ef = ea @ W_edge via MFMA
  f32x4 acc[8];
  #pragma unroll
  for (int cb=0; cb<8; cb++)
    acc[cb] = __builtin_amdgcn_mfma_f32_16x16x32_bf16(af, wb[cb],
                (f32x4){0.f,0.f,0.f,0.f}, 0,0,0);

  // eb = ea @ We + be
  {
    int e_eb = tid >> 2, h0 = (tid & 3) * 2;
    const unsigned short* earow = (const unsigned short*)ea + (long)sEid[e_eb]*32;
    float a0 = sBe[h0], a1 = sBe[h0+1];
    #pragma unroll
    for (int dq=0; dq<8; dq++){
      ushort4 u = *(const ushort4*)(earow + dq*4);
      float f0 = b2f_raw(u.x), f1 = b2f_raw(u.y), f2 = b2f_raw(u.z), f3 = b2f_raw(u.w);
      a0 += f0*sWe[(dq*4+0)*8 + h0]   + f1*sWe[(dq*4+1)*8 + h0]
          + f2*sWe[(dq*4+2)*8 + h0]   + f3*sWe[(dq*4+3)*8 + h0];
      a1 += f0*sWe[(dq*4+0)*8 + h0+1] + f1*sWe[(dq*4+1)*8 + h0+1]
          + f2*sWe[(dq*4+2)*8 + h0+1] + f3*sWe[(dq*4+3)*8 + h0+1];
    }
    ebuf_t[(long)h0*kE     + t0 + e_eb] = a0;
    ebuf_t[(long)(h0+1)*kE + t0 + e_eb] = a1;
  }
  __syncthreads();   // sxd ready

  // epilogue: tanh(ef + sxd) * att, per-head 16-lane reduce, store exp(alpha)
  #pragma unroll
  for (int r=0; r<4; r++){
    int e_l = w*16 + (l>>4)*4 + r;
    float hp[4] = {0.f,0.f,0.f,0.f};
    #pragma unroll
    for (int cb=0; cb<8; cb++){
      int ch = cb*16 + (l&15);
      float v = acc[cb][r] + b2f_raw(sxd[e_l*132 + ch]);
      v = tanh_fast(v) * sAtt[ch];
      hp[cb>>1] += v;
    }
    #pragma unroll
    for (int hh=0; hh<4; hh++){
      float sv = hp[hh];
      sv += __shfl_xor(sv,1); sv += __shfl_xor(sv,2);
      sv += __shfl_xor(sv,4); sv += __shfl_xor(sv,8);
      if ((l&15) == 0) sAlphaF[e_l*4 + hh] = __expf(sv);
    }
  }
  __syncthreads();
  if (tid < 64)
    *(float4*)&expal_t[(t0 + tid)*4] = *(float4*)&sAlphaF[tid*4];
}

// ---------------- GAT aggregate: 32 lanes/node, 4 ch/lane, single pass (no max) -----
__global__ __launch_bounds__(256) void gat_agg_k(const float* __restrict__ expal,
    const int* __restrict__ rowptr, const int* __restrict__ src_t,
    const bf16* __restrict__ xs, const float* __restrict__ gatb_f,
    bf16* __restrict__ h_local){
  const int tid = threadIdx.x;
  const int grp = tid >> 5;             // 8 nodes per block
  const int l   = tid & 31;
  const int v   = blockIdx.x*8 + grp;
  const int c0  = l*4;
  const int head = l >> 3;
  const int beg = rowptr[v], end = rowptr[v+1];
  float den = 0.f, o0 = 0.f, o1 = 0.f, o2 = 0.f, o3 = 0.f;
  const unsigned short* xsu = (const unsigned short*)xs;
  for (int t = beg; t < end; t++){
    float w = expal[(long)t*4 + head];
    long s = src_t[t];
    ushort4 a = *(const ushort4*)(xsu + s*128 + c0);
    den += w;
    o0 += w*b2f_raw(a.x); o1 += w*b2f_raw(a.y);
    o2 += w*b2f_raw(a.z); o3 += w*b2f_raw(a.w);
  }
  float inv = 1.f/(den + 1e-16f);       // deg=0: o*==0 -> result 0
  float4 gb = *(const float4*)(gatb_f + c0);
  unsigned int lo = cvtpk_bf16(o0*inv + gb.x, o1*inv + gb.y);
  unsigned int hi = cvtpk_bf16(o2*inv + gb.z, o3*inv + gb.w);
  *(uint2*)&((unsigned short*)h_local)[(long)v*128 + c0] = (uint2){lo, hi};
}

// ---------------- MFMA flash attention: block=(g,h), 8 waves, wave = 32-query tile --
__global__ __launch_bounds__(512, 6) void attn2_k(const bf16* __restrict__ qb,
    const bf16* __restrict__ kb, const bf16* __restrict__ vb,
    const float* __restrict__ ebuf_t, const unsigned short* __restrict__ epack,
    const int* __restrict__ rowptr, bf16* __restrict__ hattn){
  __shared__ short Vf[16*64*8];     // 16 KB
  __shared__ float sb[256*33];      // 33.8 KB
  const int bid = blockIdx.x;
  const int h = (bid >> 3) >> 4;
  const int g = (((bid >> 3) & 15) << 3) | (bid & 7);
  const int tid = threadIdx.x;
  const int w = tid >> 6, l = tid & 63;
  const int q31 = l & 31, hi = l >> 5;
  const int nbase = g << 8;

  for (int s2 = tid; s2 < 1024; s2 += 512){
    int f = s2 >> 6, ll = s2 & 63;
    int keyb = (f>>1)*32 + (f&1)*16 + ((ll>>5)*8);
    int d = ll & 15;
    short tmp[8];
    #pragma unroll
    for (int j=0;j<8;j++)
      tmp[j] = ((const short*)vb)[((long)(nbase + keyb + j))*128 + h*16 + d];
    *(short8*)&Vf[s2*8] = *(short8*)tmp;
  }
  for (int i = tid; i < 256*33; i += 512) sb[i] = 0.f;
  short8 qf = *(const short8*)((const short*)qb + ((long)(nbase + w*32 + q31))*128 + h*16 + hi*8);
  __syncthreads();

  float m = -1e30f, lsum = 0.f;
  f32x16 oacc = {0.f,0.f,0.f,0.f,0.f,0.f,0.f,0.f,0.f,0.f,0.f,0.f,0.f,0.f,0.f,0.f};
  #pragma unroll 1
  for (int kt = 0; kt < 8; kt++){
    int rb = rowptr[nbase + kt*32];
    int re = rowptr[nbase + kt*32 + 32];
    for (int t = rb + tid; t < re; t += 512){
      unsigned int p = epack[t];
      atomicAdd(&sb[(p>>8)*33 + (p&31)], ebuf_t[(long)h*kE + t]);
    }
    __syncthreads();
    short8 af = *(const short8*)((const short*)kb +
                 ((long)(nbase + kt*32 + q31))*128 + h*16 + hi*8);
    f32x16 acc = {0.f,0.f,0.f,0.f,0.f,0.f,0.f,0.f,0.f,0.f,0.f,0.f,0.f,0.f,0.f,0.f};
    acc = __builtin_amdgcn_mfma_f32_32x32x16_bf16(af, qf, acc, 0, 0, 0);
    float s[16];
    float* brow = &sb[(w*32 + q31)*33];
    #pragma unroll
    for (int r=0;r<16;r++){
      int krow = (r&3) + 8*(r>>2) + 4*hi;
      s[r] = acc[r]*0.25f + brow[krow];
      brow[krow] = 0.f;
    }
    __syncthreads();
    float tmax = s[0];
    #pragma unroll
    for (int r=1;r<16;r++) tmax = fmaxf(tmax, s[r]);
    tmax = fmaxf(tmax, __shfl_xor(tmax, 32));
    float mn = fmaxf(m, tmax);
    float corrq = __expf(m - mn);
    m = mn;
    float psum = 0.f;
    #pragma unroll
    for (int r=0;r<16;r++){ s[r] = __expf(s[r] - m); psum += s[r]; }
    lsum = lsum*corrq + psum;
    #pragma unroll
    for (int r=0;r<16;r++){
      int qrow = (r&3) + 8*(r>>2) + 4*hi;
      oacc[r] *= __shfl(corrq, qrow);
    }
    unsigned int a  = cvtpk_bf16(s[0],  s[1]);
    unsigned int b  = cvtpk_bf16(s[2],  s[3]);
    unsigned int c  = cvtpk_bf16(s[4],  s[5]);
    unsigned int d  = cvtpk_bf16(s[6],  s[7]);
    unsigned int e  = cvtpk_bf16(s[8],  s[9]);
    unsigned int f  = cvtpk_bf16(s[10], s[11]);
    unsigned int g2 = cvtpk_bf16(s[12], s[13]);
    unsigned int h2 = cvtpk_bf16(s[14], s[15]);
    plane_swap(a, c); plane_swap(b, d); plane_swap(e, g2); plane_swap(f, h2);
    union { unsigned int u[4]; short8 s8; } A1, A2;
    A1.u[0]=a; A1.u[1]=b; A1.u[2]=c; A1.u[3]=d;
    A2.u[0]=e; A2.u[1]=f; A2.u[2]=g2; A2.u[3]=h2;
    short8 v1 = *(short8*)&Vf[((kt*2+0)*64 + l)*8];
    short8 v2 = *(short8*)&Vf[((kt*2+1)*64 + l)*8];
    oacc = __builtin_amdgcn_mfma_f32_32x32x16_bf16(A1.s8, v1, oacc, 0,0,0);
    oacc = __builtin_amdgcn_mfma_f32_32x32x16_bf16(A2.s8, v2, oacc, 0,0,0);
  }
  lsum += __shfl_xor(lsum, 32);
  float linv = 1.f / lsum;
  #pragma unroll
  for (int r=0;r<16;r++){
    int qrow = (r&3) + 8*(r>>2) + 4*hi;
    float li = __shfl(linv, qrow);
    float ov = oacc[r]*li;
    if (q31 < 16)
      hattn[((long)(nbase + w*32 + qrow))*128 + h*16 + q31] = f2b(ov);
  }
}

// ---------------- residual add + LayerNorm ----------------
__global__ __launch_bounds__(256) void combine_ln_k(const void* __restrict__ a,
    const bf16* __restrict__ b, const bf16* __restrict__ c3,
    const float* __restrict__ g, const float* __restrict__ bb,
    void* __restrict__ outp, const int* __restrict__ flag,
    int a_raw, int is_final){
  const int tid = threadIdx.x;
  const int lane = tid & 63;
  const long row = (long)blockIdx.x*4 + (tid>>6);
  const long base = row*128;
  float a0, a1;
  if (a_raw && (*flag)){
    const float* ap = (const float*)a;
    a0 = ap[base+lane]; a1 = ap[base+lane+64];
  } else {
    const bf16* ap = (const bf16*)a;
    a0 = b2f(ap[base+lane]); a1 = b2f(ap[base+lane+64]);
  }
  float v0 = a0 + b2f(b[base+lane]);
  float v1 = a1 + b2f(b[base+lane+64]);
  if (c3){ v0 += b2f(c3[base+lane]); v1 += b2f(c3[base+lane+64]); }
  float s = v0 + v1;
  #pragma unroll
  for (int o=1; o<64; o<<=1) s += __shfl_xor(s, o);
  float mean = s * (1.f/128.f);
  float d0 = v0 - mean, d1 = v1 - mean;
  float q = d0*d0 + d1*d1;
  #pragma unroll
  for (int o=1; o<64; o<<=1) q += __shfl_xor(q, o);
  float r = rsqrtf(q*(1.f/128.f) + 1e-5f);
  float r0v = d0*r*g[lane]    + bb[lane];
  float r1v = d1*r*g[lane+64] + bb[lane+64];
  if (is_final && (*flag)){
    float* o = (float*)outp;
    o[base+lane]    = r0v;
    o[base+lane+64] = r1v;
  } else {
    bf16* o = (bf16*)outp;
    o[base+lane]    = f2b(r0v);
    o[base+lane+64] = f2b(r1v);
  }
}

// =====================================================================================
extern "C" void kernel_launch(void* const* d_in, const int* in_sizes, int n_in,
                              void* d_out, int out_size, void* d_ws, size_t ws_size,
                              hipStream_t stream){
  const void* x_raw   = d_in[0];
  const void* ea_raw  = d_in[1];
  const int*  ei      = (const int*)d_in[25];
  const int* srcA = ei;
  const int* dstA = ei + kE;

  char* ws = (char*)d_ws;
  size_t off = 0;
  auto alloc = [&](size_t bytes)->void*{
    void* p = ws + off;
    off = (off + bytes + 255) & ~(size_t)255;
    return p;
  };
  int*   flag    = (int*)alloc(4);
  bf16*  ea_bf   = (bf16*)alloc((size_t)kE*32*2);
  float* Wsrc_f  = (float*)alloc(16384*4);
  float* Wdst_f  = (float*)alloc(16384*4);
  float* Wedge_f = (float*)alloc(4096*4);
  float* att_f   = (float*)alloc(128*4);
  float* gatb_f  = (float*)alloc(128*4);
  float* Wq_f    = (float*)alloc(16384*4);
  float* Wk_f    = (float*)alloc(16384*4);
  float* Wv_f    = (float*)alloc(16384*4);
  float* Wo_f    = (float*)alloc(16384*4);
  float* bo_f    = (float*)alloc(128*4);
  float* We_f    = (float*)alloc(256*4);
  float* be_f    = (float*)alloc(8*4);
  float* ln1g_f  = (float*)alloc(128*4);
  float* ln1b_f  = (float*)alloc(128*4);
  float* W1_f    = (float*)alloc(32768*4);
  float* b1_f    = (float*)alloc(256*4);
  float* W2_f    = (float*)alloc(32768*4);
  float* b2_f    = (float*)alloc(128*4);
  float* ln2g_f  = (float*)alloc(128*4);
  float* ln2b_f  = (float*)alloc(128*4);
  float* bias5   = (float*)alloc(640*4);
  bf16*  Wrep5   = (bf16*)alloc((size_t)5*16384*2);
  bf16*  WoR     = (bf16*)alloc((size_t)16384*2);
  bf16*  W1R     = (bf16*)alloc((size_t)32768*2);
  bf16*  W2R     = (bf16*)alloc((size_t)32768*2);
  bf16*  WeR     = (bf16*)alloc((size_t)4096*2);
  bf16*  proj5   = (bf16*)alloc((size_t)5*kN*128*2);
  bf16* xs   = proj5;
  bf16* xd   = proj5 + (size_t)kN*128;
  bf16* qb   = proj5 + (size_t)2*kN*128;
  bf16* kbuf = proj5 + (size_t)3*kN*128;
  bf16* vbuf = proj5 + (size_t)4*kN*128;
  int* cnt        = (int*)alloc((size_t)2*kN*4);
  int* cursor     = cnt + kN;
  int* rowptr     = (int*)alloc((size_t)(kN+1)*4);
  int* eidx       = (int*)alloc((size_t)kE*4);
  unsigned short* epack = (unsigned short*)alloc((size_t)kE*2);
  float* ebuf_t   = (float*)alloc((size_t)8*kE*4);
  float* expal_t  = (float*)alloc((size_t)kE*4*4);
  int*   src_t    = (int*)alloc((size_t)kE*4);
  bf16* h_local   = (bf16*)alloc((size_t)kN*128*2);
  bf16* hattn_pre = (bf16*)alloc((size_t)kN*128*2);
  bf16* h_attn    = (bf16*)alloc((size_t)kN*128*2);
  bf16* hbuf      = (bf16*)alloc((size_t)kN*128*2);
  bf16* tbuf      = (bf16*)alloc((size_t)kN*256*2);
  bf16* f2buf     = (bf16*)alloc((size_t)kN*128*2);
  (void)ws_size; (void)in_sizes; (void)n_in; (void)out_size;

  dim3 b256(256);

  detect_k<<<1, b256, 0, stream>>>(x_raw, flag);
  hipMemsetAsync(bias5, 0, 256*4, stream);
  hipMemsetAsync(cnt, 0, (size_t)2*kN*4, stream);

  // CSR build first (only needs dstA) so edge3 can run in CSR order
  hist_k<<<kE/256, b256, 0, stream>>>(dstA, cnt);
  scan_k<<<1, 1024, 0, stream>>>(cnt, rowptr);
  scatter_k<<<kE/256, b256, 0, stream>>>(dstA, rowptr, cursor, eidx);

  ImpArgs ia;
  const void* srcs[24] = {ea_raw, d_in[2], d_in[3], d_in[4], d_in[5], d_in[6],
                          d_in[7], d_in[8], d_in[9], d_in[10], d_in[11], d_in[12],
                          d_in[13], d_in[14], d_in[15], d_in[16], d_in[17], d_in[18],
                          d_in[19], d_in[20], d_in[21], d_in[22], d_in[23], d_in[24]};
  void* dsts[24] = {ea_bf, Wsrc_f, Wdst_f, Wedge_f, att_f, gatb_f,
                    Wq_f, bias5+256, Wk_f, bias5+384, Wv_f, bias5+512,
                    Wo_f, bo_f, We_f, be_f, ln1g_f, ln1b_f,
                    W1_f, b1_f, W2_f, b2_f, ln2g_f, ln2b_f};
  int ns[24] = {kE*32, 16384, 16384, 4096, 128, 128,
                16384, 128, 16384, 128, 16384, 128,
                16384, 128, 256, 8, 128, 128,
                32768, 256, 32768, 128, 128, 128};
  int isbf[24] = {1, 0,0,0,0,0, 0,0,0,0,0,0, 0,0,0,0,0,0, 0,0,0,0,0,0};
  for (int i=0;i<24;i++){ ia.e[i].src=srcs[i]; ia.e[i].dst=dsts[i]; ia.e[i].n=ns[i]; ia.e[i].dst_bf16=isbf[i]; }
  import_k<<<dim3(512,24), b256, 0, stream>>>(ia, flag);

  repack5_k<<<(5*16384)/256, b256, 0, stream>>>(Wsrc_f, Wdst_f, Wq_f, Wk_f, Wv_f, Wrep5);
  RepEnt ro{Wo_f, WoR, 16384, 3, 128};
  RepEnt r1{W1_f, W1R, 32768, 4, 256};
  RepEnt r2{W2_f, W2R, 32768, 3, 128};
  RepEnt re{Wedge_f, WeR, 4096, 3, 128};
  repack_k<<<dim3(128,4), b256, 0, stream>>>(ro, r1, r2, re);

  gemm5_k<<<kN/64, b256, 0, stream>>>(x_raw, flag, Wrep5, bias5, proj5);

  edge3_k<<<kE/64, b256, 0, stream>>>(ea_bf, eidx, srcA, dstA, xs, xd,
                                      WeR, We_f, att_f, be_f,
                                      expal_t, ebuf_t, epack, src_t);

  gat_agg_k<<<kN/8, b256, 0, stream>>>(expal_t, rowptr, src_t, xs, gatb_f, h_local);

  attn2_k<<<kG*kHA, dim3(512), 0, stream>>>(qb, kbuf, vbuf, ebuf_t, epack, rowptr, hattn_pre);
  gemm_mfma_k<128,128,1><<<kN/64, b256, 0, stream>>>(hattn_pre, WoR, bo_f, h_attn);

  combine_ln_k<<<kN/4, b256, 0, stream>>>(x_raw, h_local, h_attn, ln1g_f, ln1b_f,
                                          hbuf, flag, 1, 0);

  gemm_mfma_k<128,256,2><<<kN/64, b256, 0, stream>>>(hbuf, W1R, b1_f, tbuf);
  gemm_mfma_k<256,128,1><<<kN/64, b256, 0, stream>>>(tbuf, W2R, b2_f, f2buf);

  combine_ln_k<<<kN/4, b256, 0, stream>>>(hbuf, f2buf, nullptr, ln2g_f, ln2b_f,
                                          d_out, flag, 0, 1);
}

// Round 9
// 260.999 us; speedup vs baseline: 2.9270x; 1.1055x over previous
//
#include <hip/hip_runtime.h>
#include <hip/hip_bf16.h>

typedef __hip_bfloat16 bf16;
typedef __hip_bfloat162 bf162;
typedef __attribute__((ext_vector_type(8))) short short8;
typedef __attribute__((ext_vector_type(4))) float f32x4;
typedef __attribute__((ext_vector_type(16))) float f32x16;

constexpr int kN   = 32768;   // nodes
constexpr int kG   = 128;     // graphs
constexpr int kE   = 262144;  // edges
constexpr int kHA  = 8;       // global attn heads

__device__ __forceinline__ float b2f(bf16 v){ return __bfloat162float(v); }
__device__ __forceinline__ bf16  f2b(float v){ return __float2bfloat16(v); }
__device__ __forceinline__ float b2f_raw(unsigned short u){
  return __uint_as_float((unsigned)u << 16);
}
__device__ __forceinline__ float tanh_fast(float x){
  float e = __expf(2.f*x);
  return 1.f - 2.f/(e+1.f);
}
__device__ __forceinline__ unsigned int cvtpk_bf16(float lo, float hi){
  unsigned int r;
  asm volatile("v_cvt_pk_bf16_f32 %0, %1, %2" : "=v"(r) : "v"(lo), "v"(hi));
  return r;
}
__device__ __forceinline__ void plane_swap(unsigned int &a, unsigned int &b){
  asm volatile("v_permlane32_swap_b32 %0, %1" : "+v"(a), "+v"(b));
}

// ---------------- input dtype detection (bf16 vs fp32 device buffers) ----------------
__global__ void detect_k(const void* xraw, int* flag){
  const bf16* p = (const bf16*)xraw;
  int good = 0;
  for (int i = threadIdx.x; i < 4096; i += 256){
    float v = fabsf(b2f(p[i]));
    if (v > 0.0009765625f && v < 16.f) good++;
  }
  __shared__ int s[256];
  s[threadIdx.x] = good;
  __syncthreads();
  for (int d = 128; d; d >>= 1){
    if (threadIdx.x < d) s[threadIdx.x] += s[threadIdx.x + d];
    __syncthreads();
  }
  if (threadIdx.x == 0) *flag = (s[0] < 3500) ? 1 : 0;
}

// ---------------- import (small params only; ea handled raw in edge3) ----------------
struct ImpEnt { const void* src; void* dst; int n; };
struct ImpArgs { ImpEnt e[23]; };
__global__ __launch_bounds__(256) void import_k(ImpArgs a, const int* __restrict__ flag){
  ImpEnt en = a.e[blockIdx.y];
  const bool f32 = (*flag != 0);
  for (int i = blockIdx.x*256 + threadIdx.x; i < en.n; i += gridDim.x*256){
    float v = f32 ? ((const float*)en.src)[i] : b2f(((const bf16*)en.src)[i]);
    ((float*)en.dst)[i] = v;
  }
}

// ---------------- weight repack to MFMA-B fragment layout ----------------
__global__ __launch_bounds__(256) void repack5_k(const float* __restrict__ W0,
    const float* __restrict__ W1p, const float* __restrict__ W2p,
    const float* __restrict__ W3p, const float* __restrict__ W4p,
    bf16* __restrict__ dst){
  int idx = blockIdx.x*256 + threadIdx.x;
  const float* Ws[5] = {W0, W1p, W2p, W3p, W4p};
  int o = idx >> 14;
  int rem = idx & 16383;
  int j = rem & 7, l = (rem >> 3) & 63, t = rem >> 9;
  int ks = t >> 3, cb = t & 7;
  int k = ks*32 + (l>>4)*8 + j;
  int c = cb*16 + (l&15);
  dst[idx] = f2b(Ws[o][k*128 + c]);
}

// perm: source column permuted p(c)=(c&15)*8+(c>>4) so MFMA out col c holds
// original channel p(c) (makes per-lane channels contiguous in edge3 epilogue)
struct RepEnt { const float* src; bf16* dst; int total; int ncb_log; int dout; int perm; };
__global__ __launch_bounds__(256) void repack_k(RepEnt e0, RepEnt e1, RepEnt e2, RepEnt e3){
  RepEnt en = (blockIdx.y == 0) ? e0 : (blockIdx.y == 1) ? e1 :
              (blockIdx.y == 2) ? e2 : e3;
  int idx = blockIdx.x*256 + threadIdx.x;
  if (idx >= en.total) return;
  int j = idx & 7, l = (idx >> 3) & 63, t = idx >> 9;
  int ncbm = (1 << en.ncb_log) - 1;
  int ks = t >> en.ncb_log, cb = t & ncbm;
  int k = ks*32 + (l>>4)*8 + j;
  int c = cb*16 + (l&15);
  if (en.perm) c = ((c & 15) << 3) | (c >> 4);
  en.dst[idx] = f2b(en.src[k*en.dout + c]);
}

// ---------------- fused 5-way projection GEMM (reads raw x, dtype-flag branch) -------
__global__ __launch_bounds__(256) void gemm5_k(const void* __restrict__ xraw,
    const int* __restrict__ flag,
    const bf16* __restrict__ Wrep, const float* __restrict__ bias5,
    bf16* __restrict__ proj5){
  const int tid = threadIdx.x;
  const int wid = tid >> 6, l = tid & 63;
  const long r0 = (long)blockIdx.x*64 + wid*16;
  const bool f32 = (*flag != 0);
  short8 af[4];
  if (f32){
    const float* fr = (const float*)xraw + (r0 + (l&15))*128;
    #pragma unroll
    for (int ks=0; ks<4; ks++){
      float4 a = *(const float4*)(fr + ks*32 + (l>>4)*8);
      float4 b = *(const float4*)(fr + ks*32 + (l>>4)*8 + 4);
      union{ unsigned int u[4]; short8 s; } c;
      c.u[0]=cvtpk_bf16(a.x,a.y); c.u[1]=cvtpk_bf16(a.z,a.w);
      c.u[2]=cvtpk_bf16(b.x,b.y); c.u[3]=cvtpk_bf16(b.z,b.w);
      af[ks] = c.s;
    }
  } else {
    const short* Arow = (const short*)xraw + (r0 + (l&15))*128;
    #pragma unroll
    for (int ks=0; ks<4; ks++)
      af[ks] = *(const short8*)(Arow + ks*32 + (l>>4)*8);
  }
  const short8* Wp = (const short8*)Wrep;
  const int cc = l & 15, rr = (l >> 4) * 4;
  #pragma unroll 1
  for (int o=0; o<5; o++){
    f32x4 acc[8];
    #pragma unroll
    for (int cb=0; cb<8; cb++) acc[cb] = (f32x4){0.f,0.f,0.f,0.f};
    #pragma unroll
    for (int ks=0; ks<4; ks++){
      #pragma unroll
      for (int cb=0; cb<8; cb++){
        short8 bf = Wp[(o*32 + ks*8 + cb)*64 + l];
        acc[cb] = __builtin_amdgcn_mfma_f32_16x16x32_bf16(af[ks], bf, acc[cb], 0,0,0);
      }
    }
    bf16* outb = proj5 + (long)o*kN*128;
    #pragma unroll
    for (int cb=0; cb<8; cb++){
      float bb = bias5[o*128 + cb*16 + cc];
      #pragma unroll
      for (int r=0; r<4; r++){
        long row = r0 + rr + r;
        outb[row*128 + cb*16 + cc] = f2b(acc[cb][r] + bb);
      }
    }
  }
}

// ---------------- generic MFMA GEMM ----------------
template<int DIN, int DOUT, int EPI>
__global__ __launch_bounds__(256) void gemm_mfma_k(const bf16* __restrict__ A,
    const bf16* __restrict__ Wrep, const float* __restrict__ bias,
    bf16* __restrict__ C){
  constexpr int KS = DIN/32, NCB = DOUT/16;
  const int tid = threadIdx.x;
  const int wid = tid >> 6, l = tid & 63;
  const long r0 = (long)blockIdx.x*64 + wid*16;
  const short* Arow = (const short*)(A + (r0 + (l&15))*(long)DIN);
  short8 af[KS];
  #pragma unroll
  for (int ks=0; ks<KS; ks++)
    af[ks] = *(const short8*)(Arow + ks*32 + (l>>4)*8);
  f32x4 acc[NCB];
  #pragma unroll
  for (int cb=0; cb<NCB; cb++) acc[cb] = (f32x4){0.f,0.f,0.f,0.f};
  const short8* Wp = (const short8*)Wrep;
  #pragma unroll
  for (int ks=0; ks<KS; ks++){
    #pragma unroll
    for (int cb=0; cb<NCB; cb++){
      short8 bf = Wp[(ks*NCB + cb)*64 + l];
      acc[cb] = __builtin_amdgcn_mfma_f32_16x16x32_bf16(af[ks], bf, acc[cb], 0,0,0);
    }
  }
  const int cc = l & 15, rr = (l >> 4) * 4;
  #pragma unroll
  for (int cb=0; cb<NCB; cb++){
    float bb = bias[cb*16 + cc];
    #pragma unroll
    for (int r=0; r<4; r++){
      long row = r0 + rr + r;
      float v = acc[cb][r] + bb;
      if (EPI == 2) v = 0.5f*v*(1.f + erff(v*0.70710678118654752f));
      C[row*DOUT + cb*16 + cc] = f2b(v);
    }
  }
}

// ---------------- CSR build ----------------
__global__ void hist_k(const int* __restrict__ dstA, int* __restrict__ cnt){
  int e = blockIdx.x*256 + threadIdx.x;
  if (e < kE) atomicAdd(&cnt[dstA[e]], 1);
}

__global__ __launch_bounds__(1024) void scan_k(const int* __restrict__ cnt, int* __restrict__ rowptr){
  __shared__ int part[1024];
  const int t = threadIdx.x;
  const int base = t*32;
  int s = 0;
  #pragma unroll
  for (int i=0;i<32;i++) s += cnt[base+i];
  part[t] = s;
  __syncthreads();
  for (int d=1; d<1024; d<<=1){
    int v = (t>=d) ? part[t-d] : 0;
    __syncthreads();
    part[t] += v;
    __syncthreads();
  }
  int run = (t==0) ? 0 : part[t-1];
  for (int i=0;i<32;i++){ rowptr[base+i] = run; run += cnt[base+i]; }
  if (t == 1023) rowptr[kN] = run;
}

__global__ void scatter_k(const int* __restrict__ dstA, const int* __restrict__ rowptr,
                          int* __restrict__ cursor, int* __restrict__ eidx){
  int e = blockIdx.x*256 + threadIdx.x;
  if (e < kE){
    int d = dstA[e];
    int p = atomicAdd(&cursor[d], 1);
    eidx[rowptr[d]+p] = e;
  }
}

// ---------------- edge3: CSR-ordered, MFMA edge GEMM (perm'd cols) + staged gather ---
// 64 edges/block; reads RAW edge_attr (flag branch); stores EXP(alpha).
__global__ __launch_bounds__(256) void edge3_k(const void* __restrict__ ea_raw,
    const int* __restrict__ flag,
    const int* __restrict__ eidx, const int* __restrict__ srcA,
    const int* __restrict__ dstA,
    const bf16* __restrict__ xs, const bf16* __restrict__ xd,
    const bf16* __restrict__ WeR_edge,     // perm'd: out col c -> orig ch (c&15)*8+(c>>4)
    const float* __restrict__ We_f, const float* __restrict__ att_f,
    const float* __restrict__ be_f,
    float* __restrict__ expal_t, float* __restrict__ ebuf_t,
    unsigned short* __restrict__ epack, int* __restrict__ src_t){
  __shared__ unsigned short sxd[64*136];   // 17.4 KB (stride 136 -> 16B-aligned rows)
  __shared__ float sWe[256];
  __shared__ float sBe[8];
  __shared__ int   sEid[64], sSrc[64], sDst[64];
  __shared__ float sAlphaF[64*4];
  const int tid = threadIdx.x;
  const int w = tid >> 6, l = tid & 63;
  const long t0 = (long)blockIdx.x * 64;
  const bool f32 = (*flag != 0);

  if (tid < 64){
    int e = eidx[t0 + tid];
    int s = srcA[e], d = dstA[e];
    sEid[tid] = e; sSrc[tid] = s; sDst[tid] = d;
    src_t[t0 + tid] = s;
    epack[t0 + tid] = (unsigned short)(((s & 255) << 8) | (d & 255));
  }
  if (tid < 256) sWe[tid] = We_f[tid];
  if (tid >= 128 && tid < 136) sBe[tid-128] = be_f[tid-128];
  __syncthreads();

  // MFMA A-frag: 16 edge rows per wave (via eidx), raw dtype branch
  short8 af;
  {
    long eoff = (long)sEid[w*16 + (l&15)]*32 + (l>>4)*8;
    if (f32){
      const float* er = (const float*)ea_raw + eoff;
      float4 a = *(const float4*)er;
      float4 b = *(const float4*)(er + 4);
      union{ unsigned int u[4]; short8 s; } c;
      c.u[0]=cvtpk_bf16(a.x,a.y); c.u[1]=cvtpk_bf16(a.z,a.w);
      c.u[2]=cvtpk_bf16(b.x,b.y); c.u[3]=cvtpk_bf16(b.z,b.w);
      af = c.s;
    } else {
      af = *(const short8*)((const short*)ea_raw + eoff);
    }
  }
  short8 wb[8];
  #pragma unroll
  for (int cb=0; cb<8; cb++)
    wb[cb] = *(const short8*)((const short*)WeR_edge + (cb*64 + l)*8);

  // stage xs[src]+xd[dst] -> sxd (original channel order)
  {
    const int c0 = (tid & 31) * 4;
    const int rb = tid >> 5;
    const unsigned short* xsu = (const unsigned short*)xs;
    const unsigned short* xdu = (const unsigned short*)xd;
    #pragma unroll 4
    for (int p = 0; p < 8; p++){
      int row = p*8 + rb;
      long s = sSrc[row], dd = sDst[row];
      ushort4 a = *(const ushort4*)(xsu + s*128 + c0);
      ushort4 b = *(const ushort4*)(xdu + dd*128 + c0);
      unsigned int lo = cvtpk_bf16(b2f_raw(a.x)+b2f_raw(b.x), b2f_raw(a.y)+b2f_raw(b.y));
      unsigned int hi = cvtpk_bf16(b2f_raw(a.z)+b2f_raw(b.z), b2f_raw(a.w)+b2f_raw(b.w));
      *(uint2*)&sxd[row*136 + c0] = (uint2){lo, hi};
    }
  }

  // ef = ea @ W_edge via MFMA (acc[cb][r] = orig channel (l&15)*8+cb of edge row)
  f32x4 acc[8];
  #pragma unroll
  for (int cb=0; cb<8; cb++)
    acc[cb] = __builtin_amdgcn_mfma_f32_16x16x32_bf16(af, wb[cb],
                (f32x4){0.f,0.f,0.f,0.f}, 0,0,0);

  // eb = ea @ We + be (raw dtype branch; rows L2-hot)
  {
    int e_eb = tid >> 2, h0 = (tid & 3) * 2;
    long ebase = (long)sEid[e_eb]*32;
    float a0 = sBe[h0], a1 = sBe[h0+1];
    #pragma unroll
    for (int dq=0; dq<8; dq++){
      float f0,f1,f2,f3;
      if (f32){
        float4 u = *(const float4*)((const float*)ea_raw + ebase + dq*4);
        f0=u.x; f1=u.y; f2=u.z; f3=u.w;
      } else {
        ushort4 u = *(const ushort4*)((const unsigned short*)ea_raw + ebase + dq*4);
        f0=b2f_raw(u.x); f1=b2f_raw(u.y); f2=b2f_raw(u.z); f3=b2f_raw(u.w);
      }
      a0 += f0*sWe[(dq*4+0)*8 + h0]   + f1*sWe[(dq*4+1)*8 + h0]
          + f2*sWe[(dq*4+2)*8 + h0]   + f3*sWe[(dq*4+3)*8 + h0];
      a1 += f0*sWe[(dq*4+0)*8 + h0+1] + f1*sWe[(dq*4+1)*8 + h0+1]
          + f2*sWe[(dq*4+2)*8 + h0+1] + f3*sWe[(dq*4+3)*8 + h0+1];
    }
    ebuf_t[(long)h0*kE     + t0 + e_eb] = a0;
    ebuf_t[(long)(h0+1)*kE + t0 + e_eb] = a1;
  }
  __syncthreads();   // sxd ready

  // epilogue: lane's 8 channels are contiguous orig [c15*8, c15*8+8) -> 1 b128/row;
  // all 8 belong to head c15>>2; reduce over 4 lanes (c15 low 2 bits)
  const int c15 = l & 15;
  float4 at0 = *(const float4*)(att_f + c15*8);
  float4 at1 = *(const float4*)(att_f + c15*8 + 4);
  const float attv[8] = {at0.x,at0.y,at0.z,at0.w, at1.x,at1.y,at1.z,at1.w};
  #pragma unroll
  for (int r=0; r<4; r++){
    int e_l = w*16 + (l>>4)*4 + r;
    union{ short8 s8; unsigned short u[8]; } sx;
    sx.s8 = *(short8*)&sxd[e_l*136 + c15*8];
    float hsum = 0.f;
    #pragma unroll
    for (int cb=0; cb<8; cb++){
      float v = acc[cb][r] + b2f_raw(sx.u[cb]);
      hsum += tanh_fast(v) * attv[cb];
    }
    hsum += __shfl_xor(hsum,1);
    hsum += __shfl_xor(hsum,2);
    if ((c15 & 3) == 0) sAlphaF[e_l*4 + (c15>>2)] = __expf(hsum);
  }
  __syncthreads();
  if (tid < 64)
    *(float4*)&expal_t[(t0 + tid)*4] = *(float4*)&sAlphaF[tid*4];
}

// ---------------- GAT aggregate: 32 lanes/node, 4 ch/lane, single pass (no max) -----
__global__ __launch_bounds__(256) void gat_agg_k(const float* __restrict__ expal,
    const int* __restrict__ rowptr, const int* __restrict__ src_t,
    const bf16* __restrict__ xs, const float* __restrict__ gatb_f,
    bf16* __restrict__ h_local){
  const int tid = threadIdx.x;
  const int grp = tid >> 5;
  const int l   = tid & 31;
  const int v   = blockIdx.x*8 + grp;
  const int c0  = l*4;
  const int head = l >> 3;
  const int beg = rowptr[v], end = rowptr[v+1];
  float den = 0.f, o0 = 0.f, o1 = 0.f, o2 = 0.f, o3 = 0.f;
  const unsigned short* xsu = (const unsigned short*)xs;
  for (int t = beg; t < end; t++){
    float w = expal[(long)t*4 + head];
    long s = src_t[t];
    ushort4 a = *(const ushort4*)(xsu + s*128 + c0);
    den += w;
    o0 += w*b2f_raw(a.x); o1 += w*b2f_raw(a.y);
    o2 += w*b2f_raw(a.z); o3 += w*b2f_raw(a.w);
  }
  float inv = 1.f/(den + 1e-16f);
  float4 gb = *(const float4*)(gatb_f + c0);
  unsigned int lo = cvtpk_bf16(o0*inv + gb.x, o1*inv + gb.y);
  unsigned int hi = cvtpk_bf16(o2*inv + gb.z, o3*inv + gb.w);
  *(uint2*)&((unsigned short*)h_local)[(long)v*128 + c0] = (uint2){lo, hi};
}

// ---------------- MFMA flash attention: block=(g,h), 8 waves, wave = 32-query tile --
__global__ __launch_bounds__(512, 6) void attn2_k(const bf16* __restrict__ qb,
    const bf16* __restrict__ kb, const bf16* __restrict__ vb,
    const float* __restrict__ ebuf_t, const unsigned short* __restrict__ epack,
    const int* __restrict__ rowptr, bf16* __restrict__ hattn){
  __shared__ short Vf[16*64*8];     // 16 KB
  __shared__ float sb[256*33];      // 33.8 KB
  const int bid = blockIdx.x;
  const int h = (bid >> 3) >> 4;
  const int g = (((bid >> 3) & 15) << 3) | (bid & 7);
  const int tid = threadIdx.x;
  const int w = tid >> 6, l = tid & 63;
  const int q31 = l & 31, hi = l >> 5;
  const int nbase = g << 8;

  for (int s2 = tid; s2 < 1024; s2 += 512){
    int f = s2 >> 6, ll = s2 & 63;
    int keyb = (f>>1)*32 + (f&1)*16 + ((ll>>5)*8);
    int d = ll & 15;
    short tmp[8];
    #pragma unroll
    for (int j=0;j<8;j++)
      tmp[j] = ((const short*)vb)[((long)(nbase + keyb + j))*128 + h*16 + d];
    *(short8*)&Vf[s2*8] = *(short8*)tmp;
  }
  for (int i = tid; i < 256*33; i += 512) sb[i] = 0.f;
  short8 qf = *(const short8*)((const short*)qb + ((long)(nbase + w*32 + q31))*128 + h*16 + hi*8);
  __syncthreads();

  float m = -1e30f, lsum = 0.f;
  f32x16 oacc = {0.f,0.f,0.f,0.f,0.f,0.f,0.f,0.f,0.f,0.f,0.f,0.f,0.f,0.f,0.f,0.f};
  #pragma unroll 1
  for (int kt = 0; kt < 8; kt++){
    int rb = rowptr[nbase + kt*32];
    int re = rowptr[nbase + kt*32 + 32];
    for (int t = rb + tid; t < re; t += 512){
      unsigned int p = epack[t];
      atomicAdd(&sb[(p>>8)*33 + (p&31)], ebuf_t[(long)h*kE + t]);
    }
    __syncthreads();
    short8 af = *(const short8*)((const short*)kb +
                 ((long)(nbase + kt*32 + q31))*128 + h*16 + hi*8);
    f32x16 acc = {0.f,0.f,0.f,0.f,0.f,0.f,0.f,0.f,0.f,0.f,0.f,0.f,0.f,0.f,0.f,0.f};
    acc = __builtin_amdgcn_mfma_f32_32x32x16_bf16(af, qf, acc, 0, 0, 0);
    float s[16];
    float* brow = &sb[(w*32 + q31)*33];
    #pragma unroll
    for (int r=0;r<16;r++){
      int krow = (r&3) + 8*(r>>2) + 4*hi;
      s[r] = acc[r]*0.25f + brow[krow];
      brow[krow] = 0.f;
    }
    __syncthreads();
    float tmax = s[0];
    #pragma unroll
    for (int r=1;r<16;r++) tmax = fmaxf(tmax, s[r]);
    tmax = fmaxf(tmax, __shfl_xor(tmax, 32));
    float mn = fmaxf(m, tmax);
    float corrq = __expf(m - mn);
    m = mn;
    float psum = 0.f;
    #pragma unroll
    for (int r=0;r<16;r++){ s[r] = __expf(s[r] - m); psum += s[r]; }
    lsum = lsum*corrq + psum;
    #pragma unroll
    for (int r=0;r<16;r++){
      int qrow = (r&3) + 8*(r>>2) + 4*hi;
      oacc[r] *= __shfl(corrq, qrow);
    }
    unsigned int a  = cvtpk_bf16(s[0],  s[1]);
    unsigned int b  = cvtpk_bf16(s[2],  s[3]);
    unsigned int c  = cvtpk_bf16(s[4],  s[5]);
    unsigned int d  = cvtpk_bf16(s[6],  s[7]);
    unsigned int e  = cvtpk_bf16(s[8],  s[9]);
    unsigned int f  = cvtpk_bf16(s[10], s[11]);
    unsigned int g2 = cvtpk_bf16(s[12], s[13]);
    unsigned int h2 = cvtpk_bf16(s[14], s[15]);
    plane_swap(a, c); plane_swap(b, d); plane_swap(e, g2); plane_swap(f, h2);
    union { unsigned int u[4]; short8 s8; } A1, A2;
    A1.u[0]=a; A1.u[1]=b; A1.u[2]=c; A1.u[3]=d;
    A2.u[0]=e; A2.u[1]=f; A2.u[2]=g2; A2.u[3]=h2;
    short8 v1 = *(short8*)&Vf[((kt*2+0)*64 + l)*8];
    short8 v2 = *(short8*)&Vf[((kt*2+1)*64 + l)*8];
    oacc = __builtin_amdgcn_mfma_f32_32x32x16_bf16(A1.s8, v1, oacc, 0,0,0);
    oacc = __builtin_amdgcn_mfma_f32_32x32x16_bf16(A2.s8, v2, oacc, 0,0,0);
  }
  lsum += __shfl_xor(lsum, 32);
  float linv = 1.f / lsum;
  #pragma unroll
  for (int r=0;r<16;r++){
    int qrow = (r&3) + 8*(r>>2) + 4*hi;
    float li = __shfl(linv, qrow);
    float ov = oacc[r]*li;
    if (q31 < 16)
      hattn[((long)(nbase + w*32 + qrow))*128 + h*16 + q31] = f2b(ov);
  }
}

// ---------------- residual add + LayerNorm ----------------
__global__ __launch_bounds__(256) void combine_ln_k(const void* __restrict__ a,
    const bf16* __restrict__ b, const bf16* __restrict__ c3,
    const float* __restrict__ g, const float* __restrict__ bb,
    void* __restrict__ outp, const int* __restrict__ flag,
    int a_raw, int is_final){
  const int tid = threadIdx.x;
  const int lane = tid & 63;
  const long row = (long)blockIdx.x*4 + (tid>>6);
  const long base = row*128;
  float a0, a1;
  if (a_raw && (*flag)){
    const float* ap = (const float*)a;
    a0 = ap[base+lane]; a1 = ap[base+lane+64];
  } else {
    const bf16* ap = (const bf16*)a;
    a0 = b2f(ap[base+lane]); a1 = b2f(ap[base+lane+64]);
  }
  float v0 = a0 + b2f(b[base+lane]);
  float v1 = a1 + b2f(b[base+lane+64]);
  if (c3){ v0 += b2f(c3[base+lane]); v1 += b2f(c3[base+lane+64]); }
  float s = v0 + v1;
  #pragma unroll
  for (int o=1; o<64; o<<=1) s += __shfl_xor(s, o);
  float mean = s * (1.f/128.f);
  float d0 = v0 - mean, d1 = v1 - mean;
  float q = d0*d0 + d1*d1;
  #pragma unroll
  for (int o=1; o<64; o<<=1) q += __shfl_xor(q, o);
  float r = rsqrtf(q*(1.f/128.f) + 1e-5f);
  float r0v = d0*r*g[lane]    + bb[lane];
  float r1v = d1*r*g[lane+64] + bb[lane+64];
  if (is_final && (*flag)){
    float* o = (float*)outp;
    o[base+lane]    = r0v;
    o[base+lane+64] = r1v;
  } else {
    bf16* o = (bf16*)outp;
    o[base+lane]    = f2b(r0v);
    o[base+lane+64] = f2b(r1v);
  }
}

// =====================================================================================
extern "C" void kernel_launch(void* const* d_in, const int* in_sizes, int n_in,
                              void* d_out, int out_size, void* d_ws, size_t ws_size,
                              hipStream_t stream){
  const void* x_raw   = d_in[0];
  const void* ea_raw  = d_in[1];
  const int*  ei      = (const int*)d_in[25];
  const int* srcA = ei;
  const int* dstA = ei + kE;

  char* ws = (char*)d_ws;
  size_t off = 0;
  auto alloc = [&](size_t bytes)->void*{
    void* p = ws + off;
    off = (off + bytes + 255) & ~(size_t)255;
    return p;
  };
  int*   flag    = (int*)alloc(4);
  float* Wsrc_f  = (float*)alloc(16384*4);
  float* Wdst_f  = (float*)alloc(16384*4);
  float* Wedge_f = (float*)alloc(4096*4);
  float* att_f   = (float*)alloc(128*4);
  float* gatb_f  = (float*)alloc(128*4);
  float* Wq_f    = (float*)alloc(16384*4);
  float* Wk_f    = (float*)alloc(16384*4);
  float* Wv_f    = (float*)alloc(16384*4);
  float* Wo_f    = (float*)alloc(16384*4);
  float* bo_f    = (float*)alloc(128*4);
  float* We_f    = (float*)alloc(256*4);
  float* be_f    = (float*)alloc(8*4);
  float* ln1g_f  = (float*)alloc(128*4);
  float* ln1b_f  = (float*)alloc(128*4);
  float* W1_f    = (float*)alloc(32768*4);
  float* b1_f    = (float*)alloc(256*4);
  float* W2_f    = (float*)alloc(32768*4);
  float* b2_f    = (float*)alloc(128*4);
  float* ln2g_f  = (float*)alloc(128*4);
  float* ln2b_f  = (float*)alloc(128*4);
  float* bias5   = (float*)alloc(640*4);
  bf16*  Wrep5   = (bf16*)alloc((size_t)5*16384*2);
  bf16*  WoR     = (bf16*)alloc((size_t)16384*2);
  bf16*  W1R     = (bf16*)alloc((size_t)32768*2);
  bf16*  W2R     = (bf16*)alloc((size_t)32768*2);
  bf16*  WeR     = (bf16*)alloc((size_t)4096*2);
  bf16*  proj5   = (bf16*)alloc((size_t)5*kN*128*2);
  bf16* xs   = proj5;
  bf16* xd   = proj5 + (size_t)kN*128;
  bf16* qb   = proj5 + (size_t)2*kN*128;
  bf16* kbuf = proj5 + (size_t)3*kN*128;
  bf16* vbuf = proj5 + (size_t)4*kN*128;
  int* cnt        = (int*)alloc((size_t)2*kN*4);
  int* cursor     = cnt + kN;
  int* rowptr     = (int*)alloc((size_t)(kN+1)*4);
  int* eidx       = (int*)alloc((size_t)kE*4);
  unsigned short* epack = (unsigned short*)alloc((size_t)kE*2);
  float* ebuf_t   = (float*)alloc((size_t)8*kE*4);
  float* expal_t  = (float*)alloc((size_t)kE*4*4);
  int*   src_t    = (int*)alloc((size_t)kE*4);
  bf16* h_local   = (bf16*)alloc((size_t)kN*128*2);
  bf16* hattn_pre = (bf16*)alloc((size_t)kN*128*2);
  bf16* h_attn    = (bf16*)alloc((size_t)kN*128*2);
  bf16* hbuf      = (bf16*)alloc((size_t)kN*128*2);
  bf16* tbuf      = (bf16*)alloc((size_t)kN*256*2);
  bf16* f2buf     = (bf16*)alloc((size_t)kN*128*2);
  (void)ws_size; (void)in_sizes; (void)n_in; (void)out_size;

  dim3 b256(256);

  detect_k<<<1, b256, 0, stream>>>(x_raw, flag);
  hipMemsetAsync(bias5, 0, 256*4, stream);
  hipMemsetAsync(cnt, 0, (size_t)2*kN*4, stream);

  // CSR build first (only needs dstA) so edge3 can run in CSR order
  hist_k<<<kE/256, b256, 0, stream>>>(dstA, cnt);
  scan_k<<<1, 1024, 0, stream>>>(cnt, rowptr);
  scatter_k<<<kE/256, b256, 0, stream>>>(dstA, rowptr, cursor, eidx);

  ImpArgs ia;
  const void* srcs[23] = {d_in[2], d_in[3], d_in[4], d_in[5], d_in[6],
                          d_in[7], d_in[8], d_in[9], d_in[10], d_in[11], d_in[12],
                          d_in[13], d_in[14], d_in[15], d_in[16], d_in[17], d_in[18],
                          d_in[19], d_in[20], d_in[21], d_in[22], d_in[23], d_in[24]};
  void* dsts[23] = {Wsrc_f, Wdst_f, Wedge_f, att_f, gatb_f,
                    Wq_f, bias5+256, Wk_f, bias5+384, Wv_f, bias5+512,
                    Wo_f, bo_f, We_f, be_f, ln1g_f, ln1b_f,
                    W1_f, b1_f, W2_f, b2_f, ln2g_f, ln2b_f};
  int ns[23] = {16384, 16384, 4096, 128, 128,
                16384, 128, 16384, 128, 16384, 128,
                16384, 128, 256, 8, 128, 128,
                32768, 256, 32768, 128, 128, 128};
  for (int i=0;i<23;i++){ ia.e[i].src=srcs[i]; ia.e[i].dst=dsts[i]; ia.e[i].n=ns[i]; }
  import_k<<<dim3(64,23), b256, 0, stream>>>(ia, flag);

  repack5_k<<<(5*16384)/256, b256, 0, stream>>>(Wsrc_f, Wdst_f, Wq_f, Wk_f, Wv_f, Wrep5);
  RepEnt ro{Wo_f, WoR, 16384, 3, 128, 0};
  RepEnt r1{W1_f, W1R, 32768, 4, 256, 0};
  RepEnt r2{W2_f, W2R, 32768, 3, 128, 0};
  RepEnt re{Wedge_f, WeR, 4096, 3, 128, 1};   // perm'd for edge3 epilogue
  repack_k<<<dim3(128,4), b256, 0, stream>>>(ro, r1, r2, re);

  gemm5_k<<<kN/64, b256, 0, stream>>>(x_raw, flag, Wrep5, bias5, proj5);

  edge3_k<<<kE/64, b256, 0, stream>>>(ea_raw, flag, eidx, srcA, dstA, xs, xd,
                                      WeR, We_f, att_f, be_f,
                                      expal_t, ebuf_t, epack, src_t);

  gat_agg_k<<<kN/8, b256, 0, stream>>>(expal_t, rowptr, src_t, xs, gatb_f, h_local);

  attn2_k<<<kG*kHA, dim3(512), 0, stream>>>(qb, kbuf, vbuf, ebuf_t, epack, rowptr, hattn_pre);
  gemm_mfma_k<128,128,1><<<kN/64, b256, 0, stream>>>(hattn_pre, WoR, bo_f, h_attn);

  combine_ln_k<<<kN/4, b256, 0, stream>>>(x_raw, h_local, h_attn, ln1g_f, ln1b_f,
                                          hbuf, flag, 1, 0);

  gemm_mfma_k<128,256,2><<<kN/64, b256, 0, stream>>>(hbuf, W1R, b1_f, tbuf);
  gemm_mfma_k<256,128,1><<<kN/64, b256, 0, stream>>>(tbuf, W2R, b2_f, f2buf);

  combine_ln_k<<<kN/4, b256, 0, stream>>>(hbuf, f2buf, nullptr, ln2g_f, ln2b_f,
                                          d_out, flag, 0, 1);
}

// Round 10
// 234.925 us; speedup vs baseline: 3.2518x; 1.1110x over previous
//
#include <hip/hip_runtime.h>
#include <hip/hip_bf16.h>

typedef __hip_bfloat16 bf16;
typedef __hip_bfloat162 bf162;
typedef __attribute__((ext_vector_type(8))) short short8;
typedef __attribute__((ext_vector_type(4))) float f32x4;
typedef __attribute__((ext_vector_type(16))) float f32x16;

constexpr int kN   = 32768;   // nodes
constexpr int kG   = 128;     // graphs
constexpr int kE   = 262144;  // edges
constexpr int kHA  = 8;       // global attn heads

__device__ __forceinline__ float b2f(bf16 v){ return __bfloat162float(v); }
__device__ __forceinline__ bf16  f2b(float v){ return __float2bfloat16(v); }
__device__ __forceinline__ float b2f_raw(unsigned short u){
  return __uint_as_float((unsigned)u << 16);
}
__device__ __forceinline__ float tanh_fast(float x){
  float e = __expf(2.f*x);
  return 1.f - 2.f/(e+1.f);
}
__device__ __forceinline__ unsigned int cvtpk_bf16(float lo, float hi){
  unsigned int r;
  asm volatile("v_cvt_pk_bf16_f32 %0, %1, %2" : "=v"(r) : "v"(lo), "v"(hi));
  return r;
}
__device__ __forceinline__ void plane_swap(unsigned int &a, unsigned int &b){
  asm volatile("v_permlane32_swap_b32 %0, %1" : "+v"(a), "+v"(b));
}

// ---------------- input dtype detection (bf16 vs fp32 device buffers) ----------------
__global__ void detect_k(const void* xraw, int* flag){
  const bf16* p = (const bf16*)xraw;
  int good = 0;
  for (int i = threadIdx.x; i < 4096; i += 256){
    float v = fabsf(b2f(p[i]));
    if (v > 0.0009765625f && v < 16.f) good++;
  }
  __shared__ int s[256];
  s[threadIdx.x] = good;
  __syncthreads();
  for (int d = 128; d; d >>= 1){
    if (threadIdx.x < d) s[threadIdx.x] += s[threadIdx.x + d];
    __syncthreads();
  }
  if (threadIdx.x == 0) *flag = (s[0] < 3500) ? 1 : 0;
}

// ---------------- import (params to fp32 ws) ----------------
struct ImpEnt { const void* src; void* dst; int n; };
struct ImpArgs { ImpEnt e[23]; };
__global__ __launch_bounds__(256) void import_k(ImpArgs a, const int* __restrict__ flag){
  ImpEnt en = a.e[blockIdx.y];
  const bool f32 = (*flag != 0);
  for (int i = blockIdx.x*256 + threadIdx.x; i < en.n; i += gridDim.x*256){
    float v = f32 ? ((const float*)en.src)[i] : b2f(((const bf16*)en.src)[i]);
    ((float*)en.dst)[i] = v;
  }
}

// ---------------- weight repack to MFMA-B fragment layout ----------------
__global__ __launch_bounds__(256) void repack5_k(const float* __restrict__ W0,
    const float* __restrict__ W1p, const float* __restrict__ W2p,
    const float* __restrict__ W3p, const float* __restrict__ W4p,
    bf16* __restrict__ dst){
  int idx = blockIdx.x*256 + threadIdx.x;
  const float* Ws[5] = {W0, W1p, W2p, W3p, W4p};
  int o = idx >> 14;
  int rem = idx & 16383;
  int j = rem & 7, l = (rem >> 3) & 63, t = rem >> 9;
  int ks = t >> 3, cb = t & 7;
  int k = ks*32 + (l>>4)*8 + j;
  int c = cb*16 + (l&15);
  dst[idx] = f2b(Ws[o][k*128 + c]);
}

// mode 0: plain; mode 1: perm'd cols p(c)=(c&15)*8+(c>>4); mode 2: We 32x8 padded to 16 cols
struct RepEnt { const float* src; bf16* dst; int total; int ncb_log; int dout; int mode; };
__global__ __launch_bounds__(256) void repack_k(RepEnt e0, RepEnt e1, RepEnt e2,
                                                RepEnt e3, RepEnt e4){
  RepEnt en = (blockIdx.y == 0) ? e0 : (blockIdx.y == 1) ? e1 :
              (blockIdx.y == 2) ? e2 : (blockIdx.y == 3) ? e3 : e4;
  int idx = blockIdx.x*256 + threadIdx.x;
  if (idx >= en.total) return;
  int j = idx & 7, l = (idx >> 3) & 63, t = idx >> 9;
  if (en.mode == 2){
    int k = (l>>4)*8 + j;
    int c = l & 15;
    en.dst[idx] = (c < 8) ? f2b(en.src[k*8 + c]) : f2b(0.f);
    return;
  }
  int ncbm = (1 << en.ncb_log) - 1;
  int ks = t >> en.ncb_log, cb = t & ncbm;
  int k = ks*32 + (l>>4)*8 + j;
  int c = cb*16 + (l&15);
  if (en.mode == 1) c = ((c & 15) << 3) | (c >> 4);
  en.dst[idx] = f2b(en.src[k*en.dout + c]);
}

// ---------------- fused 5-way projection GEMM (reads raw x, dtype-flag branch) -------
__global__ __launch_bounds__(256) void gemm5_k(const void* __restrict__ xraw,
    const int* __restrict__ flag,
    const bf16* __restrict__ Wrep, const float* __restrict__ bias5,
    bf16* __restrict__ proj5){
  const int tid = threadIdx.x;
  const int wid = tid >> 6, l = tid & 63;
  const long r0 = (long)blockIdx.x*64 + wid*16;
  const bool f32 = (*flag != 0);
  short8 af[4];
  if (f32){
    const float* fr = (const float*)xraw + (r0 + (l&15))*128;
    #pragma unroll
    for (int ks=0; ks<4; ks++){
      float4 a = *(const float4*)(fr + ks*32 + (l>>4)*8);
      float4 b = *(const float4*)(fr + ks*32 + (l>>4)*8 + 4);
      union{ unsigned int u[4]; short8 s; } c;
      c.u[0]=cvtpk_bf16(a.x,a.y); c.u[1]=cvtpk_bf16(a.z,a.w);
      c.u[2]=cvtpk_bf16(b.x,b.y); c.u[3]=cvtpk_bf16(b.z,b.w);
      af[ks] = c.s;
    }
  } else {
    const short* Arow = (const short*)xraw + (r0 + (l&15))*128;
    #pragma unroll
    for (int ks=0; ks<4; ks++)
      af[ks] = *(const short8*)(Arow + ks*32 + (l>>4)*8);
  }
  const short8* Wp = (const short8*)Wrep;
  const int cc = l & 15, rr = (l >> 4) * 4;
  #pragma unroll 1
  for (int o=0; o<5; o++){
    f32x4 acc[8];
    #pragma unroll
    for (int cb=0; cb<8; cb++) acc[cb] = (f32x4){0.f,0.f,0.f,0.f};
    #pragma unroll
    for (int ks=0; ks<4; ks++){
      #pragma unroll
      for (int cb=0; cb<8; cb++){
        short8 bf = Wp[(o*32 + ks*8 + cb)*64 + l];
        acc[cb] = __builtin_amdgcn_mfma_f32_16x16x32_bf16(af[ks], bf, acc[cb], 0,0,0);
      }
    }
    bf16* outb = proj5 + (long)o*kN*128;
    #pragma unroll
    for (int cb=0; cb<8; cb++){
      float bb = bias5[o*128 + cb*16 + cc];
      #pragma unroll
      for (int r=0; r<4; r++){
        long row = r0 + rr + r;
        outb[row*128 + cb*16 + cc] = f2b(acc[cb][r] + bb);
      }
    }
  }
}

// ---------------- generic MFMA GEMM ----------------
template<int DIN, int DOUT, int EPI>
__global__ __launch_bounds__(256) void gemm_mfma_k(const bf16* __restrict__ A,
    const bf16* __restrict__ Wrep, const float* __restrict__ bias,
    bf16* __restrict__ C){
  constexpr int KS = DIN/32, NCB = DOUT/16;
  const int tid = threadIdx.x;
  const int wid = tid >> 6, l = tid & 63;
  const long r0 = (long)blockIdx.x*64 + wid*16;
  const short* Arow = (const short*)(A + (r0 + (l&15))*(long)DIN);
  short8 af[KS];
  #pragma unroll
  for (int ks=0; ks<KS; ks++)
    af[ks] = *(const short8*)(Arow + ks*32 + (l>>4)*8);
  f32x4 acc[NCB];
  #pragma unroll
  for (int cb=0; cb<NCB; cb++) acc[cb] = (f32x4){0.f,0.f,0.f,0.f};
  const short8* Wp = (const short8*)Wrep;
  #pragma unroll
  for (int ks=0; ks<KS; ks++){
    #pragma unroll
    for (int cb=0; cb<NCB; cb++){
      short8 bf = Wp[(ks*NCB + cb)*64 + l];
      acc[cb] = __builtin_amdgcn_mfma_f32_16x16x32_bf16(af[ks], bf, acc[cb], 0,0,0);
    }
  }
  const int cc = l & 15, rr = (l >> 4) * 4;
  #pragma unroll
  for (int cb=0; cb<NCB; cb++){
    float bb = bias[cb*16 + cc];
    #pragma unroll
    for (int r=0; r<4; r++){
      long row = r0 + rr + r;
      float v = acc[cb][r] + bb;
      if (EPI == 2) v = 0.5f*v*(1.f + erff(v*0.70710678118654752f));
      C[row*DOUT + cb*16 + cc] = f2b(v);
    }
  }
}

// ---------------- CSR build ----------------
__global__ void hist_k(const int* __restrict__ dstA, int* __restrict__ cnt){
  int e = blockIdx.x*256 + threadIdx.x;
  if (e < kE) atomicAdd(&cnt[dstA[e]], 1);
}

__global__ __launch_bounds__(1024) void scan_k(const int* __restrict__ cnt, int* __restrict__ rowptr){
  __shared__ int part[1024];
  const int t = threadIdx.x;
  const int base = t*32;
  int s = 0;
  #pragma unroll
  for (int i=0;i<32;i++) s += cnt[base+i];
  part[t] = s;
  __syncthreads();
  for (int d=1; d<1024; d<<=1){
    int v = (t>=d) ? part[t-d] : 0;
    __syncthreads();
    part[t] += v;
    __syncthreads();
  }
  int run = (t==0) ? 0 : part[t-1];
  for (int i=0;i<32;i++){ rowptr[base+i] = run; run += cnt[base+i]; }
  if (t == 1023) rowptr[kN] = run;
}

__global__ void scatter_k(const int* __restrict__ dstA, const int* __restrict__ rowptr,
                          int* __restrict__ cursor, int* __restrict__ eidx){
  int e = blockIdx.x*256 + threadIdx.x;
  if (e < kE){
    int d = dstA[e];
    int p = atomicAdd(&cursor[d], 1);
    eidx[rowptr[d]+p] = e;
  }
}

// ---------------- edge3 v4: CSR-ordered, MFMA edge GEMM (perm'd cols) + MFMA eb,
// direct coalesced epilogue gather (no LDS stage), graph-locality XCD swizzle.
__global__ __launch_bounds__(256) void edge3_k(const void* __restrict__ ea_raw,
    const int* __restrict__ flag,
    const int* __restrict__ eidx, const int* __restrict__ srcA,
    const int* __restrict__ dstA,
    const bf16* __restrict__ xs, const bf16* __restrict__ xd,
    const bf16* __restrict__ WeR_edge,     // perm'd: out col c -> orig ch (c&15)*8+(c>>4)
    const bf16* __restrict__ WeR_eb,       // We 32x8 padded to 16 cols, frag layout
    const float* __restrict__ att_f, const float* __restrict__ be_f,
    float* __restrict__ expal_t, float* __restrict__ ebuf_t,
    unsigned short* __restrict__ epack, int* __restrict__ src_t){
  __shared__ int sEid[64], sSrc[64], sDst[64];
  __shared__ float sAlphaF[64*4];
  const int tid = threadIdx.x;
  const int w = tid >> 6, l = tid & 63;
  // graph-locality swizzle: XCD x runs 512 consecutive CSR blocks (16 graphs)
  const int p = blockIdx.x;
  const int bid = (p & 7) * (gridDim.x >> 3) + (p >> 3);
  const long t0 = (long)bid * 64;
  const bool f32 = (*flag != 0);

  if (tid < 64){
    int e = eidx[t0 + tid];
    int s = srcA[e], d = dstA[e];
    sEid[tid] = e; sSrc[tid] = s; sDst[tid] = d;
    src_t[t0 + tid] = s;
    epack[t0 + tid] = (unsigned short)(((s & 255) << 8) | (d & 255));
  }
  __syncthreads();

  // A-frag: 16 edge rows per wave (via eidx), raw dtype branch
  short8 af;
  {
    long eoff = (long)sEid[w*16 + (l&15)]*32 + (l>>4)*8;
    if (f32){
      const float* er = (const float*)ea_raw + eoff;
      float4 a = *(const float4*)er;
      float4 b = *(const float4*)(er + 4);
      union{ unsigned int u[4]; short8 s; } c;
      c.u[0]=cvtpk_bf16(a.x,a.y); c.u[1]=cvtpk_bf16(a.z,a.w);
      c.u[2]=cvtpk_bf16(b.x,b.y); c.u[3]=cvtpk_bf16(b.z,b.w);
      af = c.s;
    } else {
      af = *(const short8*)((const short*)ea_raw + eoff);
    }
  }

  // ef = ea @ W_edge (8 MFMA) + eb = ea @ We (1 MFMA, padded cols)
  f32x4 acc[8], acc_eb;
  #pragma unroll
  for (int cb=0; cb<8; cb++){
    short8 wb = *(const short8*)((const short*)WeR_edge + (cb*64 + l)*8);
    acc[cb] = __builtin_amdgcn_mfma_f32_16x16x32_bf16(af, wb,
                (f32x4){0.f,0.f,0.f,0.f}, 0,0,0);
  }
  {
    short8 wbe = *(const short8*)((const short*)WeR_eb + l*8);
    acc_eb = __builtin_amdgcn_mfma_f32_16x16x32_bf16(af, wbe,
                (f32x4){0.f,0.f,0.f,0.f}, 0,0,0);
  }

  // epilogue: lane (e_l, c15) owns orig channels [c15*8, c15*8+8)
  const int c15 = l & 15;
  const float be_v = be_f[c15 & 7];
  float4 at0 = *(const float4*)(att_f + c15*8);
  float4 at1 = *(const float4*)(att_f + c15*8 + 4);
  const float attv[8] = {at0.x,at0.y,at0.z,at0.w, at1.x,at1.y,at1.z,at1.w};
  // direct coalesced gathers: 16 lanes x 16B = 256B per row
  union U8 { short8 s8; unsigned short u[8]; };
  U8 gx[4], gd[4];
  #pragma unroll
  for (int r=0; r<4; r++){
    int e_l = w*16 + (l>>4)*4 + r;
    gx[r].s8 = *(const short8*)((const short*)xs + (long)sSrc[e_l]*128 + c15*8);
    gd[r].s8 = *(const short8*)((const short*)xd + (long)sDst[e_l]*128 + c15*8);
  }
  #pragma unroll
  for (int r=0; r<4; r++){
    int e_l = w*16 + (l>>4)*4 + r;
    float hsum = 0.f;
    #pragma unroll
    for (int cb=0; cb<8; cb++){
      float v = acc[cb][r] + b2f_raw(gx[r].u[cb]) + b2f_raw(gd[r].u[cb]);
      hsum += tanh_fast(v) * attv[cb];
    }
    hsum += __shfl_xor(hsum,1);
    hsum += __shfl_xor(hsum,2);
    if ((c15 & 3) == 0) sAlphaF[e_l*4 + (c15>>2)] = __expf(hsum);
    if (c15 < 8) ebuf_t[(long)c15*kE + t0 + e_l] = acc_eb[r] + be_v;
  }
  __syncthreads();
  if (tid < 64)
    *(float4*)&expal_t[(t0 + tid)*4] = *(float4*)&sAlphaF[tid*4];
}

// ---------------- GAT aggregate: 32 lanes/node, single pass, graph-locality swizzle --
__global__ __launch_bounds__(256) void gat_agg_k(const float* __restrict__ expal,
    const int* __restrict__ rowptr, const int* __restrict__ src_t,
    const bf16* __restrict__ xs, const float* __restrict__ gatb_f,
    bf16* __restrict__ h_local){
  const int tid = threadIdx.x;
  const int grp = tid >> 5;
  const int l   = tid & 31;
  const int p   = blockIdx.x;
  const int bid = (p & 7) * (gridDim.x >> 3) + (p >> 3);
  const int v   = bid*8 + grp;
  const int c0  = l*4;
  const int head = l >> 3;
  const int beg = rowptr[v], end = rowptr[v+1];
  float den = 0.f, o0 = 0.f, o1 = 0.f, o2 = 0.f, o3 = 0.f;
  const unsigned short* xsu = (const unsigned short*)xs;
  for (int t = beg; t < end; t++){
    float w = expal[(long)t*4 + head];
    long s = src_t[t];
    ushort4 a = *(const ushort4*)(xsu + s*128 + c0);
    den += w;
    o0 += w*b2f_raw(a.x); o1 += w*b2f_raw(a.y);
    o2 += w*b2f_raw(a.z); o3 += w*b2f_raw(a.w);
  }
  float inv = 1.f/(den + 1e-16f);
  float4 gb = *(const float4*)(gatb_f + c0);
  unsigned int lo = cvtpk_bf16(o0*inv + gb.x, o1*inv + gb.y);
  unsigned int hi = cvtpk_bf16(o2*inv + gb.z, o3*inv + gb.w);
  *(uint2*)&((unsigned short*)h_local)[(long)v*128 + c0] = (uint2){lo, hi};
}

// ---------------- MFMA flash attention: block=(g,h), 8 waves, wave = 32-query tile --
__global__ __launch_bounds__(512, 6) void attn2_k(const bf16* __restrict__ qb,
    const bf16* __restrict__ kb, const bf16* __restrict__ vb,
    const float* __restrict__ ebuf_t, const unsigned short* __restrict__ epack,
    const int* __restrict__ rowptr, bf16* __restrict__ hattn){
  __shared__ short Vf[16*64*8];     // 16 KB
  __shared__ float sb[256*33];      // 33.8 KB
  const int bid = blockIdx.x;
  const int h = (bid >> 3) >> 4;
  const int g = (((bid >> 3) & 15) << 3) | (bid & 7);
  const int tid = threadIdx.x;
  const int w = tid >> 6, l = tid & 63;
  const int q31 = l & 31, hi = l >> 5;
  const int nbase = g << 8;

  for (int s2 = tid; s2 < 1024; s2 += 512){
    int f = s2 >> 6, ll = s2 & 63;
    int keyb = (f>>1)*32 + (f&1)*16 + ((ll>>5)*8);
    int d = ll & 15;
    short tmp[8];
    #pragma unroll
    for (int j=0;j<8;j++)
      tmp[j] = ((const short*)vb)[((long)(nbase + keyb + j))*128 + h*16 + d];
    *(short8*)&Vf[s2*8] = *(short8*)tmp;
  }
  for (int i = tid; i < 256*33; i += 512) sb[i] = 0.f;
  short8 qf = *(const short8*)((const short*)qb + ((long)(nbase + w*32 + q31))*128 + h*16 + hi*8);
  __syncthreads();

  float m = -1e30f, lsum = 0.f;
  f32x16 oacc = {0.f,0.f,0.f,0.f,0.f,0.f,0.f,0.f,0.f,0.f,0.f,0.f,0.f,0.f,0.f,0.f};
  #pragma unroll 1
  for (int kt = 0; kt < 8; kt++){
    int rb = rowptr[nbase + kt*32];
    int re = rowptr[nbase + kt*32 + 32];
    for (int t = rb + tid; t < re; t += 512){
      unsigned int p = epack[t];
      atomicAdd(&sb[(p>>8)*33 + (p&31)], ebuf_t[(long)h*kE + t]);
    }
    __syncthreads();
    short8 af = *(const short8*)((const short*)kb +
                 ((long)(nbase + kt*32 + q31))*128 + h*16 + hi*8);
    f32x16 acc = {0.f,0.f,0.f,0.f,0.f,0.f,0.f,0.f,0.f,0.f,0.f,0.f,0.f,0.f,0.f,0.f};
    acc = __builtin_amdgcn_mfma_f32_32x32x16_bf16(af, qf, acc, 0, 0, 0);
    float s[16];
    float* brow = &sb[(w*32 + q31)*33];
    #pragma unroll
    for (int r=0;r<16;r++){
      int krow = (r&3) + 8*(r>>2) + 4*hi;
      s[r] = acc[r]*0.25f + brow[krow];
      brow[krow] = 0.f;
    }
    __syncthreads();
    float tmax = s[0];
    #pragma unroll
    for (int r=1;r<16;r++) tmax = fmaxf(tmax, s[r]);
    tmax = fmaxf(tmax, __shfl_xor(tmax, 32));
    float mn = fmaxf(m, tmax);
    float corrq = __expf(m - mn);
    m = mn;
    float psum = 0.f;
    #pragma unroll
    for (int r=0;r<16;r++){ s[r] = __expf(s[r] - m); psum += s[r]; }
    lsum = lsum*corrq + psum;
    #pragma unroll
    for (int r=0;r<16;r++){
      int qrow = (r&3) + 8*(r>>2) + 4*hi;
      oacc[r] *= __shfl(corrq, qrow);
    }
    unsigned int a  = cvtpk_bf16(s[0],  s[1]);
    unsigned int b  = cvtpk_bf16(s[2],  s[3]);
    unsigned int c  = cvtpk_bf16(s[4],  s[5]);
    unsigned int d  = cvtpk_bf16(s[6],  s[7]);
    unsigned int e  = cvtpk_bf16(s[8],  s[9]);
    unsigned int f  = cvtpk_bf16(s[10], s[11]);
    unsigned int g2 = cvtpk_bf16(s[12], s[13]);
    unsigned int h2 = cvtpk_bf16(s[14], s[15]);
    plane_swap(a, c); plane_swap(b, d); plane_swap(e, g2); plane_swap(f, h2);
    union { unsigned int u[4]; short8 s8; } A1, A2;
    A1.u[0]=a; A1.u[1]=b; A1.u[2]=c; A1.u[3]=d;
    A2.u[0]=e; A2.u[1]=f; A2.u[2]=g2; A2.u[3]=h2;
    short8 v1 = *(short8*)&Vf[((kt*2+0)*64 + l)*8];
    short8 v2 = *(short8*)&Vf[((kt*2+1)*64 + l)*8];
    oacc = __builtin_amdgcn_mfma_f32_32x32x16_bf16(A1.s8, v1, oacc, 0,0,0);
    oacc = __builtin_amdgcn_mfma_f32_32x32x16_bf16(A2.s8, v2, oacc, 0,0,0);
  }
  lsum += __shfl_xor(lsum, 32);
  float linv = 1.f / lsum;
  #pragma unroll
  for (int r=0;r<16;r++){
    int qrow = (r&3) + 8*(r>>2) + 4*hi;
    float li = __shfl(linv, qrow);
    float ov = oacc[r]*li;
    if (q31 < 16)
      hattn[((long)(nbase + w*32 + qrow))*128 + h*16 + q31] = f2b(ov);
  }
}

// ---------------- residual add + LayerNorm ----------------
__global__ __launch_bounds__(256) void combine_ln_k(const void* __restrict__ a,
    const bf16* __restrict__ b, const bf16* __restrict__ c3,
    const float* __restrict__ g, const float* __restrict__ bb,
    void* __restrict__ outp, const int* __restrict__ flag,
    int a_raw, int is_final){
  const int tid = threadIdx.x;
  const int lane = tid & 63;
  const long row = (long)blockIdx.x*4 + (tid>>6);
  const long base = row*128;
  float a0, a1;
  if (a_raw && (*flag)){
    const float* ap = (const float*)a;
    a0 = ap[base+lane]; a1 = ap[base+lane+64];
  } else {
    const bf16* ap = (const bf16*)a;
    a0 = b2f(ap[base+lane]); a1 = b2f(ap[base+lane+64]);
  }
  float v0 = a0 + b2f(b[base+lane]);
  float v1 = a1 + b2f(b[base+lane+64]);
  if (c3){ v0 += b2f(c3[base+lane]); v1 += b2f(c3[base+lane+64]); }
  float s = v0 + v1;
  #pragma unroll
  for (int o=1; o<64; o<<=1) s += __shfl_xor(s, o);
  float mean = s * (1.f/128.f);
  float d0 = v0 - mean, d1 = v1 - mean;
  float q = d0*d0 + d1*d1;
  #pragma unroll
  for (int o=1; o<64; o<<=1) q += __shfl_xor(q, o);
  float r = rsqrtf(q*(1.f/128.f) + 1e-5f);
  float r0v = d0*r*g[lane]    + bb[lane];
  float r1v = d1*r*g[lane+64] + bb[lane+64];
  if (is_final && (*flag)){
    float* o = (float*)outp;
    o[base+lane]    = r0v;
    o[base+lane+64] = r1v;
  } else {
    bf16* o = (bf16*)outp;
    o[base+lane]    = f2b(r0v);
    o[base+lane+64] = f2b(r1v);
  }
}

// =====================================================================================
extern "C" void kernel_launch(void* const* d_in, const int* in_sizes, int n_in,
                              void* d_out, int out_size, void* d_ws, size_t ws_size,
                              hipStream_t stream){
  const void* x_raw   = d_in[0];
  const void* ea_raw  = d_in[1];
  const int*  ei      = (const int*)d_in[25];
  const int* srcA = ei;
  const int* dstA = ei + kE;

  char* ws = (char*)d_ws;
  size_t off = 0;
  auto alloc = [&](size_t bytes)->void*{
    void* p = ws + off;
    off = (off + bytes + 255) & ~(size_t)255;
    return p;
  };
  int*   flag    = (int*)alloc(4);
  float* Wsrc_f  = (float*)alloc(16384*4);
  float* Wdst_f  = (float*)alloc(16384*4);
  float* Wedge_f = (float*)alloc(4096*4);
  float* att_f   = (float*)alloc(128*4);
  float* gatb_f  = (float*)alloc(128*4);
  float* Wq_f    = (float*)alloc(16384*4);
  float* Wk_f    = (float*)alloc(16384*4);
  float* Wv_f    = (float*)alloc(16384*4);
  float* Wo_f    = (float*)alloc(16384*4);
  float* bo_f    = (float*)alloc(128*4);
  float* We_f    = (float*)alloc(256*4);
  float* be_f    = (float*)alloc(8*4);
  float* ln1g_f  = (float*)alloc(128*4);
  float* ln1b_f  = (float*)alloc(128*4);
  float* W1_f    = (float*)alloc(32768*4);
  float* b1_f    = (float*)alloc(256*4);
  float* W2_f    = (float*)alloc(32768*4);
  float* b2_f    = (float*)alloc(128*4);
  float* ln2g_f  = (float*)alloc(128*4);
  float* ln2b_f  = (float*)alloc(128*4);
  float* bias5   = (float*)alloc(640*4);
  bf16*  Wrep5   = (bf16*)alloc((size_t)5*16384*2);
  bf16*  WoR     = (bf16*)alloc((size_t)16384*2);
  bf16*  W1R     = (bf16*)alloc((size_t)32768*2);
  bf16*  W2R     = (bf16*)alloc((size_t)32768*2);
  bf16*  WeR     = (bf16*)alloc((size_t)4096*2);
  bf16*  WeRb    = (bf16*)alloc((size_t)512*2);
  bf16*  proj5   = (bf16*)alloc((size_t)5*kN*128*2);
  bf16* xs   = proj5;
  bf16* xd   = proj5 + (size_t)kN*128;
  bf16* qb   = proj5 + (size_t)2*kN*128;
  bf16* kbuf = proj5 + (size_t)3*kN*128;
  bf16* vbuf = proj5 + (size_t)4*kN*128;
  int* cnt        = (int*)alloc((size_t)2*kN*4);
  int* cursor     = cnt + kN;
  int* rowptr     = (int*)alloc((size_t)(kN+1)*4);
  int* eidx       = (int*)alloc((size_t)kE*4);
  unsigned short* epack = (unsigned short*)alloc((size_t)kE*2);
  float* ebuf_t   = (float*)alloc((size_t)8*kE*4);
  float* expal_t  = (float*)alloc((size_t)kE*4*4);
  int*   src_t    = (int*)alloc((size_t)kE*4);
  bf16* h_local   = (bf16*)alloc((size_t)kN*128*2);
  bf16* hattn_pre = (bf16*)alloc((size_t)kN*128*2);
  bf16* h_attn    = (bf16*)alloc((size_t)kN*128*2);
  bf16* hbuf      = (bf16*)alloc((size_t)kN*128*2);
  bf16* tbuf      = (bf16*)alloc((size_t)kN*256*2);
  bf16* f2buf     = (bf16*)alloc((size_t)kN*128*2);
  (void)ws_size; (void)in_sizes; (void)n_in; (void)out_size;

  dim3 b256(256);

  detect_k<<<1, b256, 0, stream>>>(x_raw, flag);
  hipMemsetAsync(bias5, 0, 256*4, stream);
  hipMemsetAsync(cnt, 0, (size_t)2*kN*4, stream);

  // CSR build first (only needs dstA) so edge3 can run in CSR order
  hist_k<<<kE/256, b256, 0, stream>>>(dstA, cnt);
  scan_k<<<1, 1024, 0, stream>>>(cnt, rowptr);
  scatter_k<<<kE/256, b256, 0, stream>>>(dstA, rowptr, cursor, eidx);

  ImpArgs ia;
  const void* srcs[23] = {d_in[2], d_in[3], d_in[4], d_in[5], d_in[6],
                          d_in[7], d_in[8], d_in[9], d_in[10], d_in[11], d_in[12],
                          d_in[13], d_in[14], d_in[15], d_in[16], d_in[17], d_in[18],
                          d_in[19], d_in[20], d_in[21], d_in[22], d_in[23], d_in[24]};
  void* dsts[23] = {Wsrc_f, Wdst_f, Wedge_f, att_f, gatb_f,
                    Wq_f, bias5+256, Wk_f, bias5+384, Wv_f, bias5+512,
                    Wo_f, bo_f, We_f, be_f, ln1g_f, ln1b_f,
                    W1_f, b1_f, W2_f, b2_f, ln2g_f, ln2b_f};
  int ns[23] = {16384, 16384, 4096, 128, 128,
                16384, 128, 16384, 128, 16384, 128,
                16384, 128, 256, 8, 128, 128,
                32768, 256, 32768, 128, 128, 128};
  for (int i=0;i<23;i++){ ia.e[i].src=srcs[i]; ia.e[i].dst=dsts[i]; ia.e[i].n=ns[i]; }
  import_k<<<dim3(64,23), b256, 0, stream>>>(ia, flag);

  repack5_k<<<(5*16384)/256, b256, 0, stream>>>(Wsrc_f, Wdst_f, Wq_f, Wk_f, Wv_f, Wrep5);
  RepEnt ro{Wo_f, WoR, 16384, 3, 128, 0};
  RepEnt r1{W1_f, W1R, 32768, 4, 256, 0};
  RepEnt r2{W2_f, W2R, 32768, 3, 128, 0};
  RepEnt re{Wedge_f, WeR, 4096, 3, 128, 1};   // perm'd for edge3 epilogue
  RepEnt rb{We_f, WeRb, 512, 0, 8, 2};        // We padded B-frag for eb MFMA
  repack_k<<<dim3(128,5), b256, 0, stream>>>(ro, r1, r2, re, rb);

  gemm5_k<<<kN/64, b256, 0, stream>>>(x_raw, flag, Wrep5, bias5, proj5);

  edge3_k<<<kE/64, b256, 0, stream>>>(ea_raw, flag, eidx, srcA, dstA, xs, xd,
                                      WeR, WeRb, att_f, be_f,
                                      expal_t, ebuf_t, epack, src_t);

  gat_agg_k<<<kN/8, b256, 0, stream>>>(expal_t, rowptr, src_t, xs, gatb_f, h_local);

  attn2_k<<<kG*kHA, dim3(512), 0, stream>>>(qb, kbuf, vbuf, ebuf_t, epack, rowptr, hattn_pre);
  gemm_mfma_k<128,128,1><<<kN/64, b256, 0, stream>>>(hattn_pre, WoR, bo_f, h_attn);

  combine_ln_k<<<kN/4, b256, 0, stream>>>(x_raw, h_local, h_attn, ln1g_f, ln1b_f,
                                          hbuf, flag, 1, 0);

  gemm_mfma_k<128,256,2><<<kN/64, b256, 0, stream>>>(hbuf, W1R, b1_f, tbuf);
  gemm_mfma_k<256,128,1><<<kN/64, b256, 0, stream>>>(tbuf, W2R, b2_f, f2buf);

  combine_ln_k<<<kN/4, b256, 0, stream>>>(hbuf, f2buf, nullptr, ln2g_f, ln2b_f,
                                          d_out, flag, 0, 1);
}